// Round 1
// baseline (1201.717 us; speedup 1.0000x reference)
//
#include <hip/hip_runtime.h>

#define N_NODES 50000
#define N_EDGES 800000
#define F_IN    128
#define HEADS   4
#define HID     64
#define LAT     64
#define N_EC    8
#define SLOPE   0.2f

__device__ __forceinline__ float lrelu(float x) { return x > 0.f ? x : SLOPE * x; }

// ---------------- CSR build (by dst) ----------------
__global__ void count_kernel(const int* __restrict__ ei, int* __restrict__ cnt) {
    int e = blockIdx.x * blockDim.x + threadIdx.x;
    if (e < N_EDGES) atomicAdd(&cnt[ei[N_EDGES + e]], 1);
}

__global__ __launch_bounds__(1024) void scan_kernel(const int* __restrict__ cnt,
                                                    int* __restrict__ row_start) {
    __shared__ int wsum[16];
    __shared__ int carry;
    int tid = threadIdx.x, lane = tid & 63, w = tid >> 6;
    if (tid == 0) carry = 0;
    __syncthreads();
    for (int base = 0; base < N_NODES; base += 1024) {
        int i = base + tid;
        int v = (i < N_NODES) ? cnt[i] : 0;
        int incl = v;
#pragma unroll
        for (int off = 1; off < 64; off <<= 1) {
            int t = __shfl_up(incl, off, 64);
            if (lane >= off) incl += t;
        }
        if (lane == 63) wsum[w] = incl;
        __syncthreads();
        if (w == 0 && lane < 16) {
            int s = wsum[lane];
            int si = s;
#pragma unroll
            for (int off = 1; off < 16; off <<= 1) {
                int t = __shfl_up(si, off, 64);
                if (lane >= off) si += t;
            }
            wsum[lane] = si - s;  // exclusive prefix of wave sums
        }
        __syncthreads();
        int total_prev = carry;
        if (i < N_NODES) row_start[i] = total_prev + wsum[w] + incl - v;
        __syncthreads();
        if (tid == 1023) carry = total_prev + wsum[15] + incl;
        __syncthreads();
    }
    if (threadIdx.x == 0) row_start[N_NODES] = carry;
}

__global__ void scatter_kernel(const int* __restrict__ ei, const int* __restrict__ row_start,
                               int* __restrict__ cursor, int* __restrict__ esrc) {
    int e = blockIdx.x * blockDim.x + threadIdx.x;
    if (e < N_EDGES) {
        int d = ei[N_EDGES + e];
        int pos = row_start[d] + atomicAdd(&cursor[d], 1);
        esrc[pos] = ei[e];
    }
}

// ---------------- fp32 tiled GEMM: C[M,N] = A[M,K] @ B[K,N] (+bias) ----------------
// BM=BN=64, BK=32, 256 threads, 4x4 per-thread tile. K,N multiples of 32/64; M guarded.
template <bool BIAS>
__global__ __launch_bounds__(256) void gemm_kernel(const float* __restrict__ A,
                                                   const float* __restrict__ B,
                                                   const float* __restrict__ bias,
                                                   float* __restrict__ C, int M, int N, int K) {
    __shared__ float As[32][68];  // [k][row] (transposed for vectorized reads)
    __shared__ float Bs[32][68];  // [k][col]
    int tid = threadIdx.x;
    int brow = blockIdx.x * 64;
    int bcol = blockIdx.y * 64;
    int tr = (tid >> 4) * 4;
    int tc = (tid & 15) * 4;
    float acc[4][4] = {};
    for (int k0 = 0; k0 < K; k0 += 32) {
#pragma unroll
        for (int p = 0; p < 2; p++) {
            int idx = tid + p * 256;
            int r = idx >> 3;
            int c4 = (idx & 7) << 2;
            int gr = brow + r;
            float4 v = make_float4(0.f, 0.f, 0.f, 0.f);
            if (gr < M) v = *reinterpret_cast<const float4*>(&A[(size_t)gr * K + k0 + c4]);
            As[c4 + 0][r] = v.x; As[c4 + 1][r] = v.y; As[c4 + 2][r] = v.z; As[c4 + 3][r] = v.w;
        }
#pragma unroll
        for (int p = 0; p < 2; p++) {
            int idx = tid + p * 256;
            int r = idx >> 4;
            int c4 = (idx & 15) << 2;
            float4 v = *reinterpret_cast<const float4*>(&B[(size_t)(k0 + r) * N + bcol + c4]);
            *reinterpret_cast<float4*>(&Bs[r][c4]) = v;
        }
        __syncthreads();
#pragma unroll
        for (int k = 0; k < 32; k++) {
            float4 a = *reinterpret_cast<const float4*>(&As[k][tr]);
            float4 b = *reinterpret_cast<const float4*>(&Bs[k][tc]);
            acc[0][0] += a.x * b.x; acc[0][1] += a.x * b.y; acc[0][2] += a.x * b.z; acc[0][3] += a.x * b.w;
            acc[1][0] += a.y * b.x; acc[1][1] += a.y * b.y; acc[1][2] += a.y * b.z; acc[1][3] += a.y * b.w;
            acc[2][0] += a.z * b.x; acc[2][1] += a.z * b.y; acc[2][2] += a.z * b.z; acc[2][3] += a.z * b.w;
            acc[3][0] += a.w * b.x; acc[3][1] += a.w * b.y; acc[3][2] += a.w * b.z; acc[3][3] += a.w * b.w;
        }
        __syncthreads();
    }
#pragma unroll
    for (int i = 0; i < 4; i++) {
        int gr = brow + tr + i;
        if (gr < M) {
            float4 v;
            v.x = acc[i][0]; v.y = acc[i][1]; v.z = acc[i][2]; v.w = acc[i][3];
            if (BIAS) {
                const float4 bb = *reinterpret_cast<const float4*>(&bias[bcol + tc]);
                v.x += bb.x; v.y += bb.y; v.z += bb.z; v.w += bb.w;
            }
            *reinterpret_cast<float4*>(&C[(size_t)gr * N + bcol + tc]) = v;
        }
    }
}

// ---------------- attention scalars: as[n,h] = <h[n,h,:], att_src[h,:]> ----------------
template <int H>
__global__ void att_kernel(const float* __restrict__ Hf, const float* __restrict__ att_src,
                           const float* __restrict__ att_dst, float* __restrict__ as_,
                           float* __restrict__ ad_) {
    int wid = (blockIdx.x * blockDim.x + threadIdx.x) >> 6;
    int lane = threadIdx.x & 63;
    if (wid >= N_NODES * H) return;
    int h = wid % H;
    float v = Hf[(size_t)wid * 64 + lane];  // wid = n*H + h; row stride H*64
    float ps = v * att_src[h * 64 + lane];
    float pd = v * att_dst[h * 64 + lane];
#pragma unroll
    for (int off = 32; off; off >>= 1) {
        ps += __shfl_xor(ps, off, 64);
        pd += __shfl_xor(pd, off, 64);
    }
    if (lane == 0) { as_[wid] = ps; ad_[wid] = pd; }
}

// ---------------- GAT aggregation: wave per (node, head), lane = channel ----------------
template <int H, bool RELU>
__global__ void agg_kernel(const float* __restrict__ Hf, const float* __restrict__ as_,
                           const float* __restrict__ ad_, const int* __restrict__ row_start,
                           const int* __restrict__ esrc, const float* __restrict__ bias,
                           float* __restrict__ out) {
    int wid = (blockIdx.x * blockDim.x + threadIdx.x) >> 6;
    int lane = threadIdx.x & 63;
    if (wid >= N_NODES * H) return;
    int n = wid / H, h = wid % H;
    int beg = row_start[n], end = row_start[n + 1];
    float adn = ad_[wid];
    float aself = lrelu(as_[wid] + adn);
    float m = aself;
    for (int j = beg; j < end; j++) {
        int s = esrc[j];
        m = fmaxf(m, lrelu(as_[s * H + h] + adn));
    }
    float eself = __expf(aself - m);
    float denom = eself;
    float acc = eself * Hf[(size_t)wid * 64 + lane];
    for (int j = beg; j < end; j++) {
        int s = esrc[j];
        float e = __expf(lrelu(as_[s * H + h] + adn) - m);
        denom += e;
        acc += e * Hf[((size_t)s * H + h) * 64 + lane];
    }
    float v = acc / (denom + 1e-16f) + bias[h * 64 + lane];
    if (RELU) v = fmaxf(v, 0.f);
    out[(size_t)wid * 64 + lane] = v;
}

// ---------------- build B for PQ GEMM: Bpq[k][j<64]=We1[k][j]; Bpq[k][64+j]=We1[64+k][j] ----------------
__global__ void build_bpq(const float* __restrict__ We1, float* __restrict__ Bpq) {
    int idx = blockIdx.x * blockDim.x + threadIdx.x;
    if (idx < 64 * 128) {
        int k = idx >> 7;
        int j = idx & 127;
        Bpq[idx] = (j < 64) ? We1[k * 64 + j] : We1[(64 + k) * 64 + (j - 64)];
    }
}

// ---------------- edge decode: wave per edge, lane = hidden channel ----------------
__global__ void edge_decode_kernel(const float* __restrict__ PQ, const int* __restrict__ ei,
                                   const float* __restrict__ be1, const float* __restrict__ We2,
                                   const float* __restrict__ be2, float* __restrict__ out) {
    int wid = (blockIdx.x * blockDim.x + threadIdx.x) >> 6;
    int lane = threadIdx.x & 63;
    if (wid >= N_EDGES) return;
    int s = ei[wid], d = ei[N_EDGES + wid];
    float t = PQ[(size_t)s * 128 + lane] + PQ[(size_t)d * 128 + 64 + lane] + be1[lane];
    t = fmaxf(t, 0.f);
    float p[8];
#pragma unroll
    for (int j = 0; j < 8; j++) p[j] = t * We2[lane * 8 + j];
#pragma unroll
    for (int off = 32; off; off >>= 1) {
#pragma unroll
        for (int j = 0; j < 8; j++) p[j] += __shfl_xor(p[j], off, 64);
    }
    if (lane < 8) {
        float v = p[0];
#pragma unroll
        for (int j = 1; j < 8; j++)
            if (lane == j) v = p[j];
        out[(size_t)wid * 8 + lane] = v + be2[lane];
    }
}

extern "C" void kernel_launch(void* const* d_in, const int* in_sizes, int n_in,
                              void* d_out, int out_size, void* d_ws, size_t ws_size,
                              hipStream_t stream) {
    const float* x        = (const float*)d_in[0];
    const int*   ei       = (const int*)d_in[1];
    const float* W1       = (const float*)d_in[2];
    const float* att_src1 = (const float*)d_in[3];
    const float* att_dst1 = (const float*)d_in[4];
    const float* b1       = (const float*)d_in[5];
    const float* W2       = (const float*)d_in[6];
    const float* att_src2 = (const float*)d_in[7];
    const float* att_dst2 = (const float*)d_in[8];
    const float* b2       = (const float*)d_in[9];
    const float* Wn       = (const float*)d_in[10];
    const float* bn       = (const float*)d_in[11];
    const float* We1      = (const float*)d_in[12];
    const float* be1      = (const float*)d_in[13];
    const float* We2      = (const float*)d_in[14];
    const float* be2      = (const float*)d_in[15];

    char* ws = (char*)d_ws;
    size_t off = 0;
    auto alloc = [&](size_t bytes) {
        void* p = ws + off;
        off += (bytes + 255) & ~(size_t)255;
        return p;
    };
    int*   cnt       = (int*)alloc((size_t)N_NODES * 4);
    int*   row_start = (int*)alloc((size_t)(N_NODES + 1) * 4);
    int*   esrc      = (int*)alloc((size_t)N_EDGES * 4);
    float* H1        = (float*)alloc((size_t)N_NODES * 256 * 4);
    float* as1       = (float*)alloc((size_t)N_NODES * 4 * 4);
    float* ad1       = (float*)alloc((size_t)N_NODES * 4 * 4);
    float* hout      = (float*)alloc((size_t)N_NODES * 256 * 4);
    float* H2        = (float*)alloc((size_t)N_NODES * 64 * 4);
    float* as2       = (float*)alloc((size_t)N_NODES * 4);
    float* ad2       = (float*)alloc((size_t)N_NODES * 4);
    float* z         = (float*)alloc((size_t)N_NODES * 64 * 4);
    float* Bpq       = (float*)alloc((size_t)64 * 128 * 4);
    float* PQ        = H1;  // H1 is dead by the time PQ is produced

    float* recon_x = (float*)d_out;
    float* recon_e = (float*)d_out + (size_t)N_NODES * F_IN;

    // CSR build
    hipMemsetAsync(cnt, 0, (size_t)N_NODES * 4, stream);
    count_kernel<<<(N_EDGES + 255) / 256, 256, 0, stream>>>(ei, cnt);
    scan_kernel<<<1, 1024, 0, stream>>>(cnt, row_start);
    hipMemsetAsync(cnt, 0, (size_t)N_NODES * 4, stream);
    scatter_kernel<<<(N_EDGES + 255) / 256, 256, 0, stream>>>(ei, row_start, cnt, esrc);

    // conv1
    dim3 g1((N_NODES + 63) / 64, 256 / 64);
    gemm_kernel<false><<<g1, 256, 0, stream>>>(x, W1, nullptr, H1, N_NODES, 256, 128);
    att_kernel<4><<<(N_NODES * 4 * 64 + 255) / 256, 256, 0, stream>>>(H1, att_src1, att_dst1, as1, ad1);
    agg_kernel<4, true><<<(N_NODES * 4 * 64 + 255) / 256, 256, 0, stream>>>(H1, as1, ad1, row_start, esrc, b1, hout);

    // conv2
    dim3 g2((N_NODES + 63) / 64, 1);
    gemm_kernel<false><<<g2, 256, 0, stream>>>(hout, W2, nullptr, H2, N_NODES, 64, 256);
    att_kernel<1><<<(N_NODES * 64 + 255) / 256, 256, 0, stream>>>(H2, att_src2, att_dst2, as2, ad2);
    agg_kernel<1, false><<<(N_NODES * 64 + 255) / 256, 256, 0, stream>>>(H2, as2, ad2, row_start, esrc, b2, z);

    // node decode
    dim3 g3((N_NODES + 63) / 64, 128 / 64);
    gemm_kernel<true><<<g3, 256, 0, stream>>>(z, Wn, bn, recon_x, N_NODES, 128, 64);

    // edge decode: P|Q precompute then per-edge fuse
    build_bpq<<<(64 * 128 + 255) / 256, 256, 0, stream>>>(We1, Bpq);
    gemm_kernel<false><<<g3, 256, 0, stream>>>(z, Bpq, nullptr, PQ, N_NODES, 128, 64);
    edge_decode_kernel<<<(N_EDGES * 64 + 255) / 256, 256, 0, stream>>>(PQ, ei, be1, We2, be2, recon_e);
}

// Round 2
// 852.174 us; speedup vs baseline: 1.4102x; 1.4102x over previous
//
#include <hip/hip_runtime.h>

#define N_NODES 50000
#define N_EDGES 800000
#define F_IN    128
#define HEADS   4
#define HID     64
#define LAT     64
#define N_EC    8
#define SLOPE   0.2f

__device__ __forceinline__ float lrelu(float x) { return x > 0.f ? x : SLOPE * x; }
__device__ __forceinline__ float4 operator+(float4 a, float4 b) { return make_float4(a.x+b.x, a.y+b.y, a.z+b.z, a.w+b.w); }
__device__ __forceinline__ float4 operator*(float4 a, float4 b) { return make_float4(a.x*b.x, a.y*b.y, a.z*b.z, a.w*b.w); }
__device__ __forceinline__ float4 lrelu4(float4 a) { return make_float4(lrelu(a.x), lrelu(a.y), lrelu(a.z), lrelu(a.w)); }
__device__ __forceinline__ float4 max4(float4 a, float4 b) { return make_float4(fmaxf(a.x,b.x), fmaxf(a.y,b.y), fmaxf(a.z,b.z), fmaxf(a.w,b.w)); }
__device__ __forceinline__ float4 exp4(float4 a) { return make_float4(__expf(a.x), __expf(a.y), __expf(a.z), __expf(a.w)); }
__device__ __forceinline__ float4 fma4(float4 a, float4 b, float4 c) {
    return make_float4(fmaf(a.x,b.x,c.x), fmaf(a.y,b.y,c.y), fmaf(a.z,b.z,c.z), fmaf(a.w,b.w,c.w));
}

// ---------------- CSR build (by dst) ----------------
__global__ void count_kernel(const int* __restrict__ ei, int* __restrict__ cnt) {
    int e = blockIdx.x * blockDim.x + threadIdx.x;
    if (e < N_EDGES) atomicAdd(&cnt[ei[N_EDGES + e]], 1);
}

__global__ __launch_bounds__(1024) void scan_kernel(const int* __restrict__ cnt,
                                                    int* __restrict__ row_start) {
    __shared__ int wsum[16];
    __shared__ int carry;
    int tid = threadIdx.x, lane = tid & 63, w = tid >> 6;
    if (tid == 0) carry = 0;
    __syncthreads();
    for (int base = 0; base < N_NODES; base += 1024) {
        int i = base + tid;
        int v = (i < N_NODES) ? cnt[i] : 0;
        int incl = v;
#pragma unroll
        for (int off = 1; off < 64; off <<= 1) {
            int t = __shfl_up(incl, off, 64);
            if (lane >= off) incl += t;
        }
        if (lane == 63) wsum[w] = incl;
        __syncthreads();
        if (w == 0 && lane < 16) {
            int s = wsum[lane];
            int si = s;
#pragma unroll
            for (int off = 1; off < 16; off <<= 1) {
                int t = __shfl_up(si, off, 64);
                if (lane >= off) si += t;
            }
            wsum[lane] = si - s;  // exclusive prefix of wave sums
        }
        __syncthreads();
        int total_prev = carry;
        if (i < N_NODES) row_start[i] = total_prev + wsum[w] + incl - v;
        __syncthreads();
        if (tid == 1023) carry = total_prev + wsum[15] + incl;
        __syncthreads();
    }
    if (threadIdx.x == 0) row_start[N_NODES] = carry;
}

__global__ void scatter_kernel(const int* __restrict__ ei, const int* __restrict__ row_start,
                               int* __restrict__ cursor, int* __restrict__ esrc) {
    int e = blockIdx.x * blockDim.x + threadIdx.x;
    if (e < N_EDGES) {
        int d = ei[N_EDGES + e];
        int pos = row_start[d] + atomicAdd(&cursor[d], 1);
        esrc[pos] = ei[e];
    }
}

// ---------------- weight permutes for head-major (channel-major-heads) layout ----------------
// W1p[k][c*4+h] = W1[k][h*64+c]; att/bias likewise
__global__ void permute_w1(const float* __restrict__ W1, const float* __restrict__ as_,
                           const float* __restrict__ ad_, const float* __restrict__ b1,
                           float* __restrict__ W1p, float* __restrict__ asp,
                           float* __restrict__ adp, float* __restrict__ b1p) {
    int idx = blockIdx.x * blockDim.x + threadIdx.x;
    if (idx < 128 * 256) {
        int k = idx >> 8, j = idx & 255;
        int c = j >> 2, h = j & 3;
        W1p[idx] = W1[k * 256 + h * 64 + c];
    }
    if (idx < 256) {
        int c = idx >> 2, h = idx & 3;
        asp[idx] = as_[h * 64 + c];
        adp[idx] = ad_[h * 64 + c];
        b1p[idx] = b1[h * 64 + c];
    }
}

// W2p[c*4+h][j] = W2[h*64+c][j]
__global__ void permute_w2(const float* __restrict__ W2, float* __restrict__ W2p) {
    int idx = blockIdx.x * blockDim.x + threadIdx.x;
    if (idx < 256 * 64) {
        int r = idx >> 6, j = idx & 63;
        int c = r >> 2, h = r & 3;
        W2p[idx] = W2[(h * 64 + c) * 64 + j];
    }
}

// ---------------- fp32 tiled GEMM: C[M,N] = A[M,K] @ B[K,N] (+bias) ----------------
template <bool BIAS>
__global__ __launch_bounds__(256) void gemm_kernel(const float* __restrict__ A,
                                                   const float* __restrict__ B,
                                                   const float* __restrict__ bias,
                                                   float* __restrict__ C, int M, int N, int K) {
    __shared__ float As[32][68];  // [k][row]
    __shared__ float Bs[32][68];  // [k][col]
    int tid = threadIdx.x;
    int brow = blockIdx.x * 64;
    int bcol = blockIdx.y * 64;
    int tr = (tid >> 4) * 4;
    int tc = (tid & 15) * 4;
    float acc[4][4] = {};
    for (int k0 = 0; k0 < K; k0 += 32) {
#pragma unroll
        for (int p = 0; p < 2; p++) {
            int idx = tid + p * 256;
            int r = idx >> 3;
            int c4 = (idx & 7) << 2;
            int gr = brow + r;
            float4 v = make_float4(0.f, 0.f, 0.f, 0.f);
            if (gr < M) v = *reinterpret_cast<const float4*>(&A[(size_t)gr * K + k0 + c4]);
            As[c4 + 0][r] = v.x; As[c4 + 1][r] = v.y; As[c4 + 2][r] = v.z; As[c4 + 3][r] = v.w;
        }
#pragma unroll
        for (int p = 0; p < 2; p++) {
            int idx = tid + p * 256;
            int r = idx >> 4;
            int c4 = (idx & 15) << 2;
            float4 v = *reinterpret_cast<const float4*>(&B[(size_t)(k0 + r) * N + bcol + c4]);
            *reinterpret_cast<float4*>(&Bs[r][c4]) = v;
        }
        __syncthreads();
#pragma unroll
        for (int k = 0; k < 32; k++) {
            float4 a = *reinterpret_cast<const float4*>(&As[k][tr]);
            float4 b = *reinterpret_cast<const float4*>(&Bs[k][tc]);
            acc[0][0] += a.x * b.x; acc[0][1] += a.x * b.y; acc[0][2] += a.x * b.z; acc[0][3] += a.x * b.w;
            acc[1][0] += a.y * b.x; acc[1][1] += a.y * b.y; acc[1][2] += a.y * b.z; acc[1][3] += a.y * b.w;
            acc[2][0] += a.z * b.x; acc[2][1] += a.z * b.y; acc[2][2] += a.z * b.z; acc[2][3] += a.z * b.w;
            acc[3][0] += a.w * b.x; acc[3][1] += a.w * b.y; acc[3][2] += a.w * b.z; acc[3][3] += a.w * b.w;
        }
        __syncthreads();
    }
#pragma unroll
    for (int i = 0; i < 4; i++) {
        int gr = brow + tr + i;
        if (gr < M) {
            float4 v;
            v.x = acc[i][0]; v.y = acc[i][1]; v.z = acc[i][2]; v.w = acc[i][3];
            if (BIAS) {
                const float4 bb = *reinterpret_cast<const float4*>(&bias[bcol + tc]);
                v.x += bb.x; v.y += bb.y; v.z += bb.z; v.w += bb.w;
            }
            *reinterpret_cast<float4*>(&C[(size_t)gr * N + bcol + tc]) = v;
        }
    }
}

// ---------------- conv1 attention scalars, head-major: wave per node ----------------
__global__ __launch_bounds__(256) void att4_kernel(const float* __restrict__ H1p,
                                                   const float* __restrict__ asp,
                                                   const float* __restrict__ adp,
                                                   float4* __restrict__ as4,
                                                   float4* __restrict__ ad4) {
    int wid = (blockIdx.x * blockDim.x + threadIdx.x) >> 6;
    int lane = threadIdx.x & 63;
    if (wid >= N_NODES) return;
    float4 v = *reinterpret_cast<const float4*>(&H1p[(size_t)wid * 256 + lane * 4]);
    float4 s = *reinterpret_cast<const float4*>(&asp[lane * 4]);
    float4 d = *reinterpret_cast<const float4*>(&adp[lane * 4]);
    float4 ps = v * s, pd = v * d;
#pragma unroll
    for (int off = 32; off; off >>= 1) {
        ps.x += __shfl_xor(ps.x, off, 64); ps.y += __shfl_xor(ps.y, off, 64);
        ps.z += __shfl_xor(ps.z, off, 64); ps.w += __shfl_xor(ps.w, off, 64);
        pd.x += __shfl_xor(pd.x, off, 64); pd.y += __shfl_xor(pd.y, off, 64);
        pd.z += __shfl_xor(pd.z, off, 64); pd.w += __shfl_xor(pd.w, off, 64);
    }
    if (lane == 0) { as4[wid] = ps; ad4[wid] = pd; }
}

// ---------------- conv1 aggregation: wave per node, all 4 heads, lane=channel ----------------
__global__ __launch_bounds__(256) void agg4_kernel(const float* __restrict__ H1p,
                                                   const float4* __restrict__ as4,
                                                   const float4* __restrict__ ad4,
                                                   const int* __restrict__ row_start,
                                                   const int* __restrict__ esrc,
                                                   const float* __restrict__ b1p,
                                                   float* __restrict__ out) {
    int wid = (blockIdx.x * blockDim.x + threadIdx.x) >> 6;
    int lane = threadIdx.x & 63;
    if (wid >= N_NODES) return;
    int beg = row_start[wid], end = row_start[wid + 1];
    float4 adn = ad4[wid];
    float4 a_self = lrelu4(as4[wid] + adn);
    float4 m = a_self;
    // pass 1: segment max (unroll 4; gathers independent)
    int j = beg;
    for (; j + 3 < end; j += 4) {
        int s0 = esrc[j], s1 = esrc[j + 1], s2 = esrc[j + 2], s3 = esrc[j + 3];
        float4 a0 = as4[s0], a1 = as4[s1], a2 = as4[s2], a3 = as4[s3];
        m = max4(m, lrelu4(a0 + adn));
        m = max4(m, lrelu4(a1 + adn));
        m = max4(m, lrelu4(a2 + adn));
        m = max4(m, lrelu4(a3 + adn));
    }
    for (; j < end; j++) m = max4(m, lrelu4(as4[esrc[j]] + adn));
    // pass 2: exp + weighted accumulate (unroll 2 for gather MLP)
    float4 mneg = make_float4(-m.x, -m.y, -m.z, -m.w);
    float4 e_self = exp4(a_self + mneg);
    float4 den = e_self;
    float4 vself = *reinterpret_cast<const float4*>(&H1p[(size_t)wid * 256 + lane * 4]);
    float4 acc = e_self * vself;
    j = beg;
    for (; j + 1 < end; j += 2) {
        int s0 = esrc[j], s1 = esrc[j + 1];
        float4 a0 = as4[s0];
        float4 v0 = *reinterpret_cast<const float4*>(&H1p[(size_t)s0 * 256 + lane * 4]);
        float4 a1 = as4[s1];
        float4 v1 = *reinterpret_cast<const float4*>(&H1p[(size_t)s1 * 256 + lane * 4]);
        float4 e0 = exp4(lrelu4(a0 + adn) + mneg);
        float4 e1 = exp4(lrelu4(a1 + adn) + mneg);
        den = den + e0 + e1;
        acc = fma4(e0, v0, acc);
        acc = fma4(e1, v1, acc);
    }
    if (j < end) {
        int s0 = esrc[j];
        float4 a0 = as4[s0];
        float4 v0 = *reinterpret_cast<const float4*>(&H1p[(size_t)s0 * 256 + lane * 4]);
        float4 e0 = exp4(lrelu4(a0 + adn) + mneg);
        den = den + e0;
        acc = fma4(e0, v0, acc);
    }
    const float4 bb = *reinterpret_cast<const float4*>(&b1p[lane * 4]);
    float4 o;
    o.x = fmaxf(acc.x / (den.x + 1e-16f) + bb.x, 0.f);
    o.y = fmaxf(acc.y / (den.y + 1e-16f) + bb.y, 0.f);
    o.z = fmaxf(acc.z / (den.z + 1e-16f) + bb.z, 0.f);
    o.w = fmaxf(acc.w / (den.w + 1e-16f) + bb.w, 0.f);
    *reinterpret_cast<float4*>(&out[(size_t)wid * 256 + lane * 4]) = o;
}

// ---------------- conv2 attention scalars (H=1) ----------------
__global__ __launch_bounds__(256) void att1_kernel(const float* __restrict__ Hf,
                                                   const float* __restrict__ att_src,
                                                   const float* __restrict__ att_dst,
                                                   float* __restrict__ as_,
                                                   float* __restrict__ ad_) {
    int wid = (blockIdx.x * blockDim.x + threadIdx.x) >> 6;
    int lane = threadIdx.x & 63;
    if (wid >= N_NODES) return;
    float v = Hf[(size_t)wid * 64 + lane];
    float ps = v * att_src[lane];
    float pd = v * att_dst[lane];
#pragma unroll
    for (int off = 32; off; off >>= 1) {
        ps += __shfl_xor(ps, off, 64);
        pd += __shfl_xor(pd, off, 64);
    }
    if (lane == 0) { as_[wid] = ps; ad_[wid] = pd; }
}

// ---------------- conv2 aggregation: wave per node, 4 edge-slots x 16 lanes (float4/ch) ----------------
__global__ __launch_bounds__(256) void agg1_kernel(const float* __restrict__ Hf,
                                                   const float* __restrict__ as_,
                                                   const float* __restrict__ ad_,
                                                   const int* __restrict__ row_start,
                                                   const int* __restrict__ esrc,
                                                   const float* __restrict__ bias,
                                                   float* __restrict__ out) {
    int wid = (blockIdx.x * blockDim.x + threadIdx.x) >> 6;
    int lane = threadIdx.x & 63;
    if (wid >= N_NODES) return;
    int g = lane >> 4;        // edge slot 0..3
    int c16 = lane & 15;      // channel group (float4)
    int beg = row_start[wid], end = row_start[wid + 1];
    float adn = ad_[wid];
    float a_self = lrelu(as_[wid] + adn);
    float m = a_self;
    for (int j = beg + g; j < end; j += 4)
        m = fmaxf(m, lrelu(as_[esrc[j]] + adn));
    m = fmaxf(m, __shfl_xor(m, 16, 64));
    m = fmaxf(m, __shfl_xor(m, 32, 64));
    float4 acc = make_float4(0.f, 0.f, 0.f, 0.f);
    float den = 0.f;
    for (int j = beg + g; j < end; j += 4) {
        int s = esrc[j];
        float e = __expf(lrelu(as_[s] + adn) - m);
        float4 v = *reinterpret_cast<const float4*>(&Hf[(size_t)s * 64 + c16 * 4]);
        den += e;
        acc.x = fmaf(e, v.x, acc.x); acc.y = fmaf(e, v.y, acc.y);
        acc.z = fmaf(e, v.z, acc.z); acc.w = fmaf(e, v.w, acc.w);
    }
    if (g == 0) {
        float e = __expf(a_self - m);
        float4 v = *reinterpret_cast<const float4*>(&Hf[(size_t)wid * 64 + c16 * 4]);
        den += e;
        acc.x = fmaf(e, v.x, acc.x); acc.y = fmaf(e, v.y, acc.y);
        acc.z = fmaf(e, v.z, acc.z); acc.w = fmaf(e, v.w, acc.w);
    }
#pragma unroll
    for (int off = 32; off >= 16; off >>= 1) {
        den += __shfl_xor(den, off, 64);
        acc.x += __shfl_xor(acc.x, off, 64);
        acc.y += __shfl_xor(acc.y, off, 64);
        acc.z += __shfl_xor(acc.z, off, 64);
        acc.w += __shfl_xor(acc.w, off, 64);
    }
    if (g == 0) {
        const float4 bb = *reinterpret_cast<const float4*>(&bias[c16 * 4]);
        float inv = 1.f / (den + 1e-16f);
        float4 o = make_float4(acc.x * inv + bb.x, acc.y * inv + bb.y,
                               acc.z * inv + bb.z, acc.w * inv + bb.w);
        *reinterpret_cast<float4*>(&out[(size_t)wid * 64 + c16 * 4]) = o;
    }
}

// ---------------- build B for PQ GEMM ----------------
__global__ void build_bpq(const float* __restrict__ We1, float* __restrict__ Bpq) {
    int idx = blockIdx.x * blockDim.x + threadIdx.x;
    if (idx < 64 * 128) {
        int k = idx >> 7;
        int j = idx & 127;
        Bpq[idx] = (j < 64) ? We1[k * 64 + j] : We1[(64 + k) * 64 + (j - 64)];
    }
}

// ---------------- edge decode: wave per edge, lane = hidden channel ----------------
__global__ void edge_decode_kernel(const float* __restrict__ PQ, const int* __restrict__ ei,
                                   const float* __restrict__ be1, const float* __restrict__ We2,
                                   const float* __restrict__ be2, float* __restrict__ out) {
    int wid = (blockIdx.x * blockDim.x + threadIdx.x) >> 6;
    int lane = threadIdx.x & 63;
    if (wid >= N_EDGES) return;
    int s = ei[wid], d = ei[N_EDGES + wid];
    float t = PQ[(size_t)s * 128 + lane] + PQ[(size_t)d * 128 + 64 + lane] + be1[lane];
    t = fmaxf(t, 0.f);
    float p[8];
#pragma unroll
    for (int j = 0; j < 8; j++) p[j] = t * We2[lane * 8 + j];
#pragma unroll
    for (int off = 32; off; off >>= 1) {
#pragma unroll
        for (int j = 0; j < 8; j++) p[j] += __shfl_xor(p[j], off, 64);
    }
    if (lane < 8) {
        float v = p[0];
#pragma unroll
        for (int j = 1; j < 8; j++)
            if (lane == j) v = p[j];
        out[(size_t)wid * 8 + lane] = v + be2[lane];
    }
}

extern "C" void kernel_launch(void* const* d_in, const int* in_sizes, int n_in,
                              void* d_out, int out_size, void* d_ws, size_t ws_size,
                              hipStream_t stream) {
    const float* x        = (const float*)d_in[0];
    const int*   ei       = (const int*)d_in[1];
    const float* W1       = (const float*)d_in[2];
    const float* att_src1 = (const float*)d_in[3];
    const float* att_dst1 = (const float*)d_in[4];
    const float* b1       = (const float*)d_in[5];
    const float* W2       = (const float*)d_in[6];
    const float* att_src2 = (const float*)d_in[7];
    const float* att_dst2 = (const float*)d_in[8];
    const float* b2       = (const float*)d_in[9];
    const float* Wn       = (const float*)d_in[10];
    const float* bn       = (const float*)d_in[11];
    const float* We1      = (const float*)d_in[12];
    const float* be1      = (const float*)d_in[13];
    const float* We2      = (const float*)d_in[14];
    const float* be2      = (const float*)d_in[15];

    char* ws = (char*)d_ws;
    size_t off = 0;
    auto alloc = [&](size_t bytes) {
        void* p = ws + off;
        off += (bytes + 255) & ~(size_t)255;
        return p;
    };
    int*   cnt       = (int*)alloc((size_t)N_NODES * 4);
    int*   row_start = (int*)alloc((size_t)(N_NODES + 1) * 4);
    int*   esrc      = (int*)alloc((size_t)N_EDGES * 4);
    float* H1p       = (float*)alloc((size_t)N_NODES * 256 * 4);
    float* as1       = (float*)alloc((size_t)N_NODES * 4 * 4);
    float* ad1       = (float*)alloc((size_t)N_NODES * 4 * 4);
    float* hout      = (float*)alloc((size_t)N_NODES * 256 * 4);
    float* H2        = (float*)alloc((size_t)N_NODES * 64 * 4);
    float* as2       = (float*)alloc((size_t)N_NODES * 4);
    float* ad2       = (float*)alloc((size_t)N_NODES * 4);
    float* z         = (float*)alloc((size_t)N_NODES * 64 * 4);
    float* Bpq       = (float*)alloc((size_t)64 * 128 * 4);
    float* W1p       = (float*)alloc((size_t)128 * 256 * 4);
    float* W2p       = (float*)alloc((size_t)256 * 64 * 4);
    float* asp       = (float*)alloc((size_t)256 * 4);
    float* adp       = (float*)alloc((size_t)256 * 4);
    float* b1p       = (float*)alloc((size_t)256 * 4);
    float* PQ        = H1p;  // H1p dead by the time PQ is produced

    float* recon_x = (float*)d_out;
    float* recon_e = (float*)d_out + (size_t)N_NODES * F_IN;

    // CSR build
    hipMemsetAsync(cnt, 0, (size_t)N_NODES * 4, stream);
    count_kernel<<<(N_EDGES + 255) / 256, 256, 0, stream>>>(ei, cnt);
    scan_kernel<<<1, 1024, 0, stream>>>(cnt, row_start);
    hipMemsetAsync(cnt, 0, (size_t)N_NODES * 4, stream);
    scatter_kernel<<<(N_EDGES + 255) / 256, 256, 0, stream>>>(ei, row_start, cnt, esrc);

    // weight permutes
    permute_w1<<<(128 * 256 + 255) / 256, 256, 0, stream>>>(W1, att_src1, att_dst1, b1,
                                                            W1p, asp, adp, b1p);
    permute_w2<<<(256 * 64 + 255) / 256, 256, 0, stream>>>(W2, W2p);

    // conv1 (head-major layout)
    dim3 g1((N_NODES + 63) / 64, 256 / 64);
    gemm_kernel<false><<<g1, 256, 0, stream>>>(x, W1p, nullptr, H1p, N_NODES, 256, 128);
    att4_kernel<<<(N_NODES * 64 + 255) / 256, 256, 0, stream>>>(H1p, asp, adp,
                                                                (float4*)as1, (float4*)ad1);
    agg4_kernel<<<(N_NODES * 64 + 255) / 256, 256, 0, stream>>>(H1p, (const float4*)as1,
                                                                (const float4*)ad1, row_start,
                                                                esrc, b1p, hout);

    // conv2
    dim3 g2((N_NODES + 63) / 64, 1);
    gemm_kernel<false><<<g2, 256, 0, stream>>>(hout, W2p, nullptr, H2, N_NODES, 64, 256);
    att1_kernel<<<(N_NODES * 64 + 255) / 256, 256, 0, stream>>>(H2, att_src2, att_dst2, as2, ad2);
    agg1_kernel<<<(N_NODES * 64 + 255) / 256, 256, 0, stream>>>(H2, as2, ad2, row_start, esrc, b2, z);

    // node decode
    dim3 g3((N_NODES + 63) / 64, 128 / 64);
    gemm_kernel<true><<<g3, 256, 0, stream>>>(z, Wn, bn, recon_x, N_NODES, 128, 64);

    // edge decode: P|Q precompute then per-edge fuse
    build_bpq<<<(64 * 128 + 255) / 256, 256, 0, stream>>>(We1, Bpq);
    gemm_kernel<false><<<g3, 256, 0, stream>>>(z, Bpq, nullptr, PQ, N_NODES, 128, 64);
    edge_decode_kernel<<<(N_EDGES * 64 + 255) / 256, 256, 0, stream>>>(PQ, ei, be1, We2, be2, recon_e);
}

// Round 3
// 540.052 us; speedup vs baseline: 2.2252x; 1.5779x over previous
//
#include <hip/hip_runtime.h>

#define N_NODES 50000
#define N_EDGES 800000
#define F_IN    128
#define HEADS   4
#define HID     64
#define LAT     64
#define N_EC    8
#define SLOPE   0.2f

__device__ __forceinline__ float lrelu(float x) { return x > 0.f ? x : SLOPE * x; }
__device__ __forceinline__ float4 operator+(float4 a, float4 b) { return make_float4(a.x+b.x, a.y+b.y, a.z+b.z, a.w+b.w); }
__device__ __forceinline__ float4 operator*(float4 a, float4 b) { return make_float4(a.x*b.x, a.y*b.y, a.z*b.z, a.w*b.w); }
__device__ __forceinline__ float4 lrelu4(float4 a) { return make_float4(lrelu(a.x), lrelu(a.y), lrelu(a.z), lrelu(a.w)); }
__device__ __forceinline__ float4 max4(float4 a, float4 b) { return make_float4(fmaxf(a.x,b.x), fmaxf(a.y,b.y), fmaxf(a.z,b.z), fmaxf(a.w,b.w)); }
__device__ __forceinline__ float4 exp4(float4 a) { return make_float4(__expf(a.x), __expf(a.y), __expf(a.z), __expf(a.w)); }
__device__ __forceinline__ float4 fma4(float4 a, float4 b, float4 c) {
    return make_float4(fmaf(a.x,b.x,c.x), fmaf(a.y,b.y,c.y), fmaf(a.z,b.z,c.z), fmaf(a.w,b.w,c.w));
}

// ---------------- CSR build (by dst) ----------------
__global__ void count_kernel(const int* __restrict__ ei, int* __restrict__ cnt) {
    int e = blockIdx.x * blockDim.x + threadIdx.x;
    if (e < N_EDGES) atomicAdd(&cnt[ei[N_EDGES + e]], 1);
}

__global__ __launch_bounds__(1024) void scan_kernel(const int* __restrict__ cnt,
                                                    int* __restrict__ row_start) {
    __shared__ int wsum[16];
    __shared__ int carry;
    int tid = threadIdx.x, lane = tid & 63, w = tid >> 6;
    if (tid == 0) carry = 0;
    __syncthreads();
    for (int base = 0; base < N_NODES; base += 1024) {
        int i = base + tid;
        int v = (i < N_NODES) ? cnt[i] : 0;
        int incl = v;
#pragma unroll
        for (int off = 1; off < 64; off <<= 1) {
            int t = __shfl_up(incl, off, 64);
            if (lane >= off) incl += t;
        }
        if (lane == 63) wsum[w] = incl;
        __syncthreads();
        if (w == 0 && lane < 16) {
            int s = wsum[lane];
            int si = s;
#pragma unroll
            for (int off = 1; off < 16; off <<= 1) {
                int t = __shfl_up(si, off, 64);
                if (lane >= off) si += t;
            }
            wsum[lane] = si - s;  // exclusive prefix of wave sums
        }
        __syncthreads();
        int total_prev = carry;
        if (i < N_NODES) row_start[i] = total_prev + wsum[w] + incl - v;
        __syncthreads();
        if (tid == 1023) carry = total_prev + wsum[15] + incl;
        __syncthreads();
    }
    if (threadIdx.x == 0) row_start[N_NODES] = carry;
}

__global__ void scatter_kernel(const int* __restrict__ ei, const int* __restrict__ row_start,
                               int* __restrict__ cursor, int* __restrict__ esrc) {
    int e = blockIdx.x * blockDim.x + threadIdx.x;
    if (e < N_EDGES) {
        int d = ei[N_EDGES + e];
        int pos = row_start[d] + atomicAdd(&cursor[d], 1);
        esrc[pos] = ei[e];
    }
}

// ---------------- weight permutes for head-major (channel-major-heads) layout ----------------
__global__ void permute_w1(const float* __restrict__ W1, const float* __restrict__ as_,
                           const float* __restrict__ ad_, const float* __restrict__ b1,
                           float* __restrict__ W1p, float* __restrict__ asp,
                           float* __restrict__ adp, float* __restrict__ b1p) {
    int idx = blockIdx.x * blockDim.x + threadIdx.x;
    if (idx < 128 * 256) {
        int k = idx >> 8, j = idx & 255;
        int c = j >> 2, h = j & 3;
        W1p[idx] = W1[k * 256 + h * 64 + c];
    }
    if (idx < 256) {
        int c = idx >> 2, h = idx & 3;
        asp[idx] = as_[h * 64 + c];
        adp[idx] = ad_[h * 64 + c];
        b1p[idx] = b1[h * 64 + c];
    }
}

__global__ void permute_w2(const float* __restrict__ W2, float* __restrict__ W2p) {
    int idx = blockIdx.x * blockDim.x + threadIdx.x;
    if (idx < 256 * 64) {
        int r = idx >> 6, j = idx & 63;
        int c = r >> 2, h = r & 3;
        W2p[idx] = W2[(h * 64 + c) * 64 + j];
    }
}

// ---------------- fp32 tiled GEMM: C[M,N] = A[M,K] @ B[K,N] (+bias) ----------------
template <bool BIAS>
__global__ __launch_bounds__(256) void gemm_kernel(const float* __restrict__ A,
                                                   const float* __restrict__ B,
                                                   const float* __restrict__ bias,
                                                   float* __restrict__ C, int M, int N, int K) {
    __shared__ float As[32][68];  // [k][row]
    __shared__ float Bs[32][68];  // [k][col]
    int tid = threadIdx.x;
    int brow = blockIdx.x * 64;
    int bcol = blockIdx.y * 64;
    int tr = (tid >> 4) * 4;
    int tc = (tid & 15) * 4;
    float acc[4][4] = {};
    for (int k0 = 0; k0 < K; k0 += 32) {
#pragma unroll
        for (int p = 0; p < 2; p++) {
            int idx = tid + p * 256;
            int r = idx >> 3;
            int c4 = (idx & 7) << 2;
            int gr = brow + r;
            float4 v = make_float4(0.f, 0.f, 0.f, 0.f);
            if (gr < M) v = *reinterpret_cast<const float4*>(&A[(size_t)gr * K + k0 + c4]);
            As[c4 + 0][r] = v.x; As[c4 + 1][r] = v.y; As[c4 + 2][r] = v.z; As[c4 + 3][r] = v.w;
        }
#pragma unroll
        for (int p = 0; p < 2; p++) {
            int idx = tid + p * 256;
            int r = idx >> 4;
            int c4 = (idx & 15) << 2;
            float4 v = *reinterpret_cast<const float4*>(&B[(size_t)(k0 + r) * N + bcol + c4]);
            *reinterpret_cast<float4*>(&Bs[r][c4]) = v;
        }
        __syncthreads();
#pragma unroll
        for (int k = 0; k < 32; k++) {
            float4 a = *reinterpret_cast<const float4*>(&As[k][tr]);
            float4 b = *reinterpret_cast<const float4*>(&Bs[k][tc]);
            acc[0][0] += a.x * b.x; acc[0][1] += a.x * b.y; acc[0][2] += a.x * b.z; acc[0][3] += a.x * b.w;
            acc[1][0] += a.y * b.x; acc[1][1] += a.y * b.y; acc[1][2] += a.y * b.z; acc[1][3] += a.y * b.w;
            acc[2][0] += a.z * b.x; acc[2][1] += a.z * b.y; acc[2][2] += a.z * b.z; acc[2][3] += a.z * b.w;
            acc[3][0] += a.w * b.x; acc[3][1] += a.w * b.y; acc[3][2] += a.w * b.z; acc[3][3] += a.w * b.w;
        }
        __syncthreads();
    }
#pragma unroll
    for (int i = 0; i < 4; i++) {
        int gr = brow + tr + i;
        if (gr < M) {
            float4 v;
            v.x = acc[i][0]; v.y = acc[i][1]; v.z = acc[i][2]; v.w = acc[i][3];
            if (BIAS) {
                const float4 bb = *reinterpret_cast<const float4*>(&bias[bcol + tc]);
                v.x += bb.x; v.y += bb.y; v.z += bb.z; v.w += bb.w;
            }
            *reinterpret_cast<float4*>(&C[(size_t)gr * N + bcol + tc]) = v;
        }
    }
}

// ---------------- conv1 attention scalars, head-major: wave per node ----------------
__global__ __launch_bounds__(256) void att4_kernel(const float* __restrict__ H1p,
                                                   const float* __restrict__ asp,
                                                   const float* __restrict__ adp,
                                                   float4* __restrict__ as4,
                                                   float4* __restrict__ ad4) {
    int wid = (blockIdx.x * blockDim.x + threadIdx.x) >> 6;
    int lane = threadIdx.x & 63;
    if (wid >= N_NODES) return;
    float4 v = *reinterpret_cast<const float4*>(&H1p[(size_t)wid * 256 + lane * 4]);
    float4 s = *reinterpret_cast<const float4*>(&asp[lane * 4]);
    float4 d = *reinterpret_cast<const float4*>(&adp[lane * 4]);
    float4 ps = v * s, pd = v * d;
#pragma unroll
    for (int off = 32; off; off >>= 1) {
        ps.x += __shfl_xor(ps.x, off, 64); ps.y += __shfl_xor(ps.y, off, 64);
        ps.z += __shfl_xor(ps.z, off, 64); ps.w += __shfl_xor(ps.w, off, 64);
        pd.x += __shfl_xor(pd.x, off, 64); pd.y += __shfl_xor(pd.y, off, 64);
        pd.z += __shfl_xor(pd.z, off, 64); pd.w += __shfl_xor(pd.w, off, 64);
    }
    if (lane == 0) { as4[wid] = ps; ad4[wid] = pd; }
}

// ---------------- conv1 aggregation: wave per node, all 4 heads, lane=channel ----------------
__global__ __launch_bounds__(256) void agg4_kernel(const float* __restrict__ H1p,
                                                   const float4* __restrict__ as4,
                                                   const float4* __restrict__ ad4,
                                                   const int* __restrict__ row_start,
                                                   const int* __restrict__ esrc,
                                                   const float* __restrict__ b1p,
                                                   float* __restrict__ out) {
    int wid = (blockIdx.x * blockDim.x + threadIdx.x) >> 6;
    int lane = threadIdx.x & 63;
    if (wid >= N_NODES) return;
    int beg = row_start[wid], end = row_start[wid + 1];
    float4 adn = ad4[wid];
    float4 a_self = lrelu4(as4[wid] + adn);
    float4 m = a_self;
    int j = beg;
    for (; j + 3 < end; j += 4) {
        int s0 = esrc[j], s1 = esrc[j + 1], s2 = esrc[j + 2], s3 = esrc[j + 3];
        float4 a0 = as4[s0], a1 = as4[s1], a2 = as4[s2], a3 = as4[s3];
        m = max4(m, lrelu4(a0 + adn));
        m = max4(m, lrelu4(a1 + adn));
        m = max4(m, lrelu4(a2 + adn));
        m = max4(m, lrelu4(a3 + adn));
    }
    for (; j < end; j++) m = max4(m, lrelu4(as4[esrc[j]] + adn));
    float4 mneg = make_float4(-m.x, -m.y, -m.z, -m.w);
    float4 e_self = exp4(a_self + mneg);
    float4 den = e_self;
    float4 vself = *reinterpret_cast<const float4*>(&H1p[(size_t)wid * 256 + lane * 4]);
    float4 acc = e_self * vself;
    j = beg;
    for (; j + 1 < end; j += 2) {
        int s0 = esrc[j], s1 = esrc[j + 1];
        float4 a0 = as4[s0];
        float4 v0 = *reinterpret_cast<const float4*>(&H1p[(size_t)s0 * 256 + lane * 4]);
        float4 a1 = as4[s1];
        float4 v1 = *reinterpret_cast<const float4*>(&H1p[(size_t)s1 * 256 + lane * 4]);
        float4 e0 = exp4(lrelu4(a0 + adn) + mneg);
        float4 e1 = exp4(lrelu4(a1 + adn) + mneg);
        den = den + e0 + e1;
        acc = fma4(e0, v0, acc);
        acc = fma4(e1, v1, acc);
    }
    if (j < end) {
        int s0 = esrc[j];
        float4 a0 = as4[s0];
        float4 v0 = *reinterpret_cast<const float4*>(&H1p[(size_t)s0 * 256 + lane * 4]);
        float4 e0 = exp4(lrelu4(a0 + adn) + mneg);
        den = den + e0;
        acc = fma4(e0, v0, acc);
    }
    const float4 bb = *reinterpret_cast<const float4*>(&b1p[lane * 4]);
    float4 o;
    o.x = fmaxf(acc.x / (den.x + 1e-16f) + bb.x, 0.f);
    o.y = fmaxf(acc.y / (den.y + 1e-16f) + bb.y, 0.f);
    o.z = fmaxf(acc.z / (den.z + 1e-16f) + bb.z, 0.f);
    o.w = fmaxf(acc.w / (den.w + 1e-16f) + bb.w, 0.f);
    *reinterpret_cast<float4*>(&out[(size_t)wid * 256 + lane * 4]) = o;
}

// ---------------- conv2 attention scalars (H=1) ----------------
__global__ __launch_bounds__(256) void att1_kernel(const float* __restrict__ Hf,
                                                   const float* __restrict__ att_src,
                                                   const float* __restrict__ att_dst,
                                                   float* __restrict__ as_,
                                                   float* __restrict__ ad_) {
    int wid = (blockIdx.x * blockDim.x + threadIdx.x) >> 6;
    int lane = threadIdx.x & 63;
    if (wid >= N_NODES) return;
    float v = Hf[(size_t)wid * 64 + lane];
    float ps = v * att_src[lane];
    float pd = v * att_dst[lane];
#pragma unroll
    for (int off = 32; off; off >>= 1) {
        ps += __shfl_xor(ps, off, 64);
        pd += __shfl_xor(pd, off, 64);
    }
    if (lane == 0) { as_[wid] = ps; ad_[wid] = pd; }
}

// ---------------- conv2 aggregation: wave per node, 4 edge-slots x 16 lanes ----------------
__global__ __launch_bounds__(256) void agg1_kernel(const float* __restrict__ Hf,
                                                   const float* __restrict__ as_,
                                                   const float* __restrict__ ad_,
                                                   const int* __restrict__ row_start,
                                                   const int* __restrict__ esrc,
                                                   const float* __restrict__ bias,
                                                   float* __restrict__ out) {
    int wid = (blockIdx.x * blockDim.x + threadIdx.x) >> 6;
    int lane = threadIdx.x & 63;
    if (wid >= N_NODES) return;
    int g = lane >> 4;
    int c16 = lane & 15;
    int beg = row_start[wid], end = row_start[wid + 1];
    float adn = ad_[wid];
    float a_self = lrelu(as_[wid] + adn);
    float m = a_self;
    for (int j = beg + g; j < end; j += 4)
        m = fmaxf(m, lrelu(as_[esrc[j]] + adn));
    m = fmaxf(m, __shfl_xor(m, 16, 64));
    m = fmaxf(m, __shfl_xor(m, 32, 64));
    float4 acc = make_float4(0.f, 0.f, 0.f, 0.f);
    float den = 0.f;
    for (int j = beg + g; j < end; j += 4) {
        int s = esrc[j];
        float e = __expf(lrelu(as_[s] + adn) - m);
        float4 v = *reinterpret_cast<const float4*>(&Hf[(size_t)s * 64 + c16 * 4]);
        den += e;
        acc.x = fmaf(e, v.x, acc.x); acc.y = fmaf(e, v.y, acc.y);
        acc.z = fmaf(e, v.z, acc.z); acc.w = fmaf(e, v.w, acc.w);
    }
    if (g == 0) {
        float e = __expf(a_self - m);
        float4 v = *reinterpret_cast<const float4*>(&Hf[(size_t)wid * 64 + c16 * 4]);
        den += e;
        acc.x = fmaf(e, v.x, acc.x); acc.y = fmaf(e, v.y, acc.y);
        acc.z = fmaf(e, v.z, acc.z); acc.w = fmaf(e, v.w, acc.w);
    }
#pragma unroll
    for (int off = 32; off >= 16; off >>= 1) {
        den += __shfl_xor(den, off, 64);
        acc.x += __shfl_xor(acc.x, off, 64);
        acc.y += __shfl_xor(acc.y, off, 64);
        acc.z += __shfl_xor(acc.z, off, 64);
        acc.w += __shfl_xor(acc.w, off, 64);
    }
    if (g == 0) {
        const float4 bb = *reinterpret_cast<const float4*>(&bias[c16 * 4]);
        float inv = 1.f / (den + 1e-16f);
        float4 o = make_float4(acc.x * inv + bb.x, acc.y * inv + bb.y,
                               acc.z * inv + bb.z, acc.w * inv + bb.w);
        *reinterpret_cast<float4*>(&out[(size_t)wid * 64 + c16 * 4]) = o;
    }
}

// ---------------- build B for PQ GEMM ----------------
__global__ void build_bpq(const float* __restrict__ We1, float* __restrict__ Bpq) {
    int idx = blockIdx.x * blockDim.x + threadIdx.x;
    if (idx < 64 * 128) {
        int k = idx >> 7;
        int j = idx & 127;
        Bpq[idx] = (j < 64) ? We1[k * 64 + j] : We1[(64 + k) * 64 + (j - 64)];
    }
}

// ---------------- edge decode v2: 8 lanes/edge, 8 edges/wave, grid-stride ----------------
// lane = g*8 + l8: edge-slot g in [0,8), channel-block l8 -> channels [l8*8, l8*8+8)
// We2 (64 regs) + be1 (8 regs) loaded once per thread; 3-step butterfly = 3 shfl-instr/edge.
#define ED_BLOCKS 2048
__global__ __launch_bounds__(256) void edge_decode_kernel(const float* __restrict__ PQ,
                                                          const int* __restrict__ ei,
                                                          const float* __restrict__ be1,
                                                          const float* __restrict__ We2,
                                                          const float* __restrict__ be2,
                                                          float* __restrict__ out) {
    int lane = threadIdx.x & 63;
    int g = lane >> 3;          // edge slot within wave
    int l8 = lane & 7;          // channel block
    int c0 = l8 * 8;            // first channel of this lane
    // load weights/bias once
    float w[8][8];
#pragma unroll
    for (int i = 0; i < 8; i++) {
        float4 a = *reinterpret_cast<const float4*>(&We2[(c0 + i) * 8]);
        float4 b = *reinterpret_cast<const float4*>(&We2[(c0 + i) * 8 + 4]);
        w[i][0] = a.x; w[i][1] = a.y; w[i][2] = a.z; w[i][3] = a.w;
        w[i][4] = b.x; w[i][5] = b.y; w[i][6] = b.z; w[i][7] = b.w;
    }
    float4 bia = *reinterpret_cast<const float4*>(&be1[c0]);
    float4 bib = *reinterpret_cast<const float4*>(&be1[c0 + 4]);
    float bout = be2[l8];

    int wgid = (blockIdx.x * blockDim.x + threadIdx.x) >> 6;   // global wave id
    const int nwaves = ED_BLOCKS * 4;                          // 256 threads = 4 waves
    const int ngroups = N_EDGES / 8;
    for (int eg = wgid; eg < ngroups; eg += nwaves) {
        int e = eg * 8 + g;
        int s = ei[e], d = ei[N_EDGES + e];
        const float* Pr = &PQ[(size_t)s * 128 + c0];
        const float* Qr = &PQ[(size_t)d * 128 + 64 + c0];
        float4 pa = *reinterpret_cast<const float4*>(Pr);
        float4 pb = *reinterpret_cast<const float4*>(Pr + 4);
        float4 qa = *reinterpret_cast<const float4*>(Qr);
        float4 qb = *reinterpret_cast<const float4*>(Qr + 4);
        float t[8];
        t[0] = fmaxf(pa.x + qa.x + bia.x, 0.f);
        t[1] = fmaxf(pa.y + qa.y + bia.y, 0.f);
        t[2] = fmaxf(pa.z + qa.z + bia.z, 0.f);
        t[3] = fmaxf(pa.w + qa.w + bia.w, 0.f);
        t[4] = fmaxf(pb.x + qb.x + bib.x, 0.f);
        t[5] = fmaxf(pb.y + qb.y + bib.y, 0.f);
        t[6] = fmaxf(pb.z + qb.z + bib.z, 0.f);
        t[7] = fmaxf(pb.w + qb.w + bib.w, 0.f);
        float p[8] = {};
#pragma unroll
        for (int i = 0; i < 8; i++)
#pragma unroll
            for (int jj = 0; jj < 8; jj++) p[jj] = fmaf(t[i], w[i][jj], p[jj]);
        // reduce across the 8 lanes of this edge group (xor 1,2,4)
#pragma unroll
        for (int off = 1; off <= 4; off <<= 1) {
#pragma unroll
            for (int jj = 0; jj < 8; jj++) p[jj] += __shfl_xor(p[jj], off, 64);
        }
        // lane l8 writes output channel l8 (static select)
        float v = p[0];
        if (l8 == 1) v = p[1];
        else if (l8 == 2) v = p[2];
        else if (l8 == 3) v = p[3];
        else if (l8 == 4) v = p[4];
        else if (l8 == 5) v = p[5];
        else if (l8 == 6) v = p[6];
        else if (l8 == 7) v = p[7];
        out[(size_t)e * 8 + l8] = v + bout;
    }
}

extern "C" void kernel_launch(void* const* d_in, const int* in_sizes, int n_in,
                              void* d_out, int out_size, void* d_ws, size_t ws_size,
                              hipStream_t stream) {
    const float* x        = (const float*)d_in[0];
    const int*   ei       = (const int*)d_in[1];
    const float* W1       = (const float*)d_in[2];
    const float* att_src1 = (const float*)d_in[3];
    const float* att_dst1 = (const float*)d_in[4];
    const float* b1       = (const float*)d_in[5];
    const float* W2       = (const float*)d_in[6];
    const float* att_src2 = (const float*)d_in[7];
    const float* att_dst2 = (const float*)d_in[8];
    const float* b2       = (const float*)d_in[9];
    const float* Wn       = (const float*)d_in[10];
    const float* bn       = (const float*)d_in[11];
    const float* We1      = (const float*)d_in[12];
    const float* be1      = (const float*)d_in[13];
    const float* We2      = (const float*)d_in[14];
    const float* be2      = (const float*)d_in[15];

    char* ws = (char*)d_ws;
    size_t off = 0;
    auto alloc = [&](size_t bytes) {
        void* p = ws + off;
        off += (bytes + 255) & ~(size_t)255;
        return p;
    };
    int*   cnt       = (int*)alloc((size_t)N_NODES * 4);
    int*   row_start = (int*)alloc((size_t)(N_NODES + 1) * 4);
    int*   esrc      = (int*)alloc((size_t)N_EDGES * 4);
    float* H1p       = (float*)alloc((size_t)N_NODES * 256 * 4);
    float* as1       = (float*)alloc((size_t)N_NODES * 4 * 4);
    float* ad1       = (float*)alloc((size_t)N_NODES * 4 * 4);
    float* hout      = (float*)alloc((size_t)N_NODES * 256 * 4);
    float* H2        = (float*)alloc((size_t)N_NODES * 64 * 4);
    float* as2       = (float*)alloc((size_t)N_NODES * 4);
    float* ad2       = (float*)alloc((size_t)N_NODES * 4);
    float* z         = (float*)alloc((size_t)N_NODES * 64 * 4);
    float* Bpq       = (float*)alloc((size_t)64 * 128 * 4);
    float* W1p       = (float*)alloc((size_t)128 * 256 * 4);
    float* W2p       = (float*)alloc((size_t)256 * 64 * 4);
    float* asp       = (float*)alloc((size_t)256 * 4);
    float* adp       = (float*)alloc((size_t)256 * 4);
    float* b1p       = (float*)alloc((size_t)256 * 4);
    float* PQ        = H1p;  // H1p dead by the time PQ is produced

    float* recon_x = (float*)d_out;
    float* recon_e = (float*)d_out + (size_t)N_NODES * F_IN;

    // CSR build
    hipMemsetAsync(cnt, 0, (size_t)N_NODES * 4, stream);
    count_kernel<<<(N_EDGES + 255) / 256, 256, 0, stream>>>(ei, cnt);
    scan_kernel<<<1, 1024, 0, stream>>>(cnt, row_start);
    hipMemsetAsync(cnt, 0, (size_t)N_NODES * 4, stream);
    scatter_kernel<<<(N_EDGES + 255) / 256, 256, 0, stream>>>(ei, row_start, cnt, esrc);

    // weight permutes
    permute_w1<<<(128 * 256 + 255) / 256, 256, 0, stream>>>(W1, att_src1, att_dst1, b1,
                                                            W1p, asp, adp, b1p);
    permute_w2<<<(256 * 64 + 255) / 256, 256, 0, stream>>>(W2, W2p);

    // conv1 (head-major layout)
    dim3 g1((N_NODES + 63) / 64, 256 / 64);
    gemm_kernel<false><<<g1, 256, 0, stream>>>(x, W1p, nullptr, H1p, N_NODES, 256, 128);
    att4_kernel<<<(N_NODES * 64 + 255) / 256, 256, 0, stream>>>(H1p, asp, adp,
                                                                (float4*)as1, (float4*)ad1);
    agg4_kernel<<<(N_NODES * 64 + 255) / 256, 256, 0, stream>>>(H1p, (const float4*)as1,
                                                                (const float4*)ad1, row_start,
                                                                esrc, b1p, hout);

    // conv2
    dim3 g2((N_NODES + 63) / 64, 1);
    gemm_kernel<false><<<g2, 256, 0, stream>>>(hout, W2p, nullptr, H2, N_NODES, 64, 256);
    att1_kernel<<<(N_NODES * 64 + 255) / 256, 256, 0, stream>>>(H2, att_src2, att_dst2, as2, ad2);
    agg1_kernel<<<(N_NODES * 64 + 255) / 256, 256, 0, stream>>>(H2, as2, ad2, row_start, esrc, b2, z);

    // node decode
    dim3 g3((N_NODES + 63) / 64, 128 / 64);
    gemm_kernel<true><<<g3, 256, 0, stream>>>(z, Wn, bn, recon_x, N_NODES, 128, 64);

    // edge decode: P|Q precompute then per-edge fuse
    build_bpq<<<(64 * 128 + 255) / 256, 256, 0, stream>>>(We1, Bpq);
    gemm_kernel<false><<<g3, 256, 0, stream>>>(z, Bpq, nullptr, PQ, N_NODES, 128, 64);
    edge_decode_kernel<<<ED_BLOCKS, 256, 0, stream>>>(PQ, ei, be1, We2, be2, recon_e);
}

// Round 4
// 532.563 us; speedup vs baseline: 2.2565x; 1.0141x over previous
//
#include <hip/hip_runtime.h>

#define N_NODES 50000
#define N_EDGES 800000
#define F_IN    128
#define HEADS   4
#define HID     64
#define LAT     64
#define N_EC    8
#define SLOPE   0.2f

__device__ __forceinline__ float lrelu(float x) { return x > 0.f ? x : SLOPE * x; }
__device__ __forceinline__ float4 operator+(float4 a, float4 b) { return make_float4(a.x+b.x, a.y+b.y, a.z+b.z, a.w+b.w); }
__device__ __forceinline__ float4 operator*(float4 a, float4 b) { return make_float4(a.x*b.x, a.y*b.y, a.z*b.z, a.w*b.w); }
__device__ __forceinline__ float4 lrelu4(float4 a) { return make_float4(lrelu(a.x), lrelu(a.y), lrelu(a.z), lrelu(a.w)); }
__device__ __forceinline__ float4 max4(float4 a, float4 b) { return make_float4(fmaxf(a.x,b.x), fmaxf(a.y,b.y), fmaxf(a.z,b.z), fmaxf(a.w,b.w)); }
__device__ __forceinline__ float4 exp4(float4 a) { return make_float4(__expf(a.x), __expf(a.y), __expf(a.z), __expf(a.w)); }

// ---------------- CSR build (by dst) ----------------
__global__ void count_kernel(const int* __restrict__ ei, int* __restrict__ cnt) {
    int e = blockIdx.x * blockDim.x + threadIdx.x;
    if (e < N_EDGES) atomicAdd(&cnt[ei[N_EDGES + e]], 1);
}

__global__ __launch_bounds__(1024) void scan_kernel(const int* __restrict__ cnt,
                                                    int* __restrict__ row_start) {
    __shared__ int wsum[16];
    __shared__ int carry;
    int tid = threadIdx.x, lane = tid & 63, w = tid >> 6;
    if (tid == 0) carry = 0;
    __syncthreads();
    for (int base = 0; base < N_NODES; base += 1024) {
        int i = base + tid;
        int v = (i < N_NODES) ? cnt[i] : 0;
        int incl = v;
#pragma unroll
        for (int off = 1; off < 64; off <<= 1) {
            int t = __shfl_up(incl, off, 64);
            if (lane >= off) incl += t;
        }
        if (lane == 63) wsum[w] = incl;
        __syncthreads();
        if (w == 0 && lane < 16) {
            int s = wsum[lane];
            int si = s;
#pragma unroll
            for (int off = 1; off < 16; off <<= 1) {
                int t = __shfl_up(si, off, 64);
                if (lane >= off) si += t;
            }
            wsum[lane] = si - s;  // exclusive prefix of wave sums
        }
        __syncthreads();
        int total_prev = carry;
        if (i < N_NODES) row_start[i] = total_prev + wsum[w] + incl - v;
        __syncthreads();
        if (tid == 1023) carry = total_prev + wsum[15] + incl;
        __syncthreads();
    }
    if (threadIdx.x == 0) row_start[N_NODES] = carry;
}

// scatter also records dst and original edge id so edge_decode can run in CSR order
__global__ void scatter_kernel(const int* __restrict__ ei, const int* __restrict__ row_start,
                               int* __restrict__ cursor, int* __restrict__ esrc,
                               int* __restrict__ edst, int* __restrict__ eorig) {
    int e = blockIdx.x * blockDim.x + threadIdx.x;
    if (e < N_EDGES) {
        int d = ei[N_EDGES + e];
        int pos = row_start[d] + atomicAdd(&cursor[d], 1);
        esrc[pos] = ei[e];
        edst[pos] = d;
        eorig[pos] = e;
    }
}

// ---------------- weight permutes for head-major (channel-major-heads) layout ----------------
__global__ void permute_w1(const float* __restrict__ W1, const float* __restrict__ as_,
                           const float* __restrict__ ad_, const float* __restrict__ b1,
                           float* __restrict__ W1p, float* __restrict__ asp,
                           float* __restrict__ adp, float* __restrict__ b1p) {
    int idx = blockIdx.x * blockDim.x + threadIdx.x;
    if (idx < 128 * 256) {
        int k = idx >> 8, j = idx & 255;
        int c = j >> 2, h = j & 3;
        W1p[idx] = W1[k * 256 + h * 64 + c];
    }
    if (idx < 256) {
        int c = idx >> 2, h = idx & 3;
        asp[idx] = as_[h * 64 + c];
        adp[idx] = ad_[h * 64 + c];
        b1p[idx] = b1[h * 64 + c];
    }
}

__global__ void permute_w2(const float* __restrict__ W2, float* __restrict__ W2p) {
    int idx = blockIdx.x * blockDim.x + threadIdx.x;
    if (idx < 256 * 64) {
        int r = idx >> 6, j = idx & 63;
        int c = r >> 2, h = r & 3;
        W2p[idx] = W2[(h * 64 + c) * 64 + j];
    }
}

// ---------------- fp32 tiled GEMM: C[M,N] = A[M,K] @ B[K,N] (+bias) ----------------
template <bool BIAS>
__global__ __launch_bounds__(256) void gemm_kernel(const float* __restrict__ A,
                                                   const float* __restrict__ B,
                                                   const float* __restrict__ bias,
                                                   float* __restrict__ C, int M, int N, int K) {
    __shared__ float As[32][68];  // [k][row]
    __shared__ float Bs[32][68];  // [k][col]
    int tid = threadIdx.x;
    int brow = blockIdx.x * 64;
    int bcol = blockIdx.y * 64;
    int tr = (tid >> 4) * 4;
    int tc = (tid & 15) * 4;
    float acc[4][4] = {};
    for (int k0 = 0; k0 < K; k0 += 32) {
#pragma unroll
        for (int p = 0; p < 2; p++) {
            int idx = tid + p * 256;
            int r = idx >> 3;
            int c4 = (idx & 7) << 2;
            int gr = brow + r;
            float4 v = make_float4(0.f, 0.f, 0.f, 0.f);
            if (gr < M) v = *reinterpret_cast<const float4*>(&A[(size_t)gr * K + k0 + c4]);
            As[c4 + 0][r] = v.x; As[c4 + 1][r] = v.y; As[c4 + 2][r] = v.z; As[c4 + 3][r] = v.w;
        }
#pragma unroll
        for (int p = 0; p < 2; p++) {
            int idx = tid + p * 256;
            int r = idx >> 4;
            int c4 = (idx & 15) << 2;
            float4 v = *reinterpret_cast<const float4*>(&B[(size_t)(k0 + r) * N + bcol + c4]);
            *reinterpret_cast<float4*>(&Bs[r][c4]) = v;
        }
        __syncthreads();
#pragma unroll
        for (int k = 0; k < 32; k++) {
            float4 a = *reinterpret_cast<const float4*>(&As[k][tr]);
            float4 b = *reinterpret_cast<const float4*>(&Bs[k][tc]);
            acc[0][0] += a.x * b.x; acc[0][1] += a.x * b.y; acc[0][2] += a.x * b.z; acc[0][3] += a.x * b.w;
            acc[1][0] += a.y * b.x; acc[1][1] += a.y * b.y; acc[1][2] += a.y * b.z; acc[1][3] += a.y * b.w;
            acc[2][0] += a.z * b.x; acc[2][1] += a.z * b.y; acc[2][2] += a.z * b.z; acc[2][3] += a.z * b.w;
            acc[3][0] += a.w * b.x; acc[3][1] += a.w * b.y; acc[3][2] += a.w * b.z; acc[3][3] += a.w * b.w;
        }
        __syncthreads();
    }
#pragma unroll
    for (int i = 0; i < 4; i++) {
        int gr = brow + tr + i;
        if (gr < M) {
            float4 v;
            v.x = acc[i][0]; v.y = acc[i][1]; v.z = acc[i][2]; v.w = acc[i][3];
            if (BIAS) {
                const float4 bb = *reinterpret_cast<const float4*>(&bias[bcol + tc]);
                v.x += bb.x; v.y += bb.y; v.z += bb.z; v.w += bb.w;
            }
            *reinterpret_cast<float4*>(&C[(size_t)gr * N + bcol + tc]) = v;
        }
    }
}

// ---------------- conv1 attention scalars, head-major: wave per node ----------------
__global__ __launch_bounds__(256) void att4_kernel(const float* __restrict__ H1p,
                                                   const float* __restrict__ asp,
                                                   const float* __restrict__ adp,
                                                   float4* __restrict__ as4,
                                                   float4* __restrict__ ad4) {
    int wid = (blockIdx.x * blockDim.x + threadIdx.x) >> 6;
    int lane = threadIdx.x & 63;
    if (wid >= N_NODES) return;
    float4 v = *reinterpret_cast<const float4*>(&H1p[(size_t)wid * 256 + lane * 4]);
    float4 s = *reinterpret_cast<const float4*>(&asp[lane * 4]);
    float4 d = *reinterpret_cast<const float4*>(&adp[lane * 4]);
    float4 ps = v * s, pd = v * d;
#pragma unroll
    for (int off = 32; off; off >>= 1) {
        ps.x += __shfl_xor(ps.x, off, 64); ps.y += __shfl_xor(ps.y, off, 64);
        ps.z += __shfl_xor(ps.z, off, 64); ps.w += __shfl_xor(ps.w, off, 64);
        pd.x += __shfl_xor(pd.x, off, 64); pd.y += __shfl_xor(pd.y, off, 64);
        pd.z += __shfl_xor(pd.z, off, 64); pd.w += __shfl_xor(pd.w, off, 64);
    }
    if (lane == 0) { as4[wid] = ps; ad4[wid] = pd; }
}

// ---------------- conv1 aggregation v2: wave per node; per-edge alpha computed ONCE,
// broadcast to lanes via uniform-shfl (v_readlane); lanes = channelx4 in phase 3 ----------------
__global__ __launch_bounds__(256) void agg4_kernel(const float* __restrict__ H1p,
                                                   const float4* __restrict__ as4,
                                                   const float4* __restrict__ ad4,
                                                   const int* __restrict__ row_start,
                                                   const int* __restrict__ esrc,
                                                   const float* __restrict__ b1p,
                                                   float* __restrict__ out) {
    int wid = (blockIdx.x * blockDim.x + threadIdx.x) >> 6;
    int lane = threadIdx.x & 63;
    if (wid >= N_NODES) return;
    int beg = row_start[wid], end = row_start[wid + 1];
    float4 adn = ad4[wid];
    float4 a_self = lrelu4(as4[wid] + adn);
    // pass 1: segment max, lanes strided over edges
    float4 lm = make_float4(-1e30f, -1e30f, -1e30f, -1e30f);
    for (int j = beg + lane; j < end; j += 64) {
        int s = esrc[j];
        lm = max4(lm, lrelu4(as4[s] + adn));
    }
#pragma unroll
    for (int off = 32; off; off >>= 1) {
        lm.x = fmaxf(lm.x, __shfl_xor(lm.x, off, 64));
        lm.y = fmaxf(lm.y, __shfl_xor(lm.y, off, 64));
        lm.z = fmaxf(lm.z, __shfl_xor(lm.z, off, 64));
        lm.w = fmaxf(lm.w, __shfl_xor(lm.w, off, 64));
    }
    float4 m = max4(lm, a_self);
    float4 mneg = make_float4(-m.x, -m.y, -m.z, -m.w);
    float4 e_self = exp4(a_self + mneg);
    float4 den = e_self;                 // identical in all lanes throughout
    float4 vself = *reinterpret_cast<const float4*>(&H1p[(size_t)wid * 256 + lane * 4]);
    float4 acc = e_self * vself;
    // chunks of 64 edges: each lane computes one edge's alpha, then broadcast
    for (int c0 = beg; c0 < end; c0 += 64) {
        int clen = min(64, end - c0);
        int s = 0;
        float4 e = make_float4(0.f, 0.f, 0.f, 0.f);
        if (lane < clen) {
            s = esrc[c0 + lane];
            e = exp4(lrelu4(as4[s] + adn) + mneg);
        }
#pragma unroll 2
        for (int j = 0; j < clen; j++) {
            int sj = __shfl(s, j, 64);           // uniform src lane -> v_readlane (SGPR)
            float ex = __shfl(e.x, j, 64);
            float ey = __shfl(e.y, j, 64);
            float ez = __shfl(e.z, j, 64);
            float ew = __shfl(e.w, j, 64);
            float4 hv = *reinterpret_cast<const float4*>(&H1p[(size_t)sj * 256 + lane * 4]);
            acc.x = fmaf(ex, hv.x, acc.x);
            acc.y = fmaf(ey, hv.y, acc.y);
            acc.z = fmaf(ez, hv.z, acc.z);
            acc.w = fmaf(ew, hv.w, acc.w);
            den.x += ex; den.y += ey; den.z += ez; den.w += ew;
        }
    }
    const float4 bb = *reinterpret_cast<const float4*>(&b1p[lane * 4]);
    float4 o;
    o.x = fmaxf(acc.x / (den.x + 1e-16f) + bb.x, 0.f);
    o.y = fmaxf(acc.y / (den.y + 1e-16f) + bb.y, 0.f);
    o.z = fmaxf(acc.z / (den.z + 1e-16f) + bb.z, 0.f);
    o.w = fmaxf(acc.w / (den.w + 1e-16f) + bb.w, 0.f);
    *reinterpret_cast<float4*>(&out[(size_t)wid * 256 + lane * 4]) = o;
}

// ---------------- conv2 attention scalars (H=1) ----------------
__global__ __launch_bounds__(256) void att1_kernel(const float* __restrict__ Hf,
                                                   const float* __restrict__ att_src,
                                                   const float* __restrict__ att_dst,
                                                   float* __restrict__ as_,
                                                   float* __restrict__ ad_) {
    int wid = (blockIdx.x * blockDim.x + threadIdx.x) >> 6;
    int lane = threadIdx.x & 63;
    if (wid >= N_NODES) return;
    float v = Hf[(size_t)wid * 64 + lane];
    float ps = v * att_src[lane];
    float pd = v * att_dst[lane];
#pragma unroll
    for (int off = 32; off; off >>= 1) {
        ps += __shfl_xor(ps, off, 64);
        pd += __shfl_xor(pd, off, 64);
    }
    if (lane == 0) { as_[wid] = ps; ad_[wid] = pd; }
}

// ---------------- conv2 aggregation v2: same structure, H=1, lane = channel ----------------
__global__ __launch_bounds__(256) void agg1_kernel(const float* __restrict__ Hf,
                                                   const float* __restrict__ as_,
                                                   const float* __restrict__ ad_,
                                                   const int* __restrict__ row_start,
                                                   const int* __restrict__ esrc,
                                                   const float* __restrict__ bias,
                                                   float* __restrict__ out) {
    int wid = (blockIdx.x * blockDim.x + threadIdx.x) >> 6;
    int lane = threadIdx.x & 63;
    if (wid >= N_NODES) return;
    int beg = row_start[wid], end = row_start[wid + 1];
    float adn = ad_[wid];
    float a_self = lrelu(as_[wid] + adn);
    float lm = -1e30f;
    for (int j = beg + lane; j < end; j += 64)
        lm = fmaxf(lm, lrelu(as_[esrc[j]] + adn));
#pragma unroll
    for (int off = 32; off; off >>= 1)
        lm = fmaxf(lm, __shfl_xor(lm, off, 64));
    float m = fmaxf(lm, a_self);
    float e_self = __expf(a_self - m);
    float den = e_self;
    float acc = e_self * Hf[(size_t)wid * 64 + lane];
    for (int c0 = beg; c0 < end; c0 += 64) {
        int clen = min(64, end - c0);
        int s = 0;
        float e = 0.f;
        if (lane < clen) {
            s = esrc[c0 + lane];
            e = __expf(lrelu(as_[s] + adn) - m);
        }
#pragma unroll 4
        for (int j = 0; j < clen; j++) {
            int sj = __shfl(s, j, 64);
            float ej = __shfl(e, j, 64);
            acc = fmaf(ej, Hf[(size_t)sj * 64 + lane], acc);
            den += ej;
        }
    }
    out[(size_t)wid * 64 + lane] = acc / (den + 1e-16f) + bias[lane];
}

// ---------------- build B for PQ GEMM ----------------
__global__ void build_bpq(const float* __restrict__ We1, float* __restrict__ Bpq) {
    int idx = blockIdx.x * blockDim.x + threadIdx.x;
    if (idx < 64 * 128) {
        int k = idx >> 7;
        int j = idx & 127;
        Bpq[idx] = (j < 64) ? We1[k * 64 + j] : We1[(64 + k) * 64 + (j - 64)];
    }
}

// ---------------- edge decode v3: CSR(dst)-ordered for Q-row L1 reuse ----------------
// 8 lanes/edge, 8 edges/wave; consecutive CSR positions share dst -> Q[d] stays in L1.
#define ED_BLOCKS 2048
__global__ __launch_bounds__(256) void edge_decode_kernel(const float* __restrict__ PQ,
                                                          const int* __restrict__ esrc,
                                                          const int* __restrict__ edst,
                                                          const int* __restrict__ eorig,
                                                          const float* __restrict__ be1,
                                                          const float* __restrict__ We2,
                                                          const float* __restrict__ be2,
                                                          float* __restrict__ out) {
    int lane = threadIdx.x & 63;
    int g = lane >> 3;          // edge slot within wave
    int l8 = lane & 7;          // channel block
    int c0 = l8 * 8;
    float w[8][8];
#pragma unroll
    for (int i = 0; i < 8; i++) {
        float4 a = *reinterpret_cast<const float4*>(&We2[(c0 + i) * 8]);
        float4 b = *reinterpret_cast<const float4*>(&We2[(c0 + i) * 8 + 4]);
        w[i][0] = a.x; w[i][1] = a.y; w[i][2] = a.z; w[i][3] = a.w;
        w[i][4] = b.x; w[i][5] = b.y; w[i][6] = b.z; w[i][7] = b.w;
    }
    float4 bia = *reinterpret_cast<const float4*>(&be1[c0]);
    float4 bib = *reinterpret_cast<const float4*>(&be1[c0 + 4]);
    float bout = be2[l8];

    int wgid = (blockIdx.x * blockDim.x + threadIdx.x) >> 6;
    const int nwaves = ED_BLOCKS * 4;
    const int ngroups = N_EDGES / 8;
    for (int eg = wgid; eg < ngroups; eg += nwaves) {
        int p = eg * 8 + g;
        int s = esrc[p], d = edst[p], o = eorig[p];
        const float* Pr = &PQ[(size_t)s * 128 + c0];
        const float* Qr = &PQ[(size_t)d * 128 + 64 + c0];
        float4 pa = *reinterpret_cast<const float4*>(Pr);
        float4 pb = *reinterpret_cast<const float4*>(Pr + 4);
        float4 qa = *reinterpret_cast<const float4*>(Qr);
        float4 qb = *reinterpret_cast<const float4*>(Qr + 4);
        float t[8];
        t[0] = fmaxf(pa.x + qa.x + bia.x, 0.f);
        t[1] = fmaxf(pa.y + qa.y + bia.y, 0.f);
        t[2] = fmaxf(pa.z + qa.z + bia.z, 0.f);
        t[3] = fmaxf(pa.w + qa.w + bia.w, 0.f);
        t[4] = fmaxf(pb.x + qb.x + bib.x, 0.f);
        t[5] = fmaxf(pb.y + qb.y + bib.y, 0.f);
        t[6] = fmaxf(pb.z + qb.z + bib.z, 0.f);
        t[7] = fmaxf(pb.w + qb.w + bib.w, 0.f);
        float p8[8] = {};
#pragma unroll
        for (int i = 0; i < 8; i++)
#pragma unroll
            for (int jj = 0; jj < 8; jj++) p8[jj] = fmaf(t[i], w[i][jj], p8[jj]);
#pragma unroll
        for (int off = 1; off <= 4; off <<= 1) {
#pragma unroll
            for (int jj = 0; jj < 8; jj++) p8[jj] += __shfl_xor(p8[jj], off, 64);
        }
        float v = p8[0];
        if (l8 == 1) v = p8[1];
        else if (l8 == 2) v = p8[2];
        else if (l8 == 3) v = p8[3];
        else if (l8 == 4) v = p8[4];
        else if (l8 == 5) v = p8[5];
        else if (l8 == 6) v = p8[6];
        else if (l8 == 7) v = p8[7];
        out[(size_t)o * 8 + l8] = v + bout;
    }
}

extern "C" void kernel_launch(void* const* d_in, const int* in_sizes, int n_in,
                              void* d_out, int out_size, void* d_ws, size_t ws_size,
                              hipStream_t stream) {
    const float* x        = (const float*)d_in[0];
    const int*   ei       = (const int*)d_in[1];
    const float* W1       = (const float*)d_in[2];
    const float* att_src1 = (const float*)d_in[3];
    const float* att_dst1 = (const float*)d_in[4];
    const float* b1       = (const float*)d_in[5];
    const float* W2       = (const float*)d_in[6];
    const float* att_src2 = (const float*)d_in[7];
    const float* att_dst2 = (const float*)d_in[8];
    const float* b2       = (const float*)d_in[9];
    const float* Wn       = (const float*)d_in[10];
    const float* bn       = (const float*)d_in[11];
    const float* We1      = (const float*)d_in[12];
    const float* be1      = (const float*)d_in[13];
    const float* We2      = (const float*)d_in[14];
    const float* be2      = (const float*)d_in[15];

    char* ws = (char*)d_ws;
    size_t off = 0;
    auto alloc = [&](size_t bytes) {
        void* p = ws + off;
        off += (bytes + 255) & ~(size_t)255;
        return p;
    };
    int*   cnt       = (int*)alloc((size_t)N_NODES * 4);
    int*   row_start = (int*)alloc((size_t)(N_NODES + 1) * 4);
    int*   esrc      = (int*)alloc((size_t)N_EDGES * 4);
    int*   edst      = (int*)alloc((size_t)N_EDGES * 4);
    int*   eorig     = (int*)alloc((size_t)N_EDGES * 4);
    float* H1p       = (float*)alloc((size_t)N_NODES * 256 * 4);
    float* as1       = (float*)alloc((size_t)N_NODES * 4 * 4);
    float* ad1       = (float*)alloc((size_t)N_NODES * 4 * 4);
    float* hout      = (float*)alloc((size_t)N_NODES * 256 * 4);
    float* H2        = (float*)alloc((size_t)N_NODES * 64 * 4);
    float* as2       = (float*)alloc((size_t)N_NODES * 4);
    float* ad2       = (float*)alloc((size_t)N_NODES * 4);
    float* z         = (float*)alloc((size_t)N_NODES * 64 * 4);
    float* Bpq       = (float*)alloc((size_t)64 * 128 * 4);
    float* W1p       = (float*)alloc((size_t)128 * 256 * 4);
    float* W2p       = (float*)alloc((size_t)256 * 64 * 4);
    float* asp       = (float*)alloc((size_t)256 * 4);
    float* adp       = (float*)alloc((size_t)256 * 4);
    float* b1p       = (float*)alloc((size_t)256 * 4);
    float* PQ        = H1p;  // H1p dead by the time PQ is produced

    float* recon_x = (float*)d_out;
    float* recon_e = (float*)d_out + (size_t)N_NODES * F_IN;

    // CSR build
    hipMemsetAsync(cnt, 0, (size_t)N_NODES * 4, stream);
    count_kernel<<<(N_EDGES + 255) / 256, 256, 0, stream>>>(ei, cnt);
    scan_kernel<<<1, 1024, 0, stream>>>(cnt, row_start);
    hipMemsetAsync(cnt, 0, (size_t)N_NODES * 4, stream);
    scatter_kernel<<<(N_EDGES + 255) / 256, 256, 0, stream>>>(ei, row_start, cnt,
                                                              esrc, edst, eorig);

    // weight permutes
    permute_w1<<<(128 * 256 + 255) / 256, 256, 0, stream>>>(W1, att_src1, att_dst1, b1,
                                                            W1p, asp, adp, b1p);
    permute_w2<<<(256 * 64 + 255) / 256, 256, 0, stream>>>(W2, W2p);

    // conv1 (head-major layout)
    dim3 g1((N_NODES + 63) / 64, 256 / 64);
    gemm_kernel<false><<<g1, 256, 0, stream>>>(x, W1p, nullptr, H1p, N_NODES, 256, 128);
    att4_kernel<<<(N_NODES * 64 + 255) / 256, 256, 0, stream>>>(H1p, asp, adp,
                                                                (float4*)as1, (float4*)ad1);
    agg4_kernel<<<(N_NODES * 64 + 255) / 256, 256, 0, stream>>>(H1p, (const float4*)as1,
                                                                (const float4*)ad1, row_start,
                                                                esrc, b1p, hout);

    // conv2
    dim3 g2((N_NODES + 63) / 64, 1);
    gemm_kernel<false><<<g2, 256, 0, stream>>>(hout, W2p, nullptr, H2, N_NODES, 64, 256);
    att1_kernel<<<(N_NODES * 64 + 255) / 256, 256, 0, stream>>>(H2, att_src2, att_dst2, as2, ad2);
    agg1_kernel<<<(N_NODES * 64 + 255) / 256, 256, 0, stream>>>(H2, as2, ad2, row_start, esrc, b2, z);

    // node decode
    dim3 g3((N_NODES + 63) / 64, 128 / 64);
    gemm_kernel<true><<<g3, 256, 0, stream>>>(z, Wn, bn, recon_x, N_NODES, 128, 64);

    // edge decode: P|Q precompute then per-edge fuse (CSR order)
    build_bpq<<<(64 * 128 + 255) / 256, 256, 0, stream>>>(We1, Bpq);
    gemm_kernel<false><<<g3, 256, 0, stream>>>(z, Bpq, nullptr, PQ, N_NODES, 128, 64);
    edge_decode_kernel<<<ED_BLOCKS, 256, 0, stream>>>(PQ, esrc, edst, eorig, be1, We2, be2, recon_e);
}

// Round 5
// 491.308 us; speedup vs baseline: 2.4460x; 1.0840x over previous
//
#include <hip/hip_runtime.h>

#define N_NODES 50000
#define N_EDGES 800000
#define F_IN    128
#define HEADS   4
#define HID     64
#define LAT     64
#define N_EC    8
#define SLOPE   0.2f
#define PLANE   ((size_t)N_NODES * 128)   // one head's xagg plane (elements)

__device__ __forceinline__ float lrelu(float x) { return x > 0.f ? x : SLOPE * x; }
__device__ __forceinline__ float4 operator+(float4 a, float4 b) { return make_float4(a.x+b.x, a.y+b.y, a.z+b.z, a.w+b.w); }
__device__ __forceinline__ float4 lrelu4(float4 a) { return make_float4(lrelu(a.x), lrelu(a.y), lrelu(a.z), lrelu(a.w)); }
__device__ __forceinline__ float4 max4(float4 a, float4 b) { return make_float4(fmaxf(a.x,b.x), fmaxf(a.y,b.y), fmaxf(a.z,b.z), fmaxf(a.w,b.w)); }
__device__ __forceinline__ float4 exp4(float4 a) { return make_float4(__expf(a.x), __expf(a.y), __expf(a.z), __expf(a.w)); }

// ---------------- CSR build (by dst) ----------------
__global__ void count_kernel(const int* __restrict__ ei, int* __restrict__ cnt) {
    int e = blockIdx.x * blockDim.x + threadIdx.x;
    if (e < N_EDGES) atomicAdd(&cnt[ei[N_EDGES + e]], 1);
}

__global__ __launch_bounds__(1024) void scan_kernel(const int* __restrict__ cnt,
                                                    int* __restrict__ row_start) {
    __shared__ int wsum[16];
    __shared__ int carry;
    int tid = threadIdx.x, lane = tid & 63, w = tid >> 6;
    if (tid == 0) carry = 0;
    __syncthreads();
    for (int base = 0; base < N_NODES; base += 1024) {
        int i = base + tid;
        int v = (i < N_NODES) ? cnt[i] : 0;
        int incl = v;
#pragma unroll
        for (int off = 1; off < 64; off <<= 1) {
            int t = __shfl_up(incl, off, 64);
            if (lane >= off) incl += t;
        }
        if (lane == 63) wsum[w] = incl;
        __syncthreads();
        if (w == 0 && lane < 16) {
            int s = wsum[lane];
            int si = s;
#pragma unroll
            for (int off = 1; off < 16; off <<= 1) {
                int t = __shfl_up(si, off, 64);
                if (lane >= off) si += t;
            }
            wsum[lane] = si - s;  // exclusive prefix of wave sums
        }
        __syncthreads();
        int total_prev = carry;
        if (i < N_NODES) row_start[i] = total_prev + wsum[w] + incl - v;
        __syncthreads();
        if (tid == 1023) carry = total_prev + wsum[15] + incl;
        __syncthreads();
    }
    if (threadIdx.x == 0) row_start[N_NODES] = carry;
}

__global__ void scatter_kernel(const int* __restrict__ ei, const int* __restrict__ row_start,
                               int* __restrict__ cursor, int* __restrict__ esrc,
                               int* __restrict__ edst, int* __restrict__ eorig) {
    int e = blockIdx.x * blockDim.x + threadIdx.x;
    if (e < N_EDGES) {
        int d = ei[N_EDGES + e];
        int pos = row_start[d] + atomicAdd(&cursor[d], 1);
        esrc[pos] = ei[e];
        edst[pos] = d;
        eorig[pos] = e;
    }
}

// ---------------- watt[k][j] = sum_c W1[k][h*64+c] * att_{src|dst}[h][c], j=h (src) / h+4 (dst) ----------------
__global__ void watt_kernel(const float* __restrict__ W1, const float* __restrict__ as_,
                            const float* __restrict__ ad_, float* __restrict__ watt) {
    int idx = blockIdx.x * blockDim.x + threadIdx.x;
    if (idx >= 128 * 8) return;
    int k = idx >> 3, j = idx & 7;
    int h = j & 3;
    const float* av = (j < 4) ? as_ : ad_;
    float sum = 0.f;
    for (int c = 0; c < 64; c++) sum += W1[k * 256 + h * 64 + c] * av[h * 64 + c];
    watt[k * 8 + j] = sum;
}

// ---------------- attention scalars from x: wave per node, 8 outputs ----------------
__global__ __launch_bounds__(256) void asad_kernel(const float* __restrict__ x,
                                                   const float* __restrict__ watt,
                                                   float4* __restrict__ as4,
                                                   float4* __restrict__ ad4) {
    int wid = (blockIdx.x * blockDim.x + threadIdx.x) >> 6;
    int lane = threadIdx.x & 63;
    if (wid >= N_NODES) return;
    float2 xv = *reinterpret_cast<const float2*>(&x[(size_t)wid * 128 + lane * 2]);
    float p[8];
    const float* w0 = &watt[(2 * lane) * 8];
    const float* w1 = &watt[(2 * lane + 1) * 8];
#pragma unroll
    for (int j = 0; j < 8; j++) p[j] = fmaf(xv.x, w0[j], xv.y * w1[j]);
#pragma unroll
    for (int off = 32; off; off >>= 1)
#pragma unroll
        for (int j = 0; j < 8; j++) p[j] += __shfl_xor(p[j], off, 64);
    if (lane == 0) {
        as4[wid] = make_float4(p[0], p[1], p[2], p[3]);
        ad4[wid] = make_float4(p[4], p[5], p[6], p[7]);
    }
}

// ---------------- conv1 aggregation in x-domain: wave per node, gathers 512B x-rows ----------------
// xagg[h][n][:] = (e_self*x[n] + sum_e e[h]*x[src]) / den[h]; conv1 GEMM applies W1_h after.
__global__ __launch_bounds__(256) void agg4x_kernel(const float* __restrict__ x,
                                                    const float4* __restrict__ as4,
                                                    const float4* __restrict__ ad4,
                                                    const int* __restrict__ row_start,
                                                    const int* __restrict__ esrc,
                                                    float* __restrict__ xagg) {
    int wid = (blockIdx.x * blockDim.x + threadIdx.x) >> 6;
    int lane = threadIdx.x & 63;
    if (wid >= N_NODES) return;
    int beg = row_start[wid], end = row_start[wid + 1];
    float4 adn = ad4[wid];
    float4 a_self = lrelu4(as4[wid] + adn);
    // pass 1: segment max
    float4 lm = make_float4(-1e30f, -1e30f, -1e30f, -1e30f);
    for (int j = beg + lane; j < end; j += 64)
        lm = max4(lm, lrelu4(as4[esrc[j]] + adn));
#pragma unroll
    for (int off = 32; off; off >>= 1) {
        lm.x = fmaxf(lm.x, __shfl_xor(lm.x, off, 64));
        lm.y = fmaxf(lm.y, __shfl_xor(lm.y, off, 64));
        lm.z = fmaxf(lm.z, __shfl_xor(lm.z, off, 64));
        lm.w = fmaxf(lm.w, __shfl_xor(lm.w, off, 64));
    }
    float4 m = max4(lm, a_self);
    float4 mneg = make_float4(-m.x, -m.y, -m.z, -m.w);
    float4 e_self = exp4(a_self + mneg);
    float4 den = e_self;
    float2 xv = *reinterpret_cast<const float2*>(&x[(size_t)wid * 128 + lane * 2]);
    float2 acc0 = make_float2(e_self.x * xv.x, e_self.x * xv.y);
    float2 acc1 = make_float2(e_self.y * xv.x, e_self.y * xv.y);
    float2 acc2 = make_float2(e_self.z * xv.x, e_self.z * xv.y);
    float2 acc3 = make_float2(e_self.w * xv.x, e_self.w * xv.y);
    // chunks of 64 edges: each lane computes one edge's per-head alphas, then broadcast
    for (int c0 = beg; c0 < end; c0 += 64) {
        int clen = min(64, end - c0);
        int s = 0;
        float4 e = make_float4(0.f, 0.f, 0.f, 0.f);
        if (lane < clen) {
            s = esrc[c0 + lane];
            e = exp4(lrelu4(as4[s] + adn) + mneg);
        }
#pragma unroll 2
        for (int j = 0; j < clen; j++) {
            int sj = __shfl(s, j, 64);            // uniform src lane -> readlane (SGPR base)
            float e0 = __shfl(e.x, j, 64);
            float e1 = __shfl(e.y, j, 64);
            float e2 = __shfl(e.z, j, 64);
            float e3 = __shfl(e.w, j, 64);
            float2 v = *reinterpret_cast<const float2*>(&x[(size_t)sj * 128 + lane * 2]);
            acc0.x = fmaf(e0, v.x, acc0.x); acc0.y = fmaf(e0, v.y, acc0.y);
            acc1.x = fmaf(e1, v.x, acc1.x); acc1.y = fmaf(e1, v.y, acc1.y);
            acc2.x = fmaf(e2, v.x, acc2.x); acc2.y = fmaf(e2, v.y, acc2.y);
            acc3.x = fmaf(e3, v.x, acc3.x); acc3.y = fmaf(e3, v.y, acc3.y);
            den.x += e0; den.y += e1; den.z += e2; den.w += e3;
        }
    }
    float i0 = 1.f / (den.x + 1e-16f);
    float i1 = 1.f / (den.y + 1e-16f);
    float i2 = 1.f / (den.z + 1e-16f);
    float i3 = 1.f / (den.w + 1e-16f);
    size_t base = (size_t)wid * 128 + lane * 2;
    *reinterpret_cast<float2*>(&xagg[0 * PLANE + base]) = make_float2(acc0.x * i0, acc0.y * i0);
    *reinterpret_cast<float2*>(&xagg[1 * PLANE + base]) = make_float2(acc1.x * i1, acc1.y * i1);
    *reinterpret_cast<float2*>(&xagg[2 * PLANE + base]) = make_float2(acc2.x * i2, acc2.y * i2);
    *reinterpret_cast<float2*>(&xagg[3 * PLANE + base]) = make_float2(acc3.x * i3, acc3.y * i3);
}

// ---------------- fp32 tiled GEMM with strides: C = A@B (+bias) (+relu) ----------------
// blockIdx.y selects 64-col panel (bcol) and optionally an A plane (aPlane elements).
template <bool BIAS, bool RELU>
__global__ __launch_bounds__(256) void gemm_kernel(const float* __restrict__ A, int lda,
                                                   long aPlane,
                                                   const float* __restrict__ B, int ldb,
                                                   const float* __restrict__ bias,
                                                   float* __restrict__ C, int ldc,
                                                   int M, int K) {
    A += (size_t)blockIdx.y * (size_t)aPlane;
    __shared__ float As[32][68];  // [k][row]
    __shared__ float Bs[32][68];  // [k][col]
    int tid = threadIdx.x;
    int brow = blockIdx.x * 64;
    int bcol = blockIdx.y * 64;
    int tr = (tid >> 4) * 4;
    int tc = (tid & 15) * 4;
    float acc[4][4] = {};
    for (int k0 = 0; k0 < K; k0 += 32) {
#pragma unroll
        for (int p = 0; p < 2; p++) {
            int idx = tid + p * 256;
            int r = idx >> 3;
            int c4 = (idx & 7) << 2;
            int gr = brow + r;
            float4 v = make_float4(0.f, 0.f, 0.f, 0.f);
            if (gr < M) v = *reinterpret_cast<const float4*>(&A[(size_t)gr * lda + k0 + c4]);
            As[c4 + 0][r] = v.x; As[c4 + 1][r] = v.y; As[c4 + 2][r] = v.z; As[c4 + 3][r] = v.w;
        }
#pragma unroll
        for (int p = 0; p < 2; p++) {
            int idx = tid + p * 256;
            int r = idx >> 4;
            int c4 = (idx & 15) << 2;
            float4 v = *reinterpret_cast<const float4*>(&B[(size_t)(k0 + r) * ldb + bcol + c4]);
            *reinterpret_cast<float4*>(&Bs[r][c4]) = v;
        }
        __syncthreads();
#pragma unroll
        for (int k = 0; k < 32; k++) {
            float4 a = *reinterpret_cast<const float4*>(&As[k][tr]);
            float4 b = *reinterpret_cast<const float4*>(&Bs[k][tc]);
            acc[0][0] += a.x * b.x; acc[0][1] += a.x * b.y; acc[0][2] += a.x * b.z; acc[0][3] += a.x * b.w;
            acc[1][0] += a.y * b.x; acc[1][1] += a.y * b.y; acc[1][2] += a.y * b.z; acc[1][3] += a.y * b.w;
            acc[2][0] += a.z * b.x; acc[2][1] += a.z * b.y; acc[2][2] += a.z * b.z; acc[2][3] += a.z * b.w;
            acc[3][0] += a.w * b.x; acc[3][1] += a.w * b.y; acc[3][2] += a.w * b.z; acc[3][3] += a.w * b.w;
        }
        __syncthreads();
    }
#pragma unroll
    for (int i = 0; i < 4; i++) {
        int gr = brow + tr + i;
        if (gr < M) {
            float4 v;
            v.x = acc[i][0]; v.y = acc[i][1]; v.z = acc[i][2]; v.w = acc[i][3];
            if (BIAS) {
                const float4 bb = *reinterpret_cast<const float4*>(&bias[bcol + tc]);
                v.x += bb.x; v.y += bb.y; v.z += bb.z; v.w += bb.w;
            }
            if (RELU) {
                v.x = fmaxf(v.x, 0.f); v.y = fmaxf(v.y, 0.f);
                v.z = fmaxf(v.z, 0.f); v.w = fmaxf(v.w, 0.f);
            }
            *reinterpret_cast<float4*>(&C[(size_t)gr * ldc + bcol + tc]) = v;
        }
    }
}

// ---------------- conv2 attention scalars (H=1) ----------------
__global__ __launch_bounds__(256) void att1_kernel(const float* __restrict__ Hf,
                                                   const float* __restrict__ att_src,
                                                   const float* __restrict__ att_dst,
                                                   float* __restrict__ as_,
                                                   float* __restrict__ ad_) {
    int wid = (blockIdx.x * blockDim.x + threadIdx.x) >> 6;
    int lane = threadIdx.x & 63;
    if (wid >= N_NODES) return;
    float v = Hf[(size_t)wid * 64 + lane];
    float ps = v * att_src[lane];
    float pd = v * att_dst[lane];
#pragma unroll
    for (int off = 32; off; off >>= 1) {
        ps += __shfl_xor(ps, off, 64);
        pd += __shfl_xor(pd, off, 64);
    }
    if (lane == 0) { as_[wid] = ps; ad_[wid] = pd; }
}

// ---------------- conv2 aggregation: wave per node, per-edge alpha once + broadcast ----------------
__global__ __launch_bounds__(256) void agg1_kernel(const float* __restrict__ Hf,
                                                   const float* __restrict__ as_,
                                                   const float* __restrict__ ad_,
                                                   const int* __restrict__ row_start,
                                                   const int* __restrict__ esrc,
                                                   const float* __restrict__ bias,
                                                   float* __restrict__ out) {
    int wid = (blockIdx.x * blockDim.x + threadIdx.x) >> 6;
    int lane = threadIdx.x & 63;
    if (wid >= N_NODES) return;
    int beg = row_start[wid], end = row_start[wid + 1];
    float adn = ad_[wid];
    float a_self = lrelu(as_[wid] + adn);
    float lm = -1e30f;
    for (int j = beg + lane; j < end; j += 64)
        lm = fmaxf(lm, lrelu(as_[esrc[j]] + adn));
#pragma unroll
    for (int off = 32; off; off >>= 1)
        lm = fmaxf(lm, __shfl_xor(lm, off, 64));
    float m = fmaxf(lm, a_self);
    float e_self = __expf(a_self - m);
    float den = e_self;
    float acc = e_self * Hf[(size_t)wid * 64 + lane];
    for (int c0 = beg; c0 < end; c0 += 64) {
        int clen = min(64, end - c0);
        int s = 0;
        float e = 0.f;
        if (lane < clen) {
            s = esrc[c0 + lane];
            e = __expf(lrelu(as_[s] + adn) - m);
        }
#pragma unroll 4
        for (int j = 0; j < clen; j++) {
            int sj = __shfl(s, j, 64);
            float ej = __shfl(e, j, 64);
            acc = fmaf(ej, Hf[(size_t)sj * 64 + lane], acc);
            den += ej;
        }
    }
    out[(size_t)wid * 64 + lane] = acc / (den + 1e-16f) + bias[lane];
}

// ---------------- build B for PQ GEMM ----------------
__global__ void build_bpq(const float* __restrict__ We1, float* __restrict__ Bpq) {
    int idx = blockIdx.x * blockDim.x + threadIdx.x;
    if (idx < 64 * 128) {
        int k = idx >> 7;
        int j = idx & 127;
        Bpq[idx] = (j < 64) ? We1[k * 64 + j] : We1[(64 + k) * 64 + (j - 64)];
    }
}

// ---------------- edge decode: CSR(dst)-ordered, 8 lanes/edge, 8 edges/wave ----------------
#define ED_BLOCKS 2048
__global__ __launch_bounds__(256) void edge_decode_kernel(const float* __restrict__ PQ,
                                                          const int* __restrict__ esrc,
                                                          const int* __restrict__ edst,
                                                          const int* __restrict__ eorig,
                                                          const float* __restrict__ be1,
                                                          const float* __restrict__ We2,
                                                          const float* __restrict__ be2,
                                                          float* __restrict__ out) {
    int lane = threadIdx.x & 63;
    int g = lane >> 3;
    int l8 = lane & 7;
    int c0 = l8 * 8;
    float w[8][8];
#pragma unroll
    for (int i = 0; i < 8; i++) {
        float4 a = *reinterpret_cast<const float4*>(&We2[(c0 + i) * 8]);
        float4 b = *reinterpret_cast<const float4*>(&We2[(c0 + i) * 8 + 4]);
        w[i][0] = a.x; w[i][1] = a.y; w[i][2] = a.z; w[i][3] = a.w;
        w[i][4] = b.x; w[i][5] = b.y; w[i][6] = b.z; w[i][7] = b.w;
    }
    float4 bia = *reinterpret_cast<const float4*>(&be1[c0]);
    float4 bib = *reinterpret_cast<const float4*>(&be1[c0 + 4]);
    float bout = be2[l8];

    int wgid = (blockIdx.x * blockDim.x + threadIdx.x) >> 6;
    const int nwaves = ED_BLOCKS * 4;
    const int ngroups = N_EDGES / 8;
    for (int eg = wgid; eg < ngroups; eg += nwaves) {
        int p = eg * 8 + g;
        int s = esrc[p], d = edst[p], o = eorig[p];
        const float* Pr = &PQ[(size_t)s * 128 + c0];
        const float* Qr = &PQ[(size_t)d * 128 + 64 + c0];
        float4 pa = *reinterpret_cast<const float4*>(Pr);
        float4 pb = *reinterpret_cast<const float4*>(Pr + 4);
        float4 qa = *reinterpret_cast<const float4*>(Qr);
        float4 qb = *reinterpret_cast<const float4*>(Qr + 4);
        float t[8];
        t[0] = fmaxf(pa.x + qa.x + bia.x, 0.f);
        t[1] = fmaxf(pa.y + qa.y + bia.y, 0.f);
        t[2] = fmaxf(pa.z + qa.z + bia.z, 0.f);
        t[3] = fmaxf(pa.w + qa.w + bia.w, 0.f);
        t[4] = fmaxf(pb.x + qb.x + bib.x, 0.f);
        t[5] = fmaxf(pb.y + qb.y + bib.y, 0.f);
        t[6] = fmaxf(pb.z + qb.z + bib.z, 0.f);
        t[7] = fmaxf(pb.w + qb.w + bib.w, 0.f);
        float p8[8] = {};
#pragma unroll
        for (int i = 0; i < 8; i++)
#pragma unroll
            for (int jj = 0; jj < 8; jj++) p8[jj] = fmaf(t[i], w[i][jj], p8[jj]);
#pragma unroll
        for (int off = 1; off <= 4; off <<= 1) {
#pragma unroll
            for (int jj = 0; jj < 8; jj++) p8[jj] += __shfl_xor(p8[jj], off, 64);
        }
        float v = p8[0];
        if (l8 == 1) v = p8[1];
        else if (l8 == 2) v = p8[2];
        else if (l8 == 3) v = p8[3];
        else if (l8 == 4) v = p8[4];
        else if (l8 == 5) v = p8[5];
        else if (l8 == 6) v = p8[6];
        else if (l8 == 7) v = p8[7];
        out[(size_t)o * 8 + l8] = v + bout;
    }
}

extern "C" void kernel_launch(void* const* d_in, const int* in_sizes, int n_in,
                              void* d_out, int out_size, void* d_ws, size_t ws_size,
                              hipStream_t stream) {
    const float* x        = (const float*)d_in[0];
    const int*   ei       = (const int*)d_in[1];
    const float* W1       = (const float*)d_in[2];
    const float* att_src1 = (const float*)d_in[3];
    const float* att_dst1 = (const float*)d_in[4];
    const float* b1       = (const float*)d_in[5];
    const float* W2       = (const float*)d_in[6];
    const float* att_src2 = (const float*)d_in[7];
    const float* att_dst2 = (const float*)d_in[8];
    const float* b2       = (const float*)d_in[9];
    const float* Wn       = (const float*)d_in[10];
    const float* bn       = (const float*)d_in[11];
    const float* We1      = (const float*)d_in[12];
    const float* be1      = (const float*)d_in[13];
    const float* We2      = (const float*)d_in[14];
    const float* be2      = (const float*)d_in[15];

    char* ws = (char*)d_ws;
    size_t off = 0;
    auto alloc = [&](size_t bytes) {
        void* p = ws + off;
        off += (bytes + 255) & ~(size_t)255;
        return p;
    };
    int*   cnt       = (int*)alloc((size_t)N_NODES * 4);
    int*   row_start = (int*)alloc((size_t)(N_NODES + 1) * 4);
    int*   esrc      = (int*)alloc((size_t)N_EDGES * 4);
    int*   edst      = (int*)alloc((size_t)N_EDGES * 4);
    int*   eorig     = (int*)alloc((size_t)N_EDGES * 4);
    float* watt      = (float*)alloc((size_t)128 * 8 * 4);
    float* as1       = (float*)alloc((size_t)N_NODES * 4 * 4);
    float* ad1       = (float*)alloc((size_t)N_NODES * 4 * 4);
    float* xagg      = (float*)alloc((size_t)4 * PLANE * 4);   // 102.4 MB, 4 head planes
    float* hout      = (float*)alloc((size_t)N_NODES * 256 * 4);
    float* Bpq       = (float*)alloc((size_t)64 * 128 * 4);
    // xagg is dead after the conv1 GEMMs -> carve later buffers from it
    float* H2  = xagg + 0 * PLANE;            // 12.8 MB (fits plane0)
    float* z   = xagg + 1 * PLANE;            // 12.8 MB
    float* PQ  = xagg + 2 * PLANE;            // 25.6 MB
    float* as2 = xagg + 3 * PLANE;
    float* ad2 = as2 + N_NODES;

    float* recon_x = (float*)d_out;
    float* recon_e = (float*)d_out + (size_t)N_NODES * F_IN;

    // CSR build
    hipMemsetAsync(cnt, 0, (size_t)N_NODES * 4, stream);
    count_kernel<<<(N_EDGES + 255) / 256, 256, 0, stream>>>(ei, cnt);
    scan_kernel<<<1, 1024, 0, stream>>>(cnt, row_start);
    hipMemsetAsync(cnt, 0, (size_t)N_NODES * 4, stream);
    scatter_kernel<<<(N_EDGES + 255) / 256, 256, 0, stream>>>(ei, row_start, cnt,
                                                              esrc, edst, eorig);

    // conv1: attention scalars straight from x, aggregate x rows, then per-head GEMM
    watt_kernel<<<4, 256, 0, stream>>>(W1, att_src1, att_dst1, watt);
    asad_kernel<<<(N_NODES * 64 + 255) / 256, 256, 0, stream>>>(x, watt,
                                                                (float4*)as1, (float4*)ad1);
    agg4x_kernel<<<(N_NODES * 64 + 255) / 256, 256, 0, stream>>>(x, (const float4*)as1,
                                                                 (const float4*)ad1, row_start,
                                                                 esrc, xagg);
    dim3 gc1((N_NODES + 63) / 64, 4);
    gemm_kernel<true, true><<<gc1, 256, 0, stream>>>(xagg, 128, (long)PLANE, W1, 256,
                                                     b1, hout, 256, N_NODES, 128);

    // conv2
    dim3 gc2((N_NODES + 63) / 64, 1);
    gemm_kernel<false, false><<<gc2, 256, 0, stream>>>(hout, 256, 0, W2, 64,
                                                       nullptr, H2, 64, N_NODES, 256);
    att1_kernel<<<(N_NODES * 64 + 255) / 256, 256, 0, stream>>>(H2, att_src2, att_dst2, as2, ad2);
    agg1_kernel<<<(N_NODES * 64 + 255) / 256, 256, 0, stream>>>(H2, as2, ad2, row_start, esrc, b2, z);

    // node decode
    dim3 gc3((N_NODES + 63) / 64, 2);
    gemm_kernel<true, false><<<gc3, 256, 0, stream>>>(z, 64, 0, Wn, 128,
                                                      bn, recon_x, 128, N_NODES, 64);

    // edge decode: P|Q precompute then per-edge fuse (CSR order)
    build_bpq<<<(64 * 128 + 255) / 256, 256, 0, stream>>>(We1, Bpq);
    gemm_kernel<false, false><<<gc3, 256, 0, stream>>>(z, 64, 0, Bpq, 128,
                                                       nullptr, PQ, 128, N_NODES, 64);
    edge_decode_kernel<<<ED_BLOCKS, 256, 0, stream>>>(PQ, esrc, edst, eorig, be1, We2, be2, recon_e);
}

// Round 6
// 479.116 us; speedup vs baseline: 2.5082x; 1.0254x over previous
//
#include <hip/hip_runtime.h>

#define N_NODES 50000
#define N_EDGES 800000
#define F_IN    128
#define HEADS   4
#define HID     64
#define LAT     64
#define N_EC    8
#define SLOPE   0.2f
#define PLANE   ((size_t)N_NODES * 128)   // one head's xagg plane (elements)

__device__ __forceinline__ float lrelu(float x) { return x > 0.f ? x : SLOPE * x; }
__device__ __forceinline__ float4 operator+(float4 a, float4 b) { return make_float4(a.x+b.x, a.y+b.y, a.z+b.z, a.w+b.w); }
__device__ __forceinline__ float4 lrelu4(float4 a) { return make_float4(lrelu(a.x), lrelu(a.y), lrelu(a.z), lrelu(a.w)); }
__device__ __forceinline__ float4 max4(float4 a, float4 b) { return make_float4(fmaxf(a.x,b.x), fmaxf(a.y,b.y), fmaxf(a.z,b.z), fmaxf(a.w,b.w)); }
__device__ __forceinline__ float4 exp4(float4 a) { return make_float4(__expf(a.x), __expf(a.y), __expf(a.z), __expf(a.w)); }

// bf16 helpers (manual, RNE)
__device__ __forceinline__ unsigned short f2bf(float f) {
    union { float f; unsigned u; } a; a.f = f;
    unsigned r = a.u + 0x7fffu + ((a.u >> 16) & 1u);
    return (unsigned short)(r >> 16);
}
__device__ __forceinline__ float2 bf2f2(unsigned u) {
    union { unsigned q; float f; } a, b;
    a.q = u << 16; b.q = u & 0xffff0000u;
    return make_float2(a.f, b.f);
}

// ---------------- fp32 -> bf16 copy ----------------
__global__ void to_bf16_kernel(const float* __restrict__ in, unsigned short* __restrict__ out,
                               int n4) {
    int i = blockIdx.x * blockDim.x + threadIdx.x;
    if (i < n4) {
        float4 v = reinterpret_cast<const float4*>(in)[i];
        ushort4 o;
        o.x = f2bf(v.x); o.y = f2bf(v.y); o.z = f2bf(v.z); o.w = f2bf(v.w);
        reinterpret_cast<ushort4*>(out)[i] = o;
    }
}

// ---------------- CSR build (by dst) ----------------
__global__ void count_kernel(const int* __restrict__ ei, int* __restrict__ cnt) {
    int e = blockIdx.x * blockDim.x + threadIdx.x;
    if (e < N_EDGES) atomicAdd(&cnt[ei[N_EDGES + e]], 1);
}

__global__ __launch_bounds__(1024) void scan_kernel(const int* __restrict__ cnt,
                                                    int* __restrict__ row_start) {
    __shared__ int wsum[16];
    __shared__ int carry;
    int tid = threadIdx.x, lane = tid & 63, w = tid >> 6;
    if (tid == 0) carry = 0;
    __syncthreads();
    for (int base = 0; base < N_NODES; base += 1024) {
        int i = base + tid;
        int v = (i < N_NODES) ? cnt[i] : 0;
        int incl = v;
#pragma unroll
        for (int off = 1; off < 64; off <<= 1) {
            int t = __shfl_up(incl, off, 64);
            if (lane >= off) incl += t;
        }
        if (lane == 63) wsum[w] = incl;
        __syncthreads();
        if (w == 0 && lane < 16) {
            int s = wsum[lane];
            int si = s;
#pragma unroll
            for (int off = 1; off < 16; off <<= 1) {
                int t = __shfl_up(si, off, 64);
                if (lane >= off) si += t;
            }
            wsum[lane] = si - s;  // exclusive prefix of wave sums
        }
        __syncthreads();
        int total_prev = carry;
        if (i < N_NODES) row_start[i] = total_prev + wsum[w] + incl - v;
        __syncthreads();
        if (tid == 1023) carry = total_prev + wsum[15] + incl;
        __syncthreads();
    }
    if (threadIdx.x == 0) row_start[N_NODES] = carry;
}

__global__ void scatter_kernel(const int* __restrict__ ei, const int* __restrict__ row_start,
                               int* __restrict__ cursor, int* __restrict__ esrc,
                               int* __restrict__ edst, int* __restrict__ eorig) {
    int e = blockIdx.x * blockDim.x + threadIdx.x;
    if (e < N_EDGES) {
        int d = ei[N_EDGES + e];
        int pos = row_start[d] + atomicAdd(&cursor[d], 1);
        esrc[pos] = ei[e];
        edst[pos] = d;
        eorig[pos] = e;
    }
}

// ---------------- watt[k][j] = sum_c W1[k][h*64+c] * att_{src|dst}[h][c] ----------------
__global__ void watt_kernel(const float* __restrict__ W1, const float* __restrict__ as_,
                            const float* __restrict__ ad_, float* __restrict__ watt) {
    int idx = blockIdx.x * blockDim.x + threadIdx.x;
    if (idx >= 128 * 8) return;
    int k = idx >> 3, j = idx & 7;
    int h = j & 3;
    const float* av = (j < 4) ? as_ : ad_;
    float sum = 0.f;
    for (int c = 0; c < 64; c++) sum += W1[k * 256 + h * 64 + c] * av[h * 64 + c];
    watt[k * 8 + j] = sum;
}

// ---------------- attention scalars from x: wave per node, 8 outputs ----------------
__global__ __launch_bounds__(256) void asad_kernel(const float* __restrict__ x,
                                                   const float* __restrict__ watt,
                                                   float4* __restrict__ as4,
                                                   float4* __restrict__ ad4) {
    int wid = (blockIdx.x * blockDim.x + threadIdx.x) >> 6;
    int lane = threadIdx.x & 63;
    if (wid >= N_NODES) return;
    float2 xv = *reinterpret_cast<const float2*>(&x[(size_t)wid * 128 + lane * 2]);
    float p[8];
    const float* w0 = &watt[(2 * lane) * 8];
    const float* w1 = &watt[(2 * lane + 1) * 8];
#pragma unroll
    for (int j = 0; j < 8; j++) p[j] = fmaf(xv.x, w0[j], xv.y * w1[j]);
#pragma unroll
    for (int off = 32; off; off >>= 1)
#pragma unroll
        for (int j = 0; j < 8; j++) p[j] += __shfl_xor(p[j], off, 64);
    if (lane == 0) {
        as4[wid] = make_float4(p[0], p[1], p[2], p[3]);
        ad4[wid] = make_float4(p[4], p[5], p[6], p[7]);
    }
}

// ---------------- conv1 aggregation in x-domain, bf16 gathers (256B rows) ----------------
__global__ __launch_bounds__(256) void agg4x_kernel(const unsigned short* __restrict__ xb,
                                                    const float4* __restrict__ as4,
                                                    const float4* __restrict__ ad4,
                                                    const int* __restrict__ row_start,
                                                    const int* __restrict__ esrc,
                                                    float* __restrict__ xagg) {
    int wid = (blockIdx.x * blockDim.x + threadIdx.x) >> 6;
    int lane = threadIdx.x & 63;
    if (wid >= N_NODES) return;
    int beg = row_start[wid], end = row_start[wid + 1];
    float4 adn = ad4[wid];
    float4 a_self = lrelu4(as4[wid] + adn);
    // pass 1: segment max
    float4 lm = make_float4(-1e30f, -1e30f, -1e30f, -1e30f);
    for (int j = beg + lane; j < end; j += 64)
        lm = max4(lm, lrelu4(as4[esrc[j]] + adn));
#pragma unroll
    for (int off = 32; off; off >>= 1) {
        lm.x = fmaxf(lm.x, __shfl_xor(lm.x, off, 64));
        lm.y = fmaxf(lm.y, __shfl_xor(lm.y, off, 64));
        lm.z = fmaxf(lm.z, __shfl_xor(lm.z, off, 64));
        lm.w = fmaxf(lm.w, __shfl_xor(lm.w, off, 64));
    }
    float4 m = max4(lm, a_self);
    float4 mneg = make_float4(-m.x, -m.y, -m.z, -m.w);
    float4 e_self = exp4(a_self + mneg);
    float4 den = e_self;
    unsigned uself = *reinterpret_cast<const unsigned*>(&xb[(size_t)wid * 128 + lane * 2]);
    float2 xv = bf2f2(uself);
    float2 acc0 = make_float2(e_self.x * xv.x, e_self.x * xv.y);
    float2 acc1 = make_float2(e_self.y * xv.x, e_self.y * xv.y);
    float2 acc2 = make_float2(e_self.z * xv.x, e_self.z * xv.y);
    float2 acc3 = make_float2(e_self.w * xv.x, e_self.w * xv.y);
    // chunks of 64 edges: each lane computes one edge's per-head alphas, then broadcast
    for (int c0 = beg; c0 < end; c0 += 64) {
        int clen = min(64, end - c0);
        int s = 0;
        float4 e = make_float4(0.f, 0.f, 0.f, 0.f);
        if (lane < clen) {
            s = esrc[c0 + lane];
            e = exp4(lrelu4(as4[s] + adn) + mneg);
        }
#pragma unroll 2
        for (int j = 0; j < clen; j++) {
            int sj = __shfl(s, j, 64);            // uniform src lane -> readlane (SGPR base)
            float e0 = __shfl(e.x, j, 64);
            float e1 = __shfl(e.y, j, 64);
            float e2 = __shfl(e.z, j, 64);
            float e3 = __shfl(e.w, j, 64);
            unsigned u = *reinterpret_cast<const unsigned*>(&xb[(size_t)sj * 128 + lane * 2]);
            float2 v = bf2f2(u);
            acc0.x = fmaf(e0, v.x, acc0.x); acc0.y = fmaf(e0, v.y, acc0.y);
            acc1.x = fmaf(e1, v.x, acc1.x); acc1.y = fmaf(e1, v.y, acc1.y);
            acc2.x = fmaf(e2, v.x, acc2.x); acc2.y = fmaf(e2, v.y, acc2.y);
            acc3.x = fmaf(e3, v.x, acc3.x); acc3.y = fmaf(e3, v.y, acc3.y);
            den.x += e0; den.y += e1; den.z += e2; den.w += e3;
        }
    }
    float i0 = 1.f / (den.x + 1e-16f);
    float i1 = 1.f / (den.y + 1e-16f);
    float i2 = 1.f / (den.z + 1e-16f);
    float i3 = 1.f / (den.w + 1e-16f);
    size_t base = (size_t)wid * 128 + lane * 2;
    *reinterpret_cast<float2*>(&xagg[0 * PLANE + base]) = make_float2(acc0.x * i0, acc0.y * i0);
    *reinterpret_cast<float2*>(&xagg[1 * PLANE + base]) = make_float2(acc1.x * i1, acc1.y * i1);
    *reinterpret_cast<float2*>(&xagg[2 * PLANE + base]) = make_float2(acc2.x * i2, acc2.y * i2);
    *reinterpret_cast<float2*>(&xagg[3 * PLANE + base]) = make_float2(acc3.x * i3, acc3.y * i3);
}

// ---------------- fp32 tiled GEMM with strides: C = A@B (+bias)(+relu)(+bf16 out) ----------------
template <bool BIAS, bool RELU, bool BF16OUT>
__global__ __launch_bounds__(256) void gemm_kernel(const float* __restrict__ A, int lda,
                                                   long aPlane,
                                                   const float* __restrict__ B, int ldb,
                                                   const float* __restrict__ bias,
                                                   float* __restrict__ C, int ldc,
                                                   int M, int K) {
    A += (size_t)blockIdx.y * (size_t)aPlane;
    __shared__ float As[32][68];  // [k][row]
    __shared__ float Bs[32][68];  // [k][col]
    int tid = threadIdx.x;
    int brow = blockIdx.x * 64;
    int bcol = blockIdx.y * 64;
    int tr = (tid >> 4) * 4;
    int tc = (tid & 15) * 4;
    float acc[4][4] = {};
    for (int k0 = 0; k0 < K; k0 += 32) {
#pragma unroll
        for (int p = 0; p < 2; p++) {
            int idx = tid + p * 256;
            int r = idx >> 3;
            int c4 = (idx & 7) << 2;
            int gr = brow + r;
            float4 v = make_float4(0.f, 0.f, 0.f, 0.f);
            if (gr < M) v = *reinterpret_cast<const float4*>(&A[(size_t)gr * lda + k0 + c4]);
            As[c4 + 0][r] = v.x; As[c4 + 1][r] = v.y; As[c4 + 2][r] = v.z; As[c4 + 3][r] = v.w;
        }
#pragma unroll
        for (int p = 0; p < 2; p++) {
            int idx = tid + p * 256;
            int r = idx >> 4;
            int c4 = (idx & 15) << 2;
            float4 v = *reinterpret_cast<const float4*>(&B[(size_t)(k0 + r) * ldb + bcol + c4]);
            *reinterpret_cast<float4*>(&Bs[r][c4]) = v;
        }
        __syncthreads();
#pragma unroll
        for (int k = 0; k < 32; k++) {
            float4 a = *reinterpret_cast<const float4*>(&As[k][tr]);
            float4 b = *reinterpret_cast<const float4*>(&Bs[k][tc]);
            acc[0][0] += a.x * b.x; acc[0][1] += a.x * b.y; acc[0][2] += a.x * b.z; acc[0][3] += a.x * b.w;
            acc[1][0] += a.y * b.x; acc[1][1] += a.y * b.y; acc[1][2] += a.y * b.z; acc[1][3] += a.y * b.w;
            acc[2][0] += a.z * b.x; acc[2][1] += a.z * b.y; acc[2][2] += a.z * b.z; acc[2][3] += a.z * b.w;
            acc[3][0] += a.w * b.x; acc[3][1] += a.w * b.y; acc[3][2] += a.w * b.z; acc[3][3] += a.w * b.w;
        }
        __syncthreads();
    }
#pragma unroll
    for (int i = 0; i < 4; i++) {
        int gr = brow + tr + i;
        if (gr < M) {
            float4 v;
            v.x = acc[i][0]; v.y = acc[i][1]; v.z = acc[i][2]; v.w = acc[i][3];
            if (BIAS) {
                const float4 bb = *reinterpret_cast<const float4*>(&bias[bcol + tc]);
                v.x += bb.x; v.y += bb.y; v.z += bb.z; v.w += bb.w;
            }
            if (RELU) {
                v.x = fmaxf(v.x, 0.f); v.y = fmaxf(v.y, 0.f);
                v.z = fmaxf(v.z, 0.f); v.w = fmaxf(v.w, 0.f);
            }
            if (BF16OUT) {
                ushort4 o;
                o.x = f2bf(v.x); o.y = f2bf(v.y); o.z = f2bf(v.z); o.w = f2bf(v.w);
                *reinterpret_cast<ushort4*>(
                    &reinterpret_cast<unsigned short*>(C)[(size_t)gr * ldc + bcol + tc]) = o;
            } else {
                *reinterpret_cast<float4*>(&C[(size_t)gr * ldc + bcol + tc]) = v;
            }
        }
    }
}

// ---------------- conv2 attention scalars (H=1) ----------------
__global__ __launch_bounds__(256) void att1_kernel(const float* __restrict__ Hf,
                                                   const float* __restrict__ att_src,
                                                   const float* __restrict__ att_dst,
                                                   float* __restrict__ as_,
                                                   float* __restrict__ ad_) {
    int wid = (blockIdx.x * blockDim.x + threadIdx.x) >> 6;
    int lane = threadIdx.x & 63;
    if (wid >= N_NODES) return;
    float v = Hf[(size_t)wid * 64 + lane];
    float ps = v * att_src[lane];
    float pd = v * att_dst[lane];
#pragma unroll
    for (int off = 32; off; off >>= 1) {
        ps += __shfl_xor(ps, off, 64);
        pd += __shfl_xor(pd, off, 64);
    }
    if (lane == 0) { as_[wid] = ps; ad_[wid] = pd; }
}

// ---------------- conv2 aggregation: 2 edge-slots x 32 lanes, bf16 gathers (128B rows) ----------------
__global__ __launch_bounds__(256) void agg1_kernel(const unsigned short* __restrict__ h2b,
                                                   const float* __restrict__ as_,
                                                   const float* __restrict__ ad_,
                                                   const int* __restrict__ row_start,
                                                   const int* __restrict__ esrc,
                                                   const float* __restrict__ bias,
                                                   float* __restrict__ out) {
    int wid = (blockIdx.x * blockDim.x + threadIdx.x) >> 6;
    int lane = threadIdx.x & 63;
    if (wid >= N_NODES) return;
    int g = lane >> 5;        // edge slot 0/1
    int c = lane & 31;        // channel pair -> channels 2c, 2c+1
    int beg = row_start[wid], end = row_start[wid + 1];
    float adn = ad_[wid];
    float a_self = lrelu(as_[wid] + adn);
    float lm = -1e30f;
    for (int j = beg + lane; j < end; j += 64)
        lm = fmaxf(lm, lrelu(as_[esrc[j]] + adn));
#pragma unroll
    for (int off = 32; off; off >>= 1)
        lm = fmaxf(lm, __shfl_xor(lm, off, 64));
    float m = fmaxf(lm, a_self);
    float e_self = __expf(a_self - m);
    float den = (g == 0) ? e_self : 0.f;
    unsigned uself = *reinterpret_cast<const unsigned*>(&h2b[(size_t)wid * 64 + 2 * c]);
    float2 hv = bf2f2(uself);
    float2 acc = (g == 0) ? make_float2(e_self * hv.x, e_self * hv.y)
                          : make_float2(0.f, 0.f);
    for (int c0 = beg; c0 < end; c0 += 64) {
        int clen = min(64, end - c0);
        int s = 0;
        float e = 0.f;
        if (lane < clen) {
            s = esrc[c0 + lane];
            e = __expf(lrelu(as_[s] + adn) - m);
        }
#pragma unroll 2
        for (int j = 0; j < clen; j += 2) {
            int jj = j + g;                       // slot g handles edge j+g (e=0 pads tail)
            int sj = __shfl(s, jj, 64);
            float ej = __shfl(e, jj, 64);
            unsigned u = *reinterpret_cast<const unsigned*>(&h2b[(size_t)sj * 64 + 2 * c]);
            float2 v = bf2f2(u);
            acc.x = fmaf(ej, v.x, acc.x);
            acc.y = fmaf(ej, v.y, acc.y);
            den += ej;
        }
    }
    den += __shfl_xor(den, 32, 64);
    acc.x += __shfl_xor(acc.x, 32, 64);
    acc.y += __shfl_xor(acc.y, 32, 64);
    if (g == 0) {
        float inv = 1.f / (den + 1e-16f);
        float2 bb = *reinterpret_cast<const float2*>(&bias[2 * c]);
        *reinterpret_cast<float2*>(&out[(size_t)wid * 64 + 2 * c]) =
            make_float2(acc.x * inv + bb.x, acc.y * inv + bb.y);
    }
}

// ---------------- build B for PQ GEMM ----------------
__global__ void build_bpq(const float* __restrict__ We1, float* __restrict__ Bpq) {
    int idx = blockIdx.x * blockDim.x + threadIdx.x;
    if (idx < 64 * 128) {
        int k = idx >> 7;
        int j = idx & 127;
        Bpq[idx] = (j < 64) ? We1[k * 64 + j] : We1[(64 + k) * 64 + (j - 64)];
    }
}

// ---------------- edge decode: CSR(dst)-ordered, bf16 PQ, 8 lanes/edge ----------------
#define ED_BLOCKS 2048
__global__ __launch_bounds__(256) void edge_decode_kernel(const unsigned short* __restrict__ PQb,
                                                          const int* __restrict__ esrc,
                                                          const int* __restrict__ edst,
                                                          const int* __restrict__ eorig,
                                                          const float* __restrict__ be1,
                                                          const float* __restrict__ We2,
                                                          const float* __restrict__ be2,
                                                          float* __restrict__ out) {
    int lane = threadIdx.x & 63;
    int g = lane >> 3;
    int l8 = lane & 7;
    int c0 = l8 * 8;
    float w[8][8];
#pragma unroll
    for (int i = 0; i < 8; i++) {
        float4 a = *reinterpret_cast<const float4*>(&We2[(c0 + i) * 8]);
        float4 b = *reinterpret_cast<const float4*>(&We2[(c0 + i) * 8 + 4]);
        w[i][0] = a.x; w[i][1] = a.y; w[i][2] = a.z; w[i][3] = a.w;
        w[i][4] = b.x; w[i][5] = b.y; w[i][6] = b.z; w[i][7] = b.w;
    }
    float4 bia = *reinterpret_cast<const float4*>(&be1[c0]);
    float4 bib = *reinterpret_cast<const float4*>(&be1[c0 + 4]);
    float bout = be2[l8];

    int wgid = (blockIdx.x * blockDim.x + threadIdx.x) >> 6;
    const int nwaves = ED_BLOCKS * 4;
    const int ngroups = N_EDGES / 8;
    for (int eg = wgid; eg < ngroups; eg += nwaves) {
        int p = eg * 8 + g;
        int s = esrc[p], d = edst[p], o = eorig[p];
        uint4 up = *reinterpret_cast<const uint4*>(&PQb[(size_t)s * 128 + c0]);
        uint4 uq = *reinterpret_cast<const uint4*>(&PQb[(size_t)d * 128 + 64 + c0]);
        float2 p0 = bf2f2(up.x), p1 = bf2f2(up.y), p2 = bf2f2(up.z), p3 = bf2f2(up.w);
        float2 q0 = bf2f2(uq.x), q1 = bf2f2(uq.y), q2 = bf2f2(uq.z), q3 = bf2f2(uq.w);
        float t[8];
        t[0] = fmaxf(p0.x + q0.x + bia.x, 0.f);
        t[1] = fmaxf(p0.y + q0.y + bia.y, 0.f);
        t[2] = fmaxf(p1.x + q1.x + bia.z, 0.f);
        t[3] = fmaxf(p1.y + q1.y + bia.w, 0.f);
        t[4] = fmaxf(p2.x + q2.x + bib.x, 0.f);
        t[5] = fmaxf(p2.y + q2.y + bib.y, 0.f);
        t[6] = fmaxf(p3.x + q3.x + bib.z, 0.f);
        t[7] = fmaxf(p3.y + q3.y + bib.w, 0.f);
        float p8[8] = {};
#pragma unroll
        for (int i = 0; i < 8; i++)
#pragma unroll
            for (int jj = 0; jj < 8; jj++) p8[jj] = fmaf(t[i], w[i][jj], p8[jj]);
#pragma unroll
        for (int off = 1; off <= 4; off <<= 1) {
#pragma unroll
            for (int jj = 0; jj < 8; jj++) p8[jj] += __shfl_xor(p8[jj], off, 64);
        }
        float v = p8[0];
        if (l8 == 1) v = p8[1];
        else if (l8 == 2) v = p8[2];
        else if (l8 == 3) v = p8[3];
        else if (l8 == 4) v = p8[4];
        else if (l8 == 5) v = p8[5];
        else if (l8 == 6) v = p8[6];
        else if (l8 == 7) v = p8[7];
        out[(size_t)o * 8 + l8] = v + bout;
    }
}

extern "C" void kernel_launch(void* const* d_in, const int* in_sizes, int n_in,
                              void* d_out, int out_size, void* d_ws, size_t ws_size,
                              hipStream_t stream) {
    const float* x        = (const float*)d_in[0];
    const int*   ei       = (const int*)d_in[1];
    const float* W1       = (const float*)d_in[2];
    const float* att_src1 = (const float*)d_in[3];
    const float* att_dst1 = (const float*)d_in[4];
    const float* b1       = (const float*)d_in[5];
    const float* W2       = (const float*)d_in[6];
    const float* att_src2 = (const float*)d_in[7];
    const float* att_dst2 = (const float*)d_in[8];
    const float* b2       = (const float*)d_in[9];
    const float* Wn       = (const float*)d_in[10];
    const float* bn       = (const float*)d_in[11];
    const float* We1      = (const float*)d_in[12];
    const float* be1      = (const float*)d_in[13];
    const float* We2      = (const float*)d_in[14];
    const float* be2      = (const float*)d_in[15];

    char* ws = (char*)d_ws;
    size_t off = 0;
    auto alloc = [&](size_t bytes) {
        void* p = ws + off;
        off += (bytes + 255) & ~(size_t)255;
        return p;
    };
    int*   cnt       = (int*)alloc((size_t)N_NODES * 4);
    int*   row_start = (int*)alloc((size_t)(N_NODES + 1) * 4);
    int*   esrc      = (int*)alloc((size_t)N_EDGES * 4);
    int*   edst      = (int*)alloc((size_t)N_EDGES * 4);
    int*   eorig     = (int*)alloc((size_t)N_EDGES * 4);
    float* watt      = (float*)alloc((size_t)128 * 8 * 4);
    float* as1       = (float*)alloc((size_t)N_NODES * 4 * 4);
    float* ad1       = (float*)alloc((size_t)N_NODES * 4 * 4);
    unsigned short* xb = (unsigned short*)alloc((size_t)N_NODES * 128 * 2);   // 12.8 MB bf16 x
    float* xagg      = (float*)alloc((size_t)4 * PLANE * 4);   // 102.4 MB, 4 head planes
    float* hout      = (float*)alloc((size_t)N_NODES * 256 * 4);
    float* Bpq       = (float*)alloc((size_t)64 * 128 * 4);
    // xagg dead after conv1 GEMM -> carve later buffers from it
    float* H2  = xagg + 0 * PLANE;                         // 12.8 MB
    float* z   = xagg + 1 * PLANE;                         // 12.8 MB
    unsigned short* PQb = (unsigned short*)(xagg + 2 * PLANE);   // 12.8 MB bf16
    float* as2 = xagg + 3 * PLANE;
    float* ad2 = as2 + N_NODES;
    unsigned short* h2b = (unsigned short*)(ad2 + N_NODES);      // 6.4 MB bf16

    float* recon_x = (float*)d_out;
    float* recon_e = (float*)d_out + (size_t)N_NODES * F_IN;

    // CSR build
    hipMemsetAsync(cnt, 0, (size_t)N_NODES * 4, stream);
    count_kernel<<<(N_EDGES + 255) / 256, 256, 0, stream>>>(ei, cnt);
    scan_kernel<<<1, 1024, 0, stream>>>(cnt, row_start);
    hipMemsetAsync(cnt, 0, (size_t)N_NODES * 4, stream);
    scatter_kernel<<<(N_EDGES + 255) / 256, 256, 0, stream>>>(ei, row_start, cnt,
                                                              esrc, edst, eorig);

    // bf16 copy of x for gathers
    to_bf16_kernel<<<(N_NODES * 128 / 4 + 255) / 256, 256, 0, stream>>>(x, xb, N_NODES * 128 / 4);

    // conv1: attention scalars from fp32 x; aggregate bf16 x rows; per-head GEMM applies W1
    watt_kernel<<<4, 256, 0, stream>>>(W1, att_src1, att_dst1, watt);
    asad_kernel<<<(N_NODES * 64 + 255) / 256, 256, 0, stream>>>(x, watt,
                                                                (float4*)as1, (float4*)ad1);
    agg4x_kernel<<<(N_NODES * 64 + 255) / 256, 256, 0, stream>>>(xb, (const float4*)as1,
                                                                 (const float4*)ad1, row_start,
                                                                 esrc, xagg);
    dim3 gc1((N_NODES + 63) / 64, 4);
    gemm_kernel<true, true, false><<<gc1, 256, 0, stream>>>(xagg, 128, (long)PLANE, W1, 256,
                                                            b1, hout, 256, N_NODES, 128);

    // conv2
    dim3 gc2((N_NODES + 63) / 64, 1);
    gemm_kernel<false, false, false><<<gc2, 256, 0, stream>>>(hout, 256, 0, W2, 64,
                                                              nullptr, H2, 64, N_NODES, 256);
    att1_kernel<<<(N_NODES * 64 + 255) / 256, 256, 0, stream>>>(H2, att_src2, att_dst2, as2, ad2);
    to_bf16_kernel<<<(N_NODES * 64 / 4 + 255) / 256, 256, 0, stream>>>(H2, h2b, N_NODES * 64 / 4);
    agg1_kernel<<<(N_NODES * 64 + 255) / 256, 256, 0, stream>>>(h2b, as2, ad2, row_start,
                                                                esrc, b2, z);

    // node decode
    dim3 gc3((N_NODES + 63) / 64, 2);
    gemm_kernel<true, false, false><<<gc3, 256, 0, stream>>>(z, 64, 0, Wn, 128,
                                                             bn, recon_x, 128, N_NODES, 64);

    // edge decode: P|Q precompute (bf16 out) then per-edge fuse (CSR order)
    build_bpq<<<(64 * 128 + 255) / 256, 256, 0, stream>>>(We1, Bpq);
    gemm_kernel<false, false, true><<<gc3, 256, 0, stream>>>(z, 64, 0, Bpq, 128,
                                                             nullptr, (float*)PQb, 128, N_NODES, 64);
    edge_decode_kernel<<<ED_BLOCKS, 256, 0, stream>>>(PQb, esrc, edst, eorig, be1, We2, be2, recon_e);
}

// Round 7
// 463.271 us; speedup vs baseline: 2.5940x; 1.0342x over previous
//
#include <hip/hip_runtime.h>

#define N_NODES 50000
#define N_EDGES 800000
#define F_IN    128
#define HEADS   4
#define HID     64
#define LAT     64
#define N_EC    8
#define SLOPE   0.2f
#define PLANE   ((size_t)N_NODES * 128)   // one head's xagg plane (bf16 elements)
#define PLANEU  ((size_t)N_NODES * 64)    // packed 2xbf16 units per plane

__device__ __forceinline__ float lrelu(float x) { return x > 0.f ? x : SLOPE * x; }
__device__ __forceinline__ float4 operator+(float4 a, float4 b) { return make_float4(a.x+b.x, a.y+b.y, a.z+b.z, a.w+b.w); }
__device__ __forceinline__ float4 lrelu4(float4 a) { return make_float4(lrelu(a.x), lrelu(a.y), lrelu(a.z), lrelu(a.w)); }
__device__ __forceinline__ float4 exp4(float4 a) { return make_float4(__expf(a.x), __expf(a.y), __expf(a.z), __expf(a.w)); }

// bf16 helpers (manual, RNE)
__device__ __forceinline__ unsigned short f2bf(float f) {
    union { float f; unsigned u; } a; a.f = f;
    unsigned r = a.u + 0x7fffu + ((a.u >> 16) & 1u);
    return (unsigned short)(r >> 16);
}
__device__ __forceinline__ unsigned pack2bf(float x, float y) {
    return (unsigned)f2bf(x) | ((unsigned)f2bf(y) << 16);
}
__device__ __forceinline__ float2 bf2f2(unsigned u) {
    union { unsigned q; float f; } a, b;
    a.q = u << 16; b.q = u & 0xffff0000u;
    return make_float2(a.f, b.f);
}

// ---------------- fp32 -> bf16 copy ----------------
__global__ void to_bf16_kernel(const float* __restrict__ in, unsigned short* __restrict__ out,
                               int n4) {
    int i = blockIdx.x * blockDim.x + threadIdx.x;
    if (i < n4) {
        float4 v = reinterpret_cast<const float4*>(in)[i];
        ushort4 o;
        o.x = f2bf(v.x); o.y = f2bf(v.y); o.z = f2bf(v.z); o.w = f2bf(v.w);
        reinterpret_cast<ushort4*>(out)[i] = o;
    }
}

// ---------------- CSR build (by dst) ----------------
__global__ void count_kernel(const int* __restrict__ ei, int* __restrict__ cnt) {
    int e = blockIdx.x * blockDim.x + threadIdx.x;
    if (e < N_EDGES) atomicAdd(&cnt[ei[N_EDGES + e]], 1);
}

__global__ __launch_bounds__(1024) void scan_kernel(const int* __restrict__ cnt,
                                                    int* __restrict__ row_start) {
    __shared__ int wsum[16];
    __shared__ int carry;
    int tid = threadIdx.x, lane = tid & 63, w = tid >> 6;
    if (tid == 0) carry = 0;
    __syncthreads();
    for (int base = 0; base < N_NODES; base += 1024) {
        int i = base + tid;
        int v = (i < N_NODES) ? cnt[i] : 0;
        int incl = v;
#pragma unroll
        for (int off = 1; off < 64; off <<= 1) {
            int t = __shfl_up(incl, off, 64);
            if (lane >= off) incl += t;
        }
        if (lane == 63) wsum[w] = incl;
        __syncthreads();
        if (w == 0 && lane < 16) {
            int s = wsum[lane];
            int si = s;
#pragma unroll
            for (int off = 1; off < 16; off <<= 1) {
                int t = __shfl_up(si, off, 64);
                if (lane >= off) si += t;
            }
            wsum[lane] = si - s;  // exclusive prefix of wave sums
        }
        __syncthreads();
        int total_prev = carry;
        if (i < N_NODES) row_start[i] = total_prev + wsum[w] + incl - v;
        __syncthreads();
        if (tid == 1023) carry = total_prev + wsum[15] + incl;
        __syncthreads();
    }
    if (threadIdx.x == 0) row_start[N_NODES] = carry;
}

// scatter + per-edge conv1 alpha. NOTE: no softmax max-subtraction — logits here are
// O(1) (|a|<~5 at this data scale; fp32 exp is safe to |a|~87) and softmax is
// shift-invariant, so exp(a) gives identical ratios.
__global__ void scatter_alpha_kernel(const int* __restrict__ ei, const int* __restrict__ row_start,
                                     int* __restrict__ cursor,
                                     const float4* __restrict__ as4, const float4* __restrict__ ad4,
                                     int* __restrict__ esrc, int* __restrict__ edst,
                                     int* __restrict__ eorig, float4* __restrict__ alpha4) {
    int e = blockIdx.x * blockDim.x + threadIdx.x;
    if (e < N_EDGES) {
        int s = ei[e];
        int d = ei[N_EDGES + e];
        int pos = row_start[d] + atomicAdd(&cursor[d], 1);
        esrc[pos] = s;
        edst[pos] = d;
        eorig[pos] = e;
        alpha4[pos] = exp4(lrelu4(as4[s] + ad4[d]));
    }
}

// ---------------- watt[k][j] = sum_c W1[k][h*64+c] * att_{src|dst}[h][c] ----------------
__global__ void watt_kernel(const float* __restrict__ W1, const float* __restrict__ as_,
                            const float* __restrict__ ad_, float* __restrict__ watt) {
    int idx = blockIdx.x * blockDim.x + threadIdx.x;
    if (idx >= 128 * 8) return;
    int k = idx >> 3, j = idx & 7;
    int h = j & 3;
    const float* av = (j < 4) ? as_ : ad_;
    float sum = 0.f;
    for (int c = 0; c < 64; c++) sum += W1[k * 256 + h * 64 + c] * av[h * 64 + c];
    watt[k * 8 + j] = sum;
}

// ---------------- attention scalars from x: wave per node, 8 outputs ----------------
__global__ __launch_bounds__(256) void asad_kernel(const float* __restrict__ x,
                                                   const float* __restrict__ watt,
                                                   float4* __restrict__ as4,
                                                   float4* __restrict__ ad4) {
    int wid = (blockIdx.x * blockDim.x + threadIdx.x) >> 6;
    int lane = threadIdx.x & 63;
    if (wid >= N_NODES) return;
    float2 xv = *reinterpret_cast<const float2*>(&x[(size_t)wid * 128 + lane * 2]);
    float p[8];
    const float* w0 = &watt[(2 * lane) * 8];
    const float* w1 = &watt[(2 * lane + 1) * 8];
#pragma unroll
    for (int j = 0; j < 8; j++) p[j] = fmaf(xv.x, w0[j], xv.y * w1[j]);
#pragma unroll
    for (int off = 32; off; off >>= 1)
#pragma unroll
        for (int j = 0; j < 8; j++) p[j] += __shfl_xor(p[j], off, 64);
    if (lane == 0) {
        as4[wid] = make_float4(p[0], p[1], p[2], p[3]);
        ad4[wid] = make_float4(p[4], p[5], p[6], p[7]);
    }
}

// ---------------- conv1 accumulate: wave/node; alpha+src via uniform SCALAR loads ----------------
// (beg/end forced uniform via readfirstlane -> alpha4[j]/esrc[j] become s_load, no DS pipe)
__global__ __launch_bounds__(256) void agg4x_acc_kernel(const unsigned short* __restrict__ xb,
                                                        const float4* __restrict__ as4,
                                                        const float4* __restrict__ ad4,
                                                        const int* __restrict__ row_start,
                                                        const int* __restrict__ esrc,
                                                        const float4* __restrict__ alpha4,
                                                        unsigned* __restrict__ xaggb) {
    int wid = (blockIdx.x * blockDim.x + threadIdx.x) >> 6;
    int lane = threadIdx.x & 63;
    if (wid >= N_NODES) return;
    int beg = __builtin_amdgcn_readfirstlane(row_start[wid]);
    int end = __builtin_amdgcn_readfirstlane(row_start[wid + 1]);
    float4 adn = ad4[wid];
    float4 e_self = exp4(lrelu4(as4[wid] + adn));
    float4 den = e_self;
    float2 xv = bf2f2(*reinterpret_cast<const unsigned*>(&xb[(size_t)wid * 128 + lane * 2]));
    float2 acc0 = make_float2(e_self.x * xv.x, e_self.x * xv.y);
    float2 acc1 = make_float2(e_self.y * xv.x, e_self.y * xv.y);
    float2 acc2 = make_float2(e_self.z * xv.x, e_self.z * xv.y);
    float2 acc3 = make_float2(e_self.w * xv.x, e_self.w * xv.y);
    int j = beg;
    for (; j + 1 < end; j += 2) {
        float4 ea = alpha4[j];
        int sa = esrc[j];
        float4 eb = alpha4[j + 1];
        int sb = esrc[j + 1];
        float2 va = bf2f2(*reinterpret_cast<const unsigned*>(&xb[(size_t)sa * 128 + lane * 2]));
        float2 vb = bf2f2(*reinterpret_cast<const unsigned*>(&xb[(size_t)sb * 128 + lane * 2]));
        acc0.x = fmaf(ea.x, va.x, acc0.x); acc0.y = fmaf(ea.x, va.y, acc0.y);
        acc1.x = fmaf(ea.y, va.x, acc1.x); acc1.y = fmaf(ea.y, va.y, acc1.y);
        acc2.x = fmaf(ea.z, va.x, acc2.x); acc2.y = fmaf(ea.z, va.y, acc2.y);
        acc3.x = fmaf(ea.w, va.x, acc3.x); acc3.y = fmaf(ea.w, va.y, acc3.y);
        den = den + ea;
        acc0.x = fmaf(eb.x, vb.x, acc0.x); acc0.y = fmaf(eb.x, vb.y, acc0.y);
        acc1.x = fmaf(eb.y, vb.x, acc1.x); acc1.y = fmaf(eb.y, vb.y, acc1.y);
        acc2.x = fmaf(eb.z, vb.x, acc2.x); acc2.y = fmaf(eb.z, vb.y, acc2.y);
        acc3.x = fmaf(eb.w, vb.x, acc3.x); acc3.y = fmaf(eb.w, vb.y, acc3.y);
        den = den + eb;
    }
    if (j < end) {
        float4 ea = alpha4[j];
        int sa = esrc[j];
        float2 va = bf2f2(*reinterpret_cast<const unsigned*>(&xb[(size_t)sa * 128 + lane * 2]));
        acc0.x = fmaf(ea.x, va.x, acc0.x); acc0.y = fmaf(ea.x, va.y, acc0.y);
        acc1.x = fmaf(ea.y, va.x, acc1.x); acc1.y = fmaf(ea.y, va.y, acc1.y);
        acc2.x = fmaf(ea.z, va.x, acc2.x); acc2.y = fmaf(ea.z, va.y, acc2.y);
        acc3.x = fmaf(ea.w, va.x, acc3.x); acc3.y = fmaf(ea.w, va.y, acc3.y);
        den = den + ea;
    }
    float i0 = 1.f / (den.x + 1e-16f);
    float i1 = 1.f / (den.y + 1e-16f);
    float i2 = 1.f / (den.z + 1e-16f);
    float i3 = 1.f / (den.w + 1e-16f);
    size_t base = (size_t)wid * 64 + lane;
    xaggb[0 * PLANEU + base] = pack2bf(acc0.x * i0, acc0.y * i0);
    xaggb[1 * PLANEU + base] = pack2bf(acc1.x * i1, acc1.y * i1);
    xaggb[2 * PLANEU + base] = pack2bf(acc2.x * i2, acc2.y * i2);
    xaggb[3 * PLANEU + base] = pack2bf(acc3.x * i3, acc3.y * i3);
}

// ---------------- fp32 tiled GEMM: C = A@B (+bias)(+relu)(+bf16out)(A may be bf16) ----------------
template <bool BIAS, bool RELU, bool BF16OUT, bool ABF16>
__global__ __launch_bounds__(256) void gemm_kernel(const void* __restrict__ Av, int lda,
                                                   long aPlane,
                                                   const float* __restrict__ B, int ldb,
                                                   const float* __restrict__ bias,
                                                   float* __restrict__ C, int ldc,
                                                   int M, int K) {
    __shared__ float As[32][68];  // [k][row]
    __shared__ float Bs[32][68];  // [k][col]
    int tid = threadIdx.x;
    int brow = blockIdx.x * 64;
    int bcol = blockIdx.y * 64;
    int tr = (tid >> 4) * 4;
    int tc = (tid & 15) * 4;
    float acc[4][4] = {};
    for (int k0 = 0; k0 < K; k0 += 32) {
        if constexpr (ABF16) {
            const unsigned short* A = (const unsigned short*)Av + (size_t)blockIdx.y * aPlane;
            int r = tid >> 2;            // 0..63
            int c8 = (tid & 3) * 8;      // 0,8,16,24
            int gr = brow + r;
            uint4 u = make_uint4(0, 0, 0, 0);
            if (gr < M) u = *reinterpret_cast<const uint4*>(&A[(size_t)gr * lda + k0 + c8]);
            float2 f0 = bf2f2(u.x), f1 = bf2f2(u.y), f2 = bf2f2(u.z), f3 = bf2f2(u.w);
            As[c8 + 0][r] = f0.x; As[c8 + 1][r] = f0.y;
            As[c8 + 2][r] = f1.x; As[c8 + 3][r] = f1.y;
            As[c8 + 4][r] = f2.x; As[c8 + 5][r] = f2.y;
            As[c8 + 6][r] = f3.x; As[c8 + 7][r] = f3.y;
        } else {
            const float* A = (const float*)Av + (size_t)blockIdx.y * aPlane;
#pragma unroll
            for (int p = 0; p < 2; p++) {
                int idx = tid + p * 256;
                int r = idx >> 3;
                int c4 = (idx & 7) << 2;
                int gr = brow + r;
                float4 v = make_float4(0.f, 0.f, 0.f, 0.f);
                if (gr < M) v = *reinterpret_cast<const float4*>(&A[(size_t)gr * lda + k0 + c4]);
                As[c4 + 0][r] = v.x; As[c4 + 1][r] = v.y; As[c4 + 2][r] = v.z; As[c4 + 3][r] = v.w;
            }
        }
#pragma unroll
        for (int p = 0; p < 2; p++) {
            int idx = tid + p * 256;
            int r = idx >> 4;
            int c4 = (idx & 15) << 2;
            float4 v = *reinterpret_cast<const float4*>(&B[(size_t)(k0 + r) * ldb + bcol + c4]);
            *reinterpret_cast<float4*>(&Bs[r][c4]) = v;
        }
        __syncthreads();
#pragma unroll
        for (int k = 0; k < 32; k++) {
            float4 a = *reinterpret_cast<const float4*>(&As[k][tr]);
            float4 b = *reinterpret_cast<const float4*>(&Bs[k][tc]);
            acc[0][0] += a.x * b.x; acc[0][1] += a.x * b.y; acc[0][2] += a.x * b.z; acc[0][3] += a.x * b.w;
            acc[1][0] += a.y * b.x; acc[1][1] += a.y * b.y; acc[1][2] += a.y * b.z; acc[1][3] += a.y * b.w;
            acc[2][0] += a.z * b.x; acc[2][1] += a.z * b.y; acc[2][2] += a.z * b.z; acc[2][3] += a.z * b.w;
            acc[3][0] += a.w * b.x; acc[3][1] += a.w * b.y; acc[3][2] += a.w * b.z; acc[3][3] += a.w * b.w;
        }
        __syncthreads();
    }
#pragma unroll
    for (int i = 0; i < 4; i++) {
        int gr = brow + tr + i;
        if (gr < M) {
            float4 v;
            v.x = acc[i][0]; v.y = acc[i][1]; v.z = acc[i][2]; v.w = acc[i][3];
            if (BIAS) {
                const float4 bb = *reinterpret_cast<const float4*>(&bias[bcol + tc]);
                v.x += bb.x; v.y += bb.y; v.z += bb.z; v.w += bb.w;
            }
            if (RELU) {
                v.x = fmaxf(v.x, 0.f); v.y = fmaxf(v.y, 0.f);
                v.z = fmaxf(v.z, 0.f); v.w = fmaxf(v.w, 0.f);
            }
            if (BF16OUT) {
                ushort4 o;
                o.x = f2bf(v.x); o.y = f2bf(v.y); o.z = f2bf(v.z); o.w = f2bf(v.w);
                *reinterpret_cast<ushort4*>(
                    &reinterpret_cast<unsigned short*>(C)[(size_t)gr * ldc + bcol + tc]) = o;
            } else {
                *reinterpret_cast<float4*>(&C[(size_t)gr * ldc + bcol + tc]) = v;
            }
        }
    }
}

// ---------------- conv2 attention scalars (H=1) ----------------
__global__ __launch_bounds__(256) void att1_kernel(const float* __restrict__ Hf,
                                                   const float* __restrict__ att_src,
                                                   const float* __restrict__ att_dst,
                                                   float* __restrict__ as_,
                                                   float* __restrict__ ad_) {
    int wid = (blockIdx.x * blockDim.x + threadIdx.x) >> 6;
    int lane = threadIdx.x & 63;
    if (wid >= N_NODES) return;
    float v = Hf[(size_t)wid * 64 + lane];
    float ps = v * att_src[lane];
    float pd = v * att_dst[lane];
#pragma unroll
    for (int off = 32; off; off >>= 1) {
        ps += __shfl_xor(ps, off, 64);
        pd += __shfl_xor(pd, off, 64);
    }
    if (lane == 0) { as_[wid] = ps; ad_[wid] = pd; }
}

// ---------------- conv2 per-edge alpha (edge-parallel, coalesced) ----------------
__global__ void alpha1_kernel(const int* __restrict__ esrc, const int* __restrict__ edst,
                              const float* __restrict__ as_, const float* __restrict__ ad_,
                              float* __restrict__ alpha1) {
    int p = blockIdx.x * blockDim.x + threadIdx.x;
    if (p < N_EDGES) alpha1[p] = __expf(lrelu(as_[esrc[p]] + ad_[edst[p]]));
}

// ---------------- conv2 accumulate: wave/node, 2 edges/iter, scalar alpha loads ----------------
__global__ __launch_bounds__(256) void agg1_acc_kernel(const unsigned short* __restrict__ h2b,
                                                       const float* __restrict__ as_,
                                                       const float* __restrict__ ad_,
                                                       const int* __restrict__ row_start,
                                                       const int* __restrict__ esrc,
                                                       const float* __restrict__ alpha1,
                                                       const float* __restrict__ bias,
                                                       float* __restrict__ z) {
    int wid = (blockIdx.x * blockDim.x + threadIdx.x) >> 6;
    int lane = threadIdx.x & 63;
    if (wid >= N_NODES) return;
    int g = lane >> 5;        // edge-half 0/1
    int c = lane & 31;        // channel pair -> channels 2c, 2c+1
    int beg = __builtin_amdgcn_readfirstlane(row_start[wid]);
    int end = __builtin_amdgcn_readfirstlane(row_start[wid + 1]);
    float adn = ad_[wid];
    float e_self = __expf(lrelu(as_[wid] + adn));
    float den = (g == 0) ? e_self : 0.f;
    float2 hv = bf2f2(*reinterpret_cast<const unsigned*>(&h2b[(size_t)wid * 64 + 2 * c]));
    float2 acc = (g == 0) ? make_float2(e_self * hv.x, e_self * hv.y)
                          : make_float2(0.f, 0.f);
    for (int j = beg; j < end; j += 2) {
        float a0 = alpha1[j];
        int s0 = esrc[j];
        float a1 = 0.f;
        int s1 = s0;
        if (j + 1 < end) { a1 = alpha1[j + 1]; s1 = esrc[j + 1]; }
        float e = g ? a1 : a0;
        int s = g ? s1 : s0;
        float2 v = bf2f2(*reinterpret_cast<const unsigned*>(&h2b[(size_t)s * 64 + 2 * c]));
        acc.x = fmaf(e, v.x, acc.x);
        acc.y = fmaf(e, v.y, acc.y);
        den += e;
    }
    den += __shfl_xor(den, 32, 64);
    acc.x += __shfl_xor(acc.x, 32, 64);
    acc.y += __shfl_xor(acc.y, 32, 64);
    if (g == 0) {
        float inv = 1.f / (den + 1e-16f);
        float2 bb = *reinterpret_cast<const float2*>(&bias[2 * c]);
        *reinterpret_cast<float2*>(&z[(size_t)wid * 64 + 2 * c]) =
            make_float2(acc.x * inv + bb.x, acc.y * inv + bb.y);
    }
}

// ---------------- build B for PQ GEMM ----------------
__global__ void build_bpq(const float* __restrict__ We1, float* __restrict__ Bpq) {
    int idx = blockIdx.x * blockDim.x + threadIdx.x;
    if (idx < 64 * 128) {
        int k = idx >> 7;
        int j = idx & 127;
        Bpq[idx] = (j < 64) ? We1[k * 64 + j] : We1[(64 + k) * 64 + (j - 64)];
    }
}

// ---------------- edge decode: CSR(dst)-ordered, bf16 PQ, 8 lanes/edge ----------------
#define ED_BLOCKS 2048
__global__ __launch_bounds__(256) void edge_decode_kernel(const unsigned short* __restrict__ PQb,
                                                          const int* __restrict__ esrc,
                                                          const int* __restrict__ edst,
                                                          const int* __restrict__ eorig,
                                                          const float* __restrict__ be1,
                                                          const float* __restrict__ We2,
                                                          const float* __restrict__ be2,
                                                          float* __restrict__ out) {
    int lane = threadIdx.x & 63;
    int g = lane >> 3;
    int l8 = lane & 7;
    int c0 = l8 * 8;
    float w[8][8];
#pragma unroll
    for (int i = 0; i < 8; i++) {
        float4 a = *reinterpret_cast<const float4*>(&We2[(c0 + i) * 8]);
        float4 b = *reinterpret_cast<const float4*>(&We2[(c0 + i) * 8 + 4]);
        w[i][0] = a.x; w[i][1] = a.y; w[i][2] = a.z; w[i][3] = a.w;
        w[i][4] = b.x; w[i][5] = b.y; w[i][6] = b.z; w[i][7] = b.w;
    }
    float4 bia = *reinterpret_cast<const float4*>(&be1[c0]);
    float4 bib = *reinterpret_cast<const float4*>(&be1[c0 + 4]);
    float bout = be2[l8];

    int wgid = (blockIdx.x * blockDim.x + threadIdx.x) >> 6;
    const int nwaves = ED_BLOCKS * 4;
    const int ngroups = N_EDGES / 8;
    for (int eg = wgid; eg < ngroups; eg += nwaves) {
        int p = eg * 8 + g;
        int s = esrc[p], d = edst[p], o = eorig[p];
        uint4 up = *reinterpret_cast<const uint4*>(&PQb[(size_t)s * 128 + c0]);
        uint4 uq = *reinterpret_cast<const uint4*>(&PQb[(size_t)d * 128 + 64 + c0]);
        float2 p0 = bf2f2(up.x), p1 = bf2f2(up.y), p2 = bf2f2(up.z), p3 = bf2f2(up.w);
        float2 q0 = bf2f2(uq.x), q1 = bf2f2(uq.y), q2 = bf2f2(uq.z), q3 = bf2f2(uq.w);
        float t[8];
        t[0] = fmaxf(p0.x + q0.x + bia.x, 0.f);
        t[1] = fmaxf(p0.y + q0.y + bia.y, 0.f);
        t[2] = fmaxf(p1.x + q1.x + bia.z, 0.f);
        t[3] = fmaxf(p1.y + q1.y + bia.w, 0.f);
        t[4] = fmaxf(p2.x + q2.x + bib.x, 0.f);
        t[5] = fmaxf(p2.y + q2.y + bib.y, 0.f);
        t[6] = fmaxf(p3.x + q3.x + bib.z, 0.f);
        t[7] = fmaxf(p3.y + q3.y + bib.w, 0.f);
        float p8[8] = {};
#pragma unroll
        for (int i = 0; i < 8; i++)
#pragma unroll
            for (int jj = 0; jj < 8; jj++) p8[jj] = fmaf(t[i], w[i][jj], p8[jj]);
#pragma unroll
        for (int off = 1; off <= 4; off <<= 1) {
#pragma unroll
            for (int jj = 0; jj < 8; jj++) p8[jj] += __shfl_xor(p8[jj], off, 64);
        }
        float v = p8[0];
        if (l8 == 1) v = p8[1];
        else if (l8 == 2) v = p8[2];
        else if (l8 == 3) v = p8[3];
        else if (l8 == 4) v = p8[4];
        else if (l8 == 5) v = p8[5];
        else if (l8 == 6) v = p8[6];
        else if (l8 == 7) v = p8[7];
        out[(size_t)o * 8 + l8] = v + bout;
    }
}

extern "C" void kernel_launch(void* const* d_in, const int* in_sizes, int n_in,
                              void* d_out, int out_size, void* d_ws, size_t ws_size,
                              hipStream_t stream) {
    const float* x        = (const float*)d_in[0];
    const int*   ei       = (const int*)d_in[1];
    const float* W1       = (const float*)d_in[2];
    const float* att_src1 = (const float*)d_in[3];
    const float* att_dst1 = (const float*)d_in[4];
    const float* b1       = (const float*)d_in[5];
    const float* W2       = (const float*)d_in[6];
    const float* att_src2 = (const float*)d_in[7];
    const float* att_dst2 = (const float*)d_in[8];
    const float* b2       = (const float*)d_in[9];
    const float* Wn       = (const float*)d_in[10];
    const float* bn       = (const float*)d_in[11];
    const float* We1      = (const float*)d_in[12];
    const float* be1      = (const float*)d_in[13];
    const float* We2      = (const float*)d_in[14];
    const float* be2      = (const float*)d_in[15];

    char* ws = (char*)d_ws;
    size_t off = 0;
    auto alloc = [&](size_t bytes) {
        void* p = ws + off;
        off += (bytes + 255) & ~(size_t)255;
        return p;
    };
    int*   cnt       = (int*)alloc((size_t)N_NODES * 4);
    int*   row_start = (int*)alloc((size_t)(N_NODES + 1) * 4);
    int*   esrc      = (int*)alloc((size_t)N_EDGES * 4);
    int*   edst      = (int*)alloc((size_t)N_EDGES * 4);
    int*   eorig     = (int*)alloc((size_t)N_EDGES * 4);
    float* watt      = (float*)alloc((size_t)128 * 8 * 4);
    float* as1       = (float*)alloc((size_t)N_NODES * 4 * 4);
    float* ad1       = (float*)alloc((size_t)N_NODES * 4 * 4);
    unsigned short* xb = (unsigned short*)alloc((size_t)N_NODES * 128 * 2);   // 12.8 MB
    float* alpha4    = (float*)alloc((size_t)N_EDGES * 4 * 4);                // 12.8 MB
    unsigned* xaggb  = (unsigned*)alloc((size_t)4 * PLANEU * 4);              // 25.6 MB bf16
    float* hout      = (float*)alloc((size_t)N_NODES * 256 * 4);              // 51.2 MB
    float* H2        = (float*)alloc((size_t)N_NODES * 64 * 4);               // 12.8 MB
    unsigned short* h2b = (unsigned short*)alloc((size_t)N_NODES * 64 * 2);   // 6.4 MB
    float* as2       = (float*)alloc((size_t)N_NODES * 4);
    float* ad2       = (float*)alloc((size_t)N_NODES * 4);
    float* alpha1    = (float*)alloc((size_t)N_EDGES * 4);                    // 3.2 MB
    float* z         = (float*)alloc((size_t)N_NODES * 64 * 4);               // 12.8 MB
    unsigned short* PQb = (unsigned short*)alloc((size_t)N_NODES * 128 * 2);  // 12.8 MB
    float* Bpq       = (float*)alloc((size_t)64 * 128 * 4);

    float* recon_x = (float*)d_out;
    float* recon_e = (float*)d_out + (size_t)N_NODES * F_IN;

    // CSR build (count/scan), attention scalars, then scatter fused with conv1 alphas
    hipMemsetAsync(cnt, 0, (size_t)N_NODES * 4, stream);
    count_kernel<<<(N_EDGES + 255) / 256, 256, 0, stream>>>(ei, cnt);
    scan_kernel<<<1, 1024, 0, stream>>>(cnt, row_start);
    watt_kernel<<<4, 256, 0, stream>>>(W1, att_src1, att_dst1, watt);
    asad_kernel<<<(N_NODES * 64 + 255) / 256, 256, 0, stream>>>(x, watt,
                                                                (float4*)as1, (float4*)ad1);
    hipMemsetAsync(cnt, 0, (size_t)N_NODES * 4, stream);
    scatter_alpha_kernel<<<(N_EDGES + 255) / 256, 256, 0, stream>>>(
        ei, row_start, cnt, (const float4*)as1, (const float4*)ad1,
        esrc, edst, eorig, (float4*)alpha4);

    // bf16 copy of x for gathers
    to_bf16_kernel<<<(N_NODES * 128 / 4 + 255) / 256, 256, 0, stream>>>(x, xb, N_NODES * 128 / 4);

    // conv1 accumulate (scalar-broadcast alphas) + per-head GEMM applies W1
    agg4x_acc_kernel<<<(N_NODES * 64 + 255) / 256, 256, 0, stream>>>(
        xb, (const float4*)as1, (const float4*)ad1, row_start, esrc,
        (const float4*)alpha4, xaggb);
    dim3 gc1((N_NODES + 63) / 64, 4);
    gemm_kernel<true, true, false, true><<<gc1, 256, 0, stream>>>(
        xaggb, 128, (long)PLANE, W1, 256, b1, hout, 256, N_NODES, 128);

    // conv2
    dim3 gc2((N_NODES + 63) / 64, 1);
    gemm_kernel<false, false, false, false><<<gc2, 256, 0, stream>>>(
        hout, 256, 0, W2, 64, nullptr, H2, 64, N_NODES, 256);
    att1_kernel<<<(N_NODES * 64 + 255) / 256, 256, 0, stream>>>(H2, att_src2, att_dst2, as2, ad2);
    alpha1_kernel<<<(N_EDGES + 255) / 256, 256, 0, stream>>>(esrc, edst, as2, ad2, alpha1);
    to_bf16_kernel<<<(N_NODES * 64 / 4 + 255) / 256, 256, 0, stream>>>(H2, h2b, N_NODES * 64 / 4);
    agg1_acc_kernel<<<(N_NODES * 64 + 255) / 256, 256, 0, stream>>>(
        h2b, as2, ad2, row_start, esrc, alpha1, b2, z);

    // node decode
    dim3 gc3((N_NODES + 63) / 64, 2);
    gemm_kernel<true, false, false, false><<<gc3, 256, 0, stream>>>(
        z, 64, 0, Wn, 128, bn, recon_x, 128, N_NODES, 64);

    // edge decode: P|Q precompute (bf16 out) then per-edge fuse (CSR order)
    build_bpq<<<(64 * 128 + 255) / 256, 256, 0, stream>>>(We1, Bpq);
    gemm_kernel<false, false, true, false><<<gc3, 256, 0, stream>>>(
        z, 64, 0, Bpq, 128, nullptr, (float*)PQb, 128, N_NODES, 64);
    edge_decode_kernel<<<ED_BLOCKS, 256, 0, stream>>>(PQb, esrc, edst, eorig, be1, We2, be2, recon_e);
}

// Round 8
// 432.514 us; speedup vs baseline: 2.7784x; 1.0711x over previous
//
#include <hip/hip_runtime.h>

#define N_NODES 50000
#define N_EDGES 800000
#define F_IN    128
#define HEADS   4
#define HID     64
#define LAT     64
#define N_EC    8
#define SLOPE   0.2f
#define PLANE   ((size_t)N_NODES * 128)   // one head's xagg plane (bf16 elements)
#define PLANEU  ((size_t)N_NODES * 64)    // packed 2xbf16 units per plane

__device__ __forceinline__ float lrelu(float x) { return x > 0.f ? x : SLOPE * x; }
__device__ __forceinline__ float4 operator+(float4 a, float4 b) { return make_float4(a.x+b.x, a.y+b.y, a.z+b.z, a.w+b.w); }
__device__ __forceinline__ float4 lrelu4(float4 a) { return make_float4(lrelu(a.x), lrelu(a.y), lrelu(a.z), lrelu(a.w)); }
__device__ __forceinline__ float4 exp4(float4 a) { return make_float4(__expf(a.x), __expf(a.y), __expf(a.z), __expf(a.w)); }

// bf16 helpers (manual, RNE)
__device__ __forceinline__ unsigned short f2bf(float f) {
    union { float f; unsigned u; } a; a.f = f;
    unsigned r = a.u + 0x7fffu + ((a.u >> 16) & 1u);
    return (unsigned short)(r >> 16);
}
__device__ __forceinline__ unsigned pack2bf(float x, float y) {
    return (unsigned)f2bf(x) | ((unsigned)f2bf(y) << 16);
}
__device__ __forceinline__ float2 bf2f2(unsigned u) {
    union { unsigned q; float f; } a, b;
    a.q = u << 16; b.q = u & 0xffff0000u;
    return make_float2(a.f, b.f);
}

// ---------------- CSR build (by dst) ----------------
__global__ void count_kernel(const int* __restrict__ ei, int* __restrict__ cnt) {
    int e = blockIdx.x * blockDim.x + threadIdx.x;
    if (e < N_EDGES) atomicAdd(&cnt[ei[N_EDGES + e]], 1);
}

__global__ __launch_bounds__(1024) void scan_kernel(const int* __restrict__ cnt,
                                                    int* __restrict__ row_start) {
    __shared__ int wsum[16];
    __shared__ int carry;
    int tid = threadIdx.x, lane = tid & 63, w = tid >> 6;
    if (tid == 0) carry = 0;
    __syncthreads();
    for (int base = 0; base < N_NODES; base += 1024) {
        int i = base + tid;
        int v = (i < N_NODES) ? cnt[i] : 0;
        int incl = v;
#pragma unroll
        for (int off = 1; off < 64; off <<= 1) {
            int t = __shfl_up(incl, off, 64);
            if (lane >= off) incl += t;
        }
        if (lane == 63) wsum[w] = incl;
        __syncthreads();
        if (w == 0 && lane < 16) {
            int s = wsum[lane];
            int si = s;
#pragma unroll
            for (int off = 1; off < 16; off <<= 1) {
                int t = __shfl_up(si, off, 64);
                if (lane >= off) si += t;
            }
            wsum[lane] = si - s;  // exclusive prefix of wave sums
        }
        __syncthreads();
        int total_prev = carry;
        if (i < N_NODES) row_start[i] = total_prev + wsum[w] + incl - v;
        __syncthreads();
        if (tid == 1023) carry = total_prev + wsum[15] + incl;
        __syncthreads();
    }
    if (threadIdx.x == 0) row_start[N_NODES] = carry;
}

// scatter: ONE packed random write per edge (int4 = s, d, orig, 0)
__global__ void scatter_pack_kernel(const int* __restrict__ ei, const int* __restrict__ row_start,
                                    int* __restrict__ cursor, int4* __restrict__ edges4) {
    int e = blockIdx.x * blockDim.x + threadIdx.x;
    if (e < N_EDGES) {
        int s = ei[e];
        int d = ei[N_EDGES + e];
        int pos = row_start[d] + atomicAdd(&cursor[d], 1);
        edges4[pos] = make_int4(s, d, e, 0);
    }
}

// CSR-ordered pass: coalesced read of edges4; emit esrc + conv1 alpha (exp without
// max-subtraction: logits are O(1) at this data scale, softmax is shift-invariant)
__global__ void csr_alpha_kernel(const int4* __restrict__ edges4,
                                 const float4* __restrict__ as4, const float4* __restrict__ ad4,
                                 int* __restrict__ esrc, float4* __restrict__ alpha4) {
    int p = blockIdx.x * blockDim.x + threadIdx.x;
    if (p < N_EDGES) {
        int4 t = edges4[p];
        esrc[p] = t.x;
        alpha4[p] = exp4(lrelu4(as4[t.x] + ad4[t.y]));
    }
}

// ---------------- watt[k][j] = sum_c W1[k][h*64+c] * att_{src|dst}[h][c] ----------------
__global__ void watt_kernel(const float* __restrict__ W1, const float* __restrict__ as_,
                            const float* __restrict__ ad_, float* __restrict__ watt) {
    int idx = blockIdx.x * blockDim.x + threadIdx.x;
    if (idx >= 128 * 8) return;
    int k = idx >> 3, j = idx & 7;
    int h = j & 3;
    const float* av = (j < 4) ? as_ : ad_;
    float sum = 0.f;
    for (int c = 0; c < 64; c++) sum += W1[k * 256 + h * 64 + c] * av[h * 64 + c];
    watt[k * 8 + j] = sum;
}

// ---------------- attention scalars from x (+ bf16 copy of x): wave per node ----------------
__global__ __launch_bounds__(256) void asad_kernel(const float* __restrict__ x,
                                                   const float* __restrict__ watt,
                                                   float4* __restrict__ as4,
                                                   float4* __restrict__ ad4,
                                                   unsigned* __restrict__ xb) {
    int wid = (blockIdx.x * blockDim.x + threadIdx.x) >> 6;
    int lane = threadIdx.x & 63;
    if (wid >= N_NODES) return;
    float2 xv = *reinterpret_cast<const float2*>(&x[(size_t)wid * 128 + lane * 2]);
    xb[(size_t)wid * 64 + lane] = pack2bf(xv.x, xv.y);
    float p[8];
    const float* w0 = &watt[(2 * lane) * 8];
    const float* w1 = &watt[(2 * lane + 1) * 8];
#pragma unroll
    for (int j = 0; j < 8; j++) p[j] = fmaf(xv.x, w0[j], xv.y * w1[j]);
#pragma unroll
    for (int off = 32; off; off >>= 1)
#pragma unroll
        for (int j = 0; j < 8; j++) p[j] += __shfl_xor(p[j], off, 64);
    if (lane == 0) {
        as4[wid] = make_float4(p[0], p[1], p[2], p[3]);
        ad4[wid] = make_float4(p[4], p[5], p[6], p[7]);
    }
}

// ---------------- conv1 accumulate: wave/node; alpha+src via uniform SCALAR loads ----------------
__global__ __launch_bounds__(256) void agg4x_acc_kernel(const unsigned short* __restrict__ xb,
                                                        const float4* __restrict__ as4,
                                                        const float4* __restrict__ ad4,
                                                        const int* __restrict__ row_start,
                                                        const int* __restrict__ esrc,
                                                        const float4* __restrict__ alpha4,
                                                        unsigned* __restrict__ xaggb) {
    int wid = (blockIdx.x * blockDim.x + threadIdx.x) >> 6;
    int lane = threadIdx.x & 63;
    if (wid >= N_NODES) return;
    int beg = __builtin_amdgcn_readfirstlane(row_start[wid]);
    int end = __builtin_amdgcn_readfirstlane(row_start[wid + 1]);
    float4 adn = ad4[wid];
    float4 e_self = exp4(lrelu4(as4[wid] + adn));
    float4 den = e_self;
    float2 xv = bf2f2(*reinterpret_cast<const unsigned*>(&xb[(size_t)wid * 128 + lane * 2]));
    float2 acc0 = make_float2(e_self.x * xv.x, e_self.x * xv.y);
    float2 acc1 = make_float2(e_self.y * xv.x, e_self.y * xv.y);
    float2 acc2 = make_float2(e_self.z * xv.x, e_self.z * xv.y);
    float2 acc3 = make_float2(e_self.w * xv.x, e_self.w * xv.y);
    int j = beg;
    for (; j + 1 < end; j += 2) {
        float4 ea = alpha4[j];
        int sa = esrc[j];
        float4 eb = alpha4[j + 1];
        int sb = esrc[j + 1];
        float2 va = bf2f2(*reinterpret_cast<const unsigned*>(&xb[(size_t)sa * 128 + lane * 2]));
        float2 vb = bf2f2(*reinterpret_cast<const unsigned*>(&xb[(size_t)sb * 128 + lane * 2]));
        acc0.x = fmaf(ea.x, va.x, acc0.x); acc0.y = fmaf(ea.x, va.y, acc0.y);
        acc1.x = fmaf(ea.y, va.x, acc1.x); acc1.y = fmaf(ea.y, va.y, acc1.y);
        acc2.x = fmaf(ea.z, va.x, acc2.x); acc2.y = fmaf(ea.z, va.y, acc2.y);
        acc3.x = fmaf(ea.w, va.x, acc3.x); acc3.y = fmaf(ea.w, va.y, acc3.y);
        den = den + ea;
        acc0.x = fmaf(eb.x, vb.x, acc0.x); acc0.y = fmaf(eb.x, vb.y, acc0.y);
        acc1.x = fmaf(eb.y, vb.x, acc1.x); acc1.y = fmaf(eb.y, vb.y, acc1.y);
        acc2.x = fmaf(eb.z, vb.x, acc2.x); acc2.y = fmaf(eb.z, vb.y, acc2.y);
        acc3.x = fmaf(eb.w, vb.x, acc3.x); acc3.y = fmaf(eb.w, vb.y, acc3.y);
        den = den + eb;
    }
    if (j < end) {
        float4 ea = alpha4[j];
        int sa = esrc[j];
        float2 va = bf2f2(*reinterpret_cast<const unsigned*>(&xb[(size_t)sa * 128 + lane * 2]));
        acc0.x = fmaf(ea.x, va.x, acc0.x); acc0.y = fmaf(ea.x, va.y, acc0.y);
        acc1.x = fmaf(ea.y, va.x, acc1.x); acc1.y = fmaf(ea.y, va.y, acc1.y);
        acc2.x = fmaf(ea.z, va.x, acc2.x); acc2.y = fmaf(ea.z, va.y, acc2.y);
        acc3.x = fmaf(ea.w, va.x, acc3.x); acc3.y = fmaf(ea.w, va.y, acc3.y);
        den = den + ea;
    }
    float i0 = 1.f / (den.x + 1e-16f);
    float i1 = 1.f / (den.y + 1e-16f);
    float i2 = 1.f / (den.z + 1e-16f);
    float i3 = 1.f / (den.w + 1e-16f);
    size_t base = (size_t)wid * 64 + lane;
    xaggb[0 * PLANEU + base] = pack2bf(acc0.x * i0, acc0.y * i0);
    xaggb[1 * PLANEU + base] = pack2bf(acc1.x * i1, acc1.y * i1);
    xaggb[2 * PLANEU + base] = pack2bf(acc2.x * i2, acc2.y * i2);
    xaggb[3 * PLANEU + base] = pack2bf(acc3.x * i3, acc3.y * i3);
}

// ---------------- generic tiled GEMM: C = A@B (+bias)(+relu)(+bf16out)(A may be bf16) ----------------
template <bool BIAS, bool RELU, bool BF16OUT, bool ABF16>
__global__ __launch_bounds__(256) void gemm_kernel(const void* __restrict__ Av, int lda,
                                                   long aPlane,
                                                   const float* __restrict__ B, int ldb,
                                                   const float* __restrict__ bias,
                                                   float* __restrict__ C, int ldc,
                                                   int M, int K) {
    __shared__ float As[32][68];
    __shared__ float Bs[32][68];
    int tid = threadIdx.x;
    int brow = blockIdx.x * 64;
    int bcol = blockIdx.y * 64;
    int tr = (tid >> 4) * 4;
    int tc = (tid & 15) * 4;
    float acc[4][4] = {};
    for (int k0 = 0; k0 < K; k0 += 32) {
        if constexpr (ABF16) {
            const unsigned short* A = (const unsigned short*)Av + (size_t)blockIdx.y * aPlane;
            int r = tid >> 2;
            int c8 = (tid & 3) * 8;
            int gr = brow + r;
            uint4 u = make_uint4(0, 0, 0, 0);
            if (gr < M) u = *reinterpret_cast<const uint4*>(&A[(size_t)gr * lda + k0 + c8]);
            float2 f0 = bf2f2(u.x), f1 = bf2f2(u.y), f2 = bf2f2(u.z), f3 = bf2f2(u.w);
            As[c8 + 0][r] = f0.x; As[c8 + 1][r] = f0.y;
            As[c8 + 2][r] = f1.x; As[c8 + 3][r] = f1.y;
            As[c8 + 4][r] = f2.x; As[c8 + 5][r] = f2.y;
            As[c8 + 6][r] = f3.x; As[c8 + 7][r] = f3.y;
        } else {
            const float* A = (const float*)Av + (size_t)blockIdx.y * aPlane;
#pragma unroll
            for (int p = 0; p < 2; p++) {
                int idx = tid + p * 256;
                int r = idx >> 3;
                int c4 = (idx & 7) << 2;
                int gr = brow + r;
                float4 v = make_float4(0.f, 0.f, 0.f, 0.f);
                if (gr < M) v = *reinterpret_cast<const float4*>(&A[(size_t)gr * lda + k0 + c4]);
                As[c4 + 0][r] = v.x; As[c4 + 1][r] = v.y; As[c4 + 2][r] = v.z; As[c4 + 3][r] = v.w;
            }
        }
#pragma unroll
        for (int p = 0; p < 2; p++) {
            int idx = tid + p * 256;
            int r = idx >> 4;
            int c4 = (idx & 15) << 2;
            float4 v = *reinterpret_cast<const float4*>(&B[(size_t)(k0 + r) * ldb + bcol + c4]);
            *reinterpret_cast<float4*>(&Bs[r][c4]) = v;
        }
        __syncthreads();
#pragma unroll
        for (int k = 0; k < 32; k++) {
            float4 a = *reinterpret_cast<const float4*>(&As[k][tr]);
            float4 b = *reinterpret_cast<const float4*>(&Bs[k][tc]);
            acc[0][0] += a.x * b.x; acc[0][1] += a.x * b.y; acc[0][2] += a.x * b.z; acc[0][3] += a.x * b.w;
            acc[1][0] += a.y * b.x; acc[1][1] += a.y * b.y; acc[1][2] += a.y * b.z; acc[1][3] += a.y * b.w;
            acc[2][0] += a.z * b.x; acc[2][1] += a.z * b.y; acc[2][2] += a.z * b.z; acc[2][3] += a.z * b.w;
            acc[3][0] += a.w * b.x; acc[3][1] += a.w * b.y; acc[3][2] += a.w * b.z; acc[3][3] += a.w * b.w;
        }
        __syncthreads();
    }
#pragma unroll
    for (int i = 0; i < 4; i++) {
        int gr = brow + tr + i;
        if (gr < M) {
            float4 v;
            v.x = acc[i][0]; v.y = acc[i][1]; v.z = acc[i][2]; v.w = acc[i][3];
            if (BIAS) {
                const float4 bb = *reinterpret_cast<const float4*>(&bias[bcol + tc]);
                v.x += bb.x; v.y += bb.y; v.z += bb.z; v.w += bb.w;
            }
            if (RELU) {
                v.x = fmaxf(v.x, 0.f); v.y = fmaxf(v.y, 0.f);
                v.z = fmaxf(v.z, 0.f); v.w = fmaxf(v.w, 0.f);
            }
            if (BF16OUT) {
                ushort4 o;
                o.x = f2bf(v.x); o.y = f2bf(v.y); o.z = f2bf(v.z); o.w = f2bf(v.w);
                *reinterpret_cast<ushort4*>(
                    &reinterpret_cast<unsigned short*>(C)[(size_t)gr * ldc + bcol + tc]) = o;
            } else {
                *reinterpret_cast<float4*>(&C[(size_t)gr * ldc + bcol + tc]) = v;
            }
        }
    }
}

// ---------------- conv2 GEMM (K=256, N=64) with fused att-scalar + bf16-out epilogue ----------------
__global__ __launch_bounds__(256) void gemm_conv2_kernel(const float* __restrict__ A,
                                                         const float* __restrict__ W2,
                                                         const float* __restrict__ att_src,
                                                         const float* __restrict__ att_dst,
                                                         unsigned* __restrict__ h2b,
                                                         float* __restrict__ as_,
                                                         float* __restrict__ ad_, int M) {
    __shared__ float As[32][68];
    __shared__ float Bs[32][68];
    int tid = threadIdx.x;
    int brow = blockIdx.x * 64;
    int tr = (tid >> 4) * 4;
    int tc = (tid & 15) * 4;
    float acc[4][4] = {};
    for (int k0 = 0; k0 < 256; k0 += 32) {
#pragma unroll
        for (int p = 0; p < 2; p++) {
            int idx = tid + p * 256;
            int r = idx >> 3;
            int c4 = (idx & 7) << 2;
            int gr = brow + r;
            float4 v = make_float4(0.f, 0.f, 0.f, 0.f);
            if (gr < M) v = *reinterpret_cast<const float4*>(&A[(size_t)gr * 256 + k0 + c4]);
            As[c4 + 0][r] = v.x; As[c4 + 1][r] = v.y; As[c4 + 2][r] = v.z; As[c4 + 3][r] = v.w;
        }
#pragma unroll
        for (int p = 0; p < 2; p++) {
            int idx = tid + p * 256;
            int r = idx >> 4;
            int c4 = (idx & 15) << 2;
            float4 v = *reinterpret_cast<const float4*>(&W2[(size_t)(k0 + r) * 64 + c4]);
            *reinterpret_cast<float4*>(&Bs[r][c4]) = v;
        }
        __syncthreads();
#pragma unroll
        for (int k = 0; k < 32; k++) {
            float4 a = *reinterpret_cast<const float4*>(&As[k][tr]);
            float4 b = *reinterpret_cast<const float4*>(&Bs[k][tc]);
            acc[0][0] += a.x * b.x; acc[0][1] += a.x * b.y; acc[0][2] += a.x * b.z; acc[0][3] += a.x * b.w;
            acc[1][0] += a.y * b.x; acc[1][1] += a.y * b.y; acc[1][2] += a.y * b.z; acc[1][3] += a.y * b.w;
            acc[2][0] += a.z * b.x; acc[2][1] += a.z * b.y; acc[2][2] += a.z * b.z; acc[2][3] += a.z * b.w;
            acc[3][0] += a.w * b.x; acc[3][1] += a.w * b.y; acc[3][2] += a.w * b.z; acc[3][3] += a.w * b.w;
        }
        __syncthreads();
    }
    // epilogue: bf16 H2 + per-row attention scalars (16-lane reduce)
    float4 avs = *reinterpret_cast<const float4*>(&att_src[tc]);
    float4 avd = *reinterpret_cast<const float4*>(&att_dst[tc]);
    float ps[4], pd[4];
#pragma unroll
    for (int i = 0; i < 4; i++) {
        int gr = brow + tr + i;
        if (gr < M) {
            uint2 u;
            u.x = pack2bf(acc[i][0], acc[i][1]);
            u.y = pack2bf(acc[i][2], acc[i][3]);
            *reinterpret_cast<uint2*>(&h2b[(size_t)gr * 32 + tc / 2]) = u;
        }
        ps[i] = acc[i][0] * avs.x + acc[i][1] * avs.y + acc[i][2] * avs.z + acc[i][3] * avs.w;
        pd[i] = acc[i][0] * avd.x + acc[i][1] * avd.y + acc[i][2] * avd.z + acc[i][3] * avd.w;
    }
#pragma unroll
    for (int off = 1; off <= 8; off <<= 1) {
#pragma unroll
        for (int i = 0; i < 4; i++) {
            ps[i] += __shfl_xor(ps[i], off, 64);
            pd[i] += __shfl_xor(pd[i], off, 64);
        }
    }
    if ((tid & 15) == 0) {
#pragma unroll
        for (int i = 0; i < 4; i++) {
            int gr = brow + tr + i;
            if (gr < M) { as_[gr] = ps[i]; ad_[gr] = pd[i]; }
        }
    }
}

// ---------------- conv2 per-edge alpha (CSR order, coalesced) ----------------
__global__ void alpha1_kernel(const int4* __restrict__ edges4,
                              const float* __restrict__ as_, const float* __restrict__ ad_,
                              float* __restrict__ alpha1) {
    int p = blockIdx.x * blockDim.x + threadIdx.x;
    if (p < N_EDGES) {
        int4 t = edges4[p];
        alpha1[p] = __expf(lrelu(as_[t.x] + ad_[t.y]));
    }
}

// ---------------- conv2 accumulate: wave/node, 2 edges/iter, scalar alpha loads ----------------
__global__ __launch_bounds__(256) void agg1_acc_kernel(const unsigned short* __restrict__ h2b,
                                                       const float* __restrict__ as_,
                                                       const float* __restrict__ ad_,
                                                       const int* __restrict__ row_start,
                                                       const int* __restrict__ esrc,
                                                       const float* __restrict__ alpha1,
                                                       const float* __restrict__ bias,
                                                       float* __restrict__ z) {
    int wid = (blockIdx.x * blockDim.x + threadIdx.x) >> 6;
    int lane = threadIdx.x & 63;
    if (wid >= N_NODES) return;
    int g = lane >> 5;
    int c = lane & 31;
    int beg = __builtin_amdgcn_readfirstlane(row_start[wid]);
    int end = __builtin_amdgcn_readfirstlane(row_start[wid + 1]);
    float adn = ad_[wid];
    float e_self = __expf(lrelu(as_[wid] + adn));
    float den = (g == 0) ? e_self : 0.f;
    float2 hv = bf2f2(*reinterpret_cast<const unsigned*>(&h2b[(size_t)wid * 64 + 2 * c]));
    float2 acc = (g == 0) ? make_float2(e_self * hv.x, e_self * hv.y)
                          : make_float2(0.f, 0.f);
    for (int j = beg; j < end; j += 2) {
        float a0 = alpha1[j];
        int s0 = esrc[j];
        float a1 = 0.f;
        int s1 = s0;
        if (j + 1 < end) { a1 = alpha1[j + 1]; s1 = esrc[j + 1]; }
        float e = g ? a1 : a0;
        int s = g ? s1 : s0;
        float2 v = bf2f2(*reinterpret_cast<const unsigned*>(&h2b[(size_t)s * 64 + 2 * c]));
        acc.x = fmaf(e, v.x, acc.x);
        acc.y = fmaf(e, v.y, acc.y);
        den += e;
    }
    den += __shfl_xor(den, 32, 64);
    acc.x += __shfl_xor(acc.x, 32, 64);
    acc.y += __shfl_xor(acc.y, 32, 64);
    if (g == 0) {
        float inv = 1.f / (den + 1e-16f);
        float2 bb = *reinterpret_cast<const float2*>(&bias[2 * c]);
        *reinterpret_cast<float2*>(&z[(size_t)wid * 64 + 2 * c]) =
            make_float2(acc.x * inv + bb.x, acc.y * inv + bb.y);
    }
}

// ---------------- build Bcat = [Wn | Bpq] (64 x 256) ----------------
__global__ void build_bcat(const float* __restrict__ Wn, const float* __restrict__ We1,
                           float* __restrict__ Bcat) {
    int idx = blockIdx.x * blockDim.x + threadIdx.x;
    if (idx < 64 * 256) {
        int k = idx >> 8, j = idx & 255;
        float v;
        if (j < 128) v = Wn[k * 128 + j];
        else {
            int jj = j - 128;
            v = (jj < 64) ? We1[k * 64 + jj] : We1[(64 + k) * 64 + (jj - 64)];
        }
        Bcat[idx] = v;
    }
}

// ---------------- fused decode GEMM: A=z (M x 64); cols 0..127 -> recon_x (fp32+bias),
// cols 128..255 -> PQb (bf16) ----------------
__global__ __launch_bounds__(256) void gemm_decode_kernel(const float* __restrict__ z,
                                                          const float* __restrict__ Bcat,
                                                          const float* __restrict__ bn,
                                                          float* __restrict__ recon_x,
                                                          unsigned short* __restrict__ PQb,
                                                          int M) {
    __shared__ float As[32][68];
    __shared__ float Bs[32][68];
    int tid = threadIdx.x;
    int brow = blockIdx.x * 64;
    int bcol = blockIdx.y * 64;
    int tr = (tid >> 4) * 4;
    int tc = (tid & 15) * 4;
    float acc[4][4] = {};
    for (int k0 = 0; k0 < 64; k0 += 32) {
#pragma unroll
        for (int p = 0; p < 2; p++) {
            int idx = tid + p * 256;
            int r = idx >> 3;
            int c4 = (idx & 7) << 2;
            int gr = brow + r;
            float4 v = make_float4(0.f, 0.f, 0.f, 0.f);
            if (gr < M) v = *reinterpret_cast<const float4*>(&z[(size_t)gr * 64 + k0 + c4]);
            As[c4 + 0][r] = v.x; As[c4 + 1][r] = v.y; As[c4 + 2][r] = v.z; As[c4 + 3][r] = v.w;
        }
#pragma unroll
        for (int p = 0; p < 2; p++) {
            int idx = tid + p * 256;
            int r = idx >> 4;
            int c4 = (idx & 15) << 2;
            float4 v = *reinterpret_cast<const float4*>(&Bcat[(size_t)(k0 + r) * 256 + bcol + c4]);
            *reinterpret_cast<float4*>(&Bs[r][c4]) = v;
        }
        __syncthreads();
#pragma unroll
        for (int k = 0; k < 32; k++) {
            float4 a = *reinterpret_cast<const float4*>(&As[k][tr]);
            float4 b = *reinterpret_cast<const float4*>(&Bs[k][tc]);
            acc[0][0] += a.x * b.x; acc[0][1] += a.x * b.y; acc[0][2] += a.x * b.z; acc[0][3] += a.x * b.w;
            acc[1][0] += a.y * b.x; acc[1][1] += a.y * b.y; acc[1][2] += a.y * b.z; acc[1][3] += a.y * b.w;
            acc[2][0] += a.z * b.x; acc[2][1] += a.z * b.y; acc[2][2] += a.z * b.z; acc[2][3] += a.z * b.w;
            acc[3][0] += a.w * b.x; acc[3][1] += a.w * b.y; acc[3][2] += a.w * b.z; acc[3][3] += a.w * b.w;
        }
        __syncthreads();
    }
#pragma unroll
    for (int i = 0; i < 4; i++) {
        int gr = brow + tr + i;
        if (gr < M) {
            if (bcol < 128) {
                const float4 bb = *reinterpret_cast<const float4*>(&bn[bcol + tc]);
                float4 v = make_float4(acc[i][0] + bb.x, acc[i][1] + bb.y,
                                       acc[i][2] + bb.z, acc[i][3] + bb.w);
                *reinterpret_cast<float4*>(&recon_x[(size_t)gr * 128 + bcol + tc]) = v;
            } else {
                ushort4 o;
                o.x = f2bf(acc[i][0]); o.y = f2bf(acc[i][1]);
                o.z = f2bf(acc[i][2]); o.w = f2bf(acc[i][3]);
                *reinterpret_cast<ushort4*>(&PQb[(size_t)gr * 128 + (bcol - 128) + tc]) = o;
            }
        }
    }
}

// ---------------- edge decode: CSR(dst)-ordered, bf16 PQ, 8 lanes/edge ----------------
#define ED_BLOCKS 2048
__global__ __launch_bounds__(256) void edge_decode_kernel(const unsigned short* __restrict__ PQb,
                                                          const int4* __restrict__ edges4,
                                                          const float* __restrict__ be1,
                                                          const float* __restrict__ We2,
                                                          const float* __restrict__ be2,
                                                          float* __restrict__ out) {
    int lane = threadIdx.x & 63;
    int g = lane >> 3;
    int l8 = lane & 7;
    int c0 = l8 * 8;
    float w[8][8];
#pragma unroll
    for (int i = 0; i < 8; i++) {
        float4 a = *reinterpret_cast<const float4*>(&We2[(c0 + i) * 8]);
        float4 b = *reinterpret_cast<const float4*>(&We2[(c0 + i) * 8 + 4]);
        w[i][0] = a.x; w[i][1] = a.y; w[i][2] = a.z; w[i][3] = a.w;
        w[i][4] = b.x; w[i][5] = b.y; w[i][6] = b.z; w[i][7] = b.w;
    }
    float4 bia = *reinterpret_cast<const float4*>(&be1[c0]);
    float4 bib = *reinterpret_cast<const float4*>(&be1[c0 + 4]);
    float bout = be2[l8];

    int wgid = (blockIdx.x * blockDim.x + threadIdx.x) >> 6;
    const int nwaves = ED_BLOCKS * 4;
    const int ngroups = N_EDGES / 8;
    for (int eg = wgid; eg < ngroups; eg += nwaves) {
        int p = eg * 8 + g;
        int4 t4 = edges4[p];
        int s = t4.x, d = t4.y, o = t4.z;
        uint4 up = *reinterpret_cast<const uint4*>(&PQb[(size_t)s * 128 + c0]);
        uint4 uq = *reinterpret_cast<const uint4*>(&PQb[(size_t)d * 128 + 64 + c0]);
        float2 p0 = bf2f2(up.x), p1 = bf2f2(up.y), p2 = bf2f2(up.z), p3 = bf2f2(up.w);
        float2 q0 = bf2f2(uq.x), q1 = bf2f2(uq.y), q2 = bf2f2(uq.z), q3 = bf2f2(uq.w);
        float t[8];
        t[0] = fmaxf(p0.x + q0.x + bia.x, 0.f);
        t[1] = fmaxf(p0.y + q0.y + bia.y, 0.f);
        t[2] = fmaxf(p1.x + q1.x + bia.z, 0.f);
        t[3] = fmaxf(p1.y + q1.y + bia.w, 0.f);
        t[4] = fmaxf(p2.x + q2.x + bib.x, 0.f);
        t[5] = fmaxf(p2.y + q2.y + bib.y, 0.f);
        t[6] = fmaxf(p3.x + q3.x + bib.z, 0.f);
        t[7] = fmaxf(p3.y + q3.y + bib.w, 0.f);
        float p8[8] = {};
#pragma unroll
        for (int i = 0; i < 8; i++)
#pragma unroll
            for (int jj = 0; jj < 8; jj++) p8[jj] = fmaf(t[i], w[i][jj], p8[jj]);
#pragma unroll
        for (int off = 1; off <= 4; off <<= 1) {
#pragma unroll
            for (int jj = 0; jj < 8; jj++) p8[jj] += __shfl_xor(p8[jj], off, 64);
        }
        float v = p8[0];
        if (l8 == 1) v = p8[1];
        else if (l8 == 2) v = p8[2];
        else if (l8 == 3) v = p8[3];
        else if (l8 == 4) v = p8[4];
        else if (l8 == 5) v = p8[5];
        else if (l8 == 6) v = p8[6];
        else if (l8 == 7) v = p8[7];
        out[(size_t)o * 8 + l8] = v + bout;
    }
}

extern "C" void kernel_launch(void* const* d_in, const int* in_sizes, int n_in,
                              void* d_out, int out_size, void* d_ws, size_t ws_size,
                              hipStream_t stream) {
    const float* x        = (const float*)d_in[0];
    const int*   ei       = (const int*)d_in[1];
    const float* W1       = (const float*)d_in[2];
    const float* att_src1 = (const float*)d_in[3];
    const float* att_dst1 = (const float*)d_in[4];
    const float* b1       = (const float*)d_in[5];
    const float* W2       = (const float*)d_in[6];
    const float* att_src2 = (const float*)d_in[7];
    const float* att_dst2 = (const float*)d_in[8];
    const float* b2       = (const float*)d_in[9];
    const float* Wn       = (const float*)d_in[10];
    const float* bn       = (const float*)d_in[11];
    const float* We1      = (const float*)d_in[12];
    const float* be1      = (const float*)d_in[13];
    const float* We2      = (const float*)d_in[14];
    const float* be2      = (const float*)d_in[15];

    char* ws = (char*)d_ws;
    size_t off = 0;
    auto alloc = [&](size_t bytes) {
        void* p = ws + off;
        off += (bytes + 255) & ~(size_t)255;
        return p;
    };
    int*   cnt       = (int*)alloc((size_t)N_NODES * 4);
    int*   row_start = (int*)alloc((size_t)(N_NODES + 1) * 4);
    int4*  edges4    = (int4*)alloc((size_t)N_EDGES * 16);                    // 12.8 MB
    int*   esrc      = (int*)alloc((size_t)N_EDGES * 4);                      // 3.2 MB
    float* watt      = (float*)alloc((size_t)128 * 8 * 4);
    float* as1       = (float*)alloc((size_t)N_NODES * 4 * 4);
    float* ad1       = (float*)alloc((size_t)N_NODES * 4 * 4);
    unsigned* xb     = (unsigned*)alloc((size_t)N_NODES * 64 * 4);            // 12.8 MB bf16
    float* alpha4    = (float*)alloc((size_t)N_EDGES * 4 * 4);                // 12.8 MB
    unsigned* xaggb  = (unsigned*)alloc((size_t)4 * PLANEU * 4);              // 25.6 MB bf16
    float* hout      = (float*)alloc((size_t)N_NODES * 256 * 4);              // 51.2 MB
    unsigned* h2b    = (unsigned*)alloc((size_t)N_NODES * 32 * 4);            // 6.4 MB bf16
    float* as2       = (float*)alloc((size_t)N_NODES * 4);
    float* ad2       = (float*)alloc((size_t)N_NODES * 4);
    float* alpha1    = (float*)alloc((size_t)N_EDGES * 4);                    // 3.2 MB
    float* z         = (float*)alloc((size_t)N_NODES * 64 * 4);               // 12.8 MB
    unsigned short* PQb = (unsigned short*)alloc((size_t)N_NODES * 128 * 2);  // 12.8 MB
    float* Bcat      = (float*)alloc((size_t)64 * 256 * 4);

    float* recon_x = (float*)d_out;
    float* recon_e = (float*)d_out + (size_t)N_NODES * F_IN;

    // CSR build: count, scan; attention scalars; packed scatter; CSR-ordered alpha pass
    hipMemsetAsync(cnt, 0, (size_t)N_NODES * 4, stream);
    count_kernel<<<(N_EDGES + 255) / 256, 256, 0, stream>>>(ei, cnt);
    scan_kernel<<<1, 1024, 0, stream>>>(cnt, row_start);
    watt_kernel<<<4, 256, 0, stream>>>(W1, att_src1, att_dst1, watt);
    asad_kernel<<<(N_NODES * 64 + 255) / 256, 256, 0, stream>>>(x, watt, (float4*)as1,
                                                                (float4*)ad1, xb);
    hipMemsetAsync(cnt, 0, (size_t)N_NODES * 4, stream);
    scatter_pack_kernel<<<(N_EDGES + 255) / 256, 256, 0, stream>>>(ei, row_start, cnt, edges4);
    csr_alpha_kernel<<<(N_EDGES + 255) / 256, 256, 0, stream>>>(
        edges4, (const float4*)as1, (const float4*)ad1, esrc, (float4*)alpha4);

    // conv1 accumulate + per-head GEMM applies W1
    agg4x_acc_kernel<<<(N_NODES * 64 + 255) / 256, 256, 0, stream>>>(
        (const unsigned short*)xb, (const float4*)as1, (const float4*)ad1, row_start, esrc,
        (const float4*)alpha4, xaggb);
    dim3 gc1((N_NODES + 63) / 64, 4);
    gemm_kernel<true, true, false, true><<<gc1, 256, 0, stream>>>(
        xaggb, 128, (long)PLANE, W1, 256, b1, hout, 256, N_NODES, 128);

    // conv2: GEMM with fused att-scalar + bf16-H2 epilogue, then alpha + accumulate
    gemm_conv2_kernel<<<(N_NODES + 63) / 64, 256, 0, stream>>>(
        hout, W2, att_src2, att_dst2, h2b, as2, ad2, N_NODES);
    alpha1_kernel<<<(N_EDGES + 255) / 256, 256, 0, stream>>>(edges4, as2, ad2, alpha1);
    agg1_acc_kernel<<<(N_NODES * 64 + 255) / 256, 256, 0, stream>>>(
        (const unsigned short*)h2b, as2, ad2, row_start, esrc, alpha1, b2, z);

    // fused decode GEMM: recon_x (fp32) + PQ (bf16) in one pass over z
    build_bcat<<<(64 * 256 + 255) / 256, 256, 0, stream>>>(Wn, We1, Bcat);
    dim3 gdec((N_NODES + 63) / 64, 4);
    gemm_decode_kernel<<<gdec, 256, 0, stream>>>(z, Bcat, bn, recon_x, PQb, N_NODES);

    // edge decode (CSR order, packed edge records)
    edge_decode_kernel<<<ED_BLOCKS, 256, 0, stream>>>(PQb, edges4, be1, We2, be2, recon_e);
}

// Round 9
// 406.398 us; speedup vs baseline: 2.9570x; 1.0643x over previous
//
#include <hip/hip_runtime.h>

#define N_NODES 50000
#define N_EDGES 800000
#define F_IN    128
#define HEADS   4
#define HID     64
#define LAT     64
#define N_EC    8
#define SLOPE   0.2f
#define PLANE   ((size_t)N_NODES * 128)   // one head's xagg plane (bf16 elements)
#define PLANEU  ((size_t)N_NODES * 64)    // packed 2xbf16 units per plane

typedef __attribute__((ext_vector_type(8))) short bf16x8;   // 8 bf16 (4 VGPRs)
typedef __attribute__((ext_vector_type(4))) float f32x4;

__device__ __forceinline__ float lrelu(float x) { return x > 0.f ? x : SLOPE * x; }
__device__ __forceinline__ float4 operator+(float4 a, float4 b) { return make_float4(a.x+b.x, a.y+b.y, a.z+b.z, a.w+b.w); }
__device__ __forceinline__ float4 lrelu4(float4 a) { return make_float4(lrelu(a.x), lrelu(a.y), lrelu(a.z), lrelu(a.w)); }
__device__ __forceinline__ float4 exp4(float4 a) { return make_float4(__expf(a.x), __expf(a.y), __expf(a.z), __expf(a.w)); }

// bf16 helpers (manual, RNE)
__device__ __forceinline__ unsigned short f2bf(float f) {
    union { float f; unsigned u; } a; a.f = f;
    unsigned r = a.u + 0x7fffu + ((a.u >> 16) & 1u);
    return (unsigned short)(r >> 16);
}
__device__ __forceinline__ unsigned pack2bf(float x, float y) {
    return (unsigned)f2bf(x) | ((unsigned)f2bf(y) << 16);
}
__device__ __forceinline__ float2 bf2f2(unsigned u) {
    union { unsigned q; float f; } a, b;
    a.q = u << 16; b.q = u & 0xffff0000u;
    return make_float2(a.f, b.f);
}

// ---------------- CSR build (by dst) ----------------
__global__ void count_kernel(const int* __restrict__ ei, int* __restrict__ cnt) {
    int e = blockIdx.x * blockDim.x + threadIdx.x;
    if (e < N_EDGES) atomicAdd(&cnt[ei[N_EDGES + e]], 1);
}

__global__ __launch_bounds__(1024) void scan_kernel(const int* __restrict__ cnt,
                                                    int* __restrict__ row_start) {
    __shared__ int wsum[16];
    __shared__ int carry;
    int tid = threadIdx.x, lane = tid & 63, w = tid >> 6;
    if (tid == 0) carry = 0;
    __syncthreads();
    for (int base = 0; base < N_NODES; base += 1024) {
        int i = base + tid;
        int v = (i < N_NODES) ? cnt[i] : 0;
        int incl = v;
#pragma unroll
        for (int off = 1; off < 64; off <<= 1) {
            int t = __shfl_up(incl, off, 64);
            if (lane >= off) incl += t;
        }
        if (lane == 63) wsum[w] = incl;
        __syncthreads();
        if (w == 0 && lane < 16) {
            int s = wsum[lane];
            int si = s;
#pragma unroll
            for (int off = 1; off < 16; off <<= 1) {
                int t = __shfl_up(si, off, 64);
                if (lane >= off) si += t;
            }
            wsum[lane] = si - s;  // exclusive prefix of wave sums
        }
        __syncthreads();
        int total_prev = carry;
        if (i < N_NODES) row_start[i] = total_prev + wsum[w] + incl - v;
        __syncthreads();
        if (tid == 1023) carry = total_prev + wsum[15] + incl;
        __syncthreads();
    }
    if (threadIdx.x == 0) row_start[N_NODES] = carry;
}

// scatter: ONE packed random write per edge (int4 = s, d, orig, 0)
__global__ void scatter_pack_kernel(const int* __restrict__ ei, const int* __restrict__ row_start,
                                    int* __restrict__ cursor, int4* __restrict__ edges4) {
    int e = blockIdx.x * blockDim.x + threadIdx.x;
    if (e < N_EDGES) {
        int s = ei[e];
        int d = ei[N_EDGES + e];
        int pos = row_start[d] + atomicAdd(&cursor[d], 1);
        edges4[pos] = make_int4(s, d, e, 0);
    }
}

// CSR-ordered pass: coalesced read of edges4; emit esrc + conv1 alpha (exp without
// max-subtraction: logits are O(1) at this data scale, softmax is shift-invariant)
__global__ void csr_alpha_kernel(const int4* __restrict__ edges4,
                                 const float4* __restrict__ as4, const float4* __restrict__ ad4,
                                 int* __restrict__ esrc, float4* __restrict__ alpha4) {
    int p = blockIdx.x * blockDim.x + threadIdx.x;
    if (p < N_EDGES) {
        int4 t = edges4[p];
        esrc[p] = t.x;
        alpha4[p] = exp4(lrelu4(as4[t.x] + ad4[t.y]));
    }
}

// ---------------- watt[k][j] = sum_c W1[k][h*64+c] * att_{src|dst}[h][c] ----------------
__global__ void watt_kernel(const float* __restrict__ W1, const float* __restrict__ as_,
                            const float* __restrict__ ad_, float* __restrict__ watt) {
    int idx = blockIdx.x * blockDim.x + threadIdx.x;
    if (idx >= 128 * 8) return;
    int k = idx >> 3, j = idx & 7;
    int h = j & 3;
    const float* av = (j < 4) ? as_ : ad_;
    float sum = 0.f;
    for (int c = 0; c < 64; c++) sum += W1[k * 256 + h * 64 + c] * av[h * 64 + c];
    watt[k * 8 + j] = sum;
}

// ---------------- bf16 transposed weights for MFMA GEMMs ----------------
// Bt1[n][k]=W1[k][n] (256x128); Bt2[n][k]=W2[k][n] (64x256); Btd[n][k] (256x64):
//   n<128 -> Wn[k][n]; 128<=n<192 -> We1[k][n-128]; 192<=n -> We1[64+k][n-192]
__global__ void build_wts_kernel(const float* __restrict__ W1, const float* __restrict__ W2,
                                 const float* __restrict__ Wn, const float* __restrict__ We1,
                                 unsigned short* __restrict__ Bt1, unsigned short* __restrict__ Bt2,
                                 unsigned short* __restrict__ Btd) {
    int idx = blockIdx.x * blockDim.x + threadIdx.x;
    if (idx < 256 * 128) {
        int n = idx >> 7, k = idx & 127;
        Bt1[idx] = f2bf(W1[k * 256 + n]);
    }
    if (idx < 64 * 256) {
        int n = idx >> 8, k = idx & 255;
        Bt2[idx] = f2bf(W2[k * 64 + n]);
    }
    if (idx < 256 * 64) {
        int n = idx >> 6, k = idx & 63;
        float v;
        if (n < 128) v = Wn[k * 128 + n];
        else {
            int nn = n - 128;
            v = (nn < 64) ? We1[k * 64 + nn] : We1[(64 + k) * 64 + (nn - 64)];
        }
        Btd[idx] = f2bf(v);
    }
}

// ---------------- attention scalars from x (+ bf16 copy of x): wave per node ----------------
__global__ __launch_bounds__(256) void asad_kernel(const float* __restrict__ x,
                                                   const float* __restrict__ watt,
                                                   float4* __restrict__ as4,
                                                   float4* __restrict__ ad4,
                                                   unsigned* __restrict__ xb) {
    int wid = (blockIdx.x * blockDim.x + threadIdx.x) >> 6;
    int lane = threadIdx.x & 63;
    if (wid >= N_NODES) return;
    float2 xv = *reinterpret_cast<const float2*>(&x[(size_t)wid * 128 + lane * 2]);
    xb[(size_t)wid * 64 + lane] = pack2bf(xv.x, xv.y);
    float p[8];
    const float* w0 = &watt[(2 * lane) * 8];
    const float* w1 = &watt[(2 * lane + 1) * 8];
#pragma unroll
    for (int j = 0; j < 8; j++) p[j] = fmaf(xv.x, w0[j], xv.y * w1[j]);
#pragma unroll
    for (int off = 32; off; off >>= 1)
#pragma unroll
        for (int j = 0; j < 8; j++) p[j] += __shfl_xor(p[j], off, 64);
    if (lane == 0) {
        as4[wid] = make_float4(p[0], p[1], p[2], p[3]);
        ad4[wid] = make_float4(p[4], p[5], p[6], p[7]);
    }
}

// ---------------- conv1 accumulate: wave/node; alpha+src via uniform SCALAR loads ----------------
__global__ __launch_bounds__(256) void agg4x_acc_kernel(const unsigned short* __restrict__ xb,
                                                        const float4* __restrict__ as4,
                                                        const float4* __restrict__ ad4,
                                                        const int* __restrict__ row_start,
                                                        const int* __restrict__ esrc,
                                                        const float4* __restrict__ alpha4,
                                                        unsigned* __restrict__ xaggb) {
    int wid = (blockIdx.x * blockDim.x + threadIdx.x) >> 6;
    int lane = threadIdx.x & 63;
    if (wid >= N_NODES) return;
    int beg = __builtin_amdgcn_readfirstlane(row_start[wid]);
    int end = __builtin_amdgcn_readfirstlane(row_start[wid + 1]);
    float4 adn = ad4[wid];
    float4 e_self = exp4(lrelu4(as4[wid] + adn));
    float4 den = e_self;
    float2 xv = bf2f2(*reinterpret_cast<const unsigned*>(&xb[(size_t)wid * 128 + lane * 2]));
    float2 acc0 = make_float2(e_self.x * xv.x, e_self.x * xv.y);
    float2 acc1 = make_float2(e_self.y * xv.x, e_self.y * xv.y);
    float2 acc2 = make_float2(e_self.z * xv.x, e_self.z * xv.y);
    float2 acc3 = make_float2(e_self.w * xv.x, e_self.w * xv.y);
    int j = beg;
    for (; j + 1 < end; j += 2) {
        float4 ea = alpha4[j];
        int sa = esrc[j];
        float4 eb = alpha4[j + 1];
        int sb = esrc[j + 1];
        float2 va = bf2f2(*reinterpret_cast<const unsigned*>(&xb[(size_t)sa * 128 + lane * 2]));
        float2 vb = bf2f2(*reinterpret_cast<const unsigned*>(&xb[(size_t)sb * 128 + lane * 2]));
        acc0.x = fmaf(ea.x, va.x, acc0.x); acc0.y = fmaf(ea.x, va.y, acc0.y);
        acc1.x = fmaf(ea.y, va.x, acc1.x); acc1.y = fmaf(ea.y, va.y, acc1.y);
        acc2.x = fmaf(ea.z, va.x, acc2.x); acc2.y = fmaf(ea.z, va.y, acc2.y);
        acc3.x = fmaf(ea.w, va.x, acc3.x); acc3.y = fmaf(ea.w, va.y, acc3.y);
        den = den + ea;
        acc0.x = fmaf(eb.x, vb.x, acc0.x); acc0.y = fmaf(eb.x, vb.y, acc0.y);
        acc1.x = fmaf(eb.y, vb.x, acc1.x); acc1.y = fmaf(eb.y, vb.y, acc1.y);
        acc2.x = fmaf(eb.z, vb.x, acc2.x); acc2.y = fmaf(eb.z, vb.y, acc2.y);
        acc3.x = fmaf(eb.w, vb.x, acc3.x); acc3.y = fmaf(eb.w, vb.y, acc3.y);
        den = den + eb;
    }
    if (j < end) {
        float4 ea = alpha4[j];
        int sa = esrc[j];
        float2 va = bf2f2(*reinterpret_cast<const unsigned*>(&xb[(size_t)sa * 128 + lane * 2]));
        acc0.x = fmaf(ea.x, va.x, acc0.x); acc0.y = fmaf(ea.x, va.y, acc0.y);
        acc1.x = fmaf(ea.y, va.x, acc1.x); acc1.y = fmaf(ea.y, va.y, acc1.y);
        acc2.x = fmaf(ea.z, va.x, acc2.x); acc2.y = fmaf(ea.z, va.y, acc2.y);
        acc3.x = fmaf(ea.w, va.x, acc3.x); acc3.y = fmaf(ea.w, va.y, acc3.y);
        den = den + ea;
    }
    float i0 = 1.f / (den.x + 1e-16f);
    float i1 = 1.f / (den.y + 1e-16f);
    float i2 = 1.f / (den.z + 1e-16f);
    float i3 = 1.f / (den.w + 1e-16f);
    size_t base = (size_t)wid * 64 + lane;
    xaggb[0 * PLANEU + base] = pack2bf(acc0.x * i0, acc0.y * i0);
    xaggb[1 * PLANEU + base] = pack2bf(acc1.x * i1, acc1.y * i1);
    xaggb[2 * PLANEU + base] = pack2bf(acc2.x * i2, acc2.y * i2);
    xaggb[3 * PLANEU + base] = pack2bf(acc3.x * i3, acc3.y * i3);
}

// ================= MFMA GEMMs (16x16x32 bf16, LDS-free) =================
// A: bf16 row-major [M][lda]; Bt: bf16 [N][K] (transposed weights, L1-resident).
// Wave computes 16 rows x 64 cols. A-frag: lane reads A[row=l&15][k=(l>>4)*8..+8].
// B-frag: lane reads Bt[col=l&15][k=(l>>4)*8..+8]. C/D: col=lane&15, row=(lane>>4)*4+reg.

// conv1: per-head (blockIdx.y): A plane, cols [y*64, y*64+64); bias+relu, bf16 out
template <int K>
__global__ __launch_bounds__(256) void mfma_gemm1_kernel(const unsigned short* __restrict__ A,
                                                         int lda, long aPlane,
                                                         const unsigned short* __restrict__ Bt,
                                                         const float* __restrict__ bias,
                                                         unsigned short* __restrict__ C, int ldc,
                                                         int M) {
    int tid = threadIdx.x;
    int w = tid >> 6, l = tid & 63;
    int bcol = blockIdx.y * 64;
    A += (size_t)blockIdx.y * aPlane;
    int row_a = blockIdx.x * 64 + w * 16 + (l & 15);
    int kq = (l >> 4) * 8;
    bool aval = row_a < M;
    const unsigned short* Arow = A + (size_t)row_a * lda;
    f32x4 acc[4] = {};
#pragma unroll
    for (int kb = 0; kb < K / 32; kb++) {
        int k0 = kb * 32 + kq;
        bf16x8 a = {};
        if (aval) a = *reinterpret_cast<const bf16x8*>(&Arow[k0]);
#pragma unroll
        for (int nb = 0; nb < 4; nb++) {
            bf16x8 b = *reinterpret_cast<const bf16x8*>(
                &Bt[(size_t)(bcol + nb * 16 + (l & 15)) * K + k0]);
            acc[nb] = __builtin_amdgcn_mfma_f32_16x16x32_bf16(a, b, acc[nb], 0, 0, 0);
        }
    }
    int orow = blockIdx.x * 64 + w * 16 + (l >> 4) * 4;
#pragma unroll
    for (int nb = 0; nb < 4; nb++) {
        int col = bcol + nb * 16 + (l & 15);
        float bb = bias[col];
#pragma unroll
        for (int r = 0; r < 4; r++) {
            int row = orow + r;
            if (row < M) C[(size_t)row * ldc + col] = f2bf(fmaxf(acc[nb][r] + bb, 0.f));
        }
    }
}

// conv2 (K=256, N=64): bf16 H2 out + fused per-row attention scalars (from fp32 acc)
__global__ __launch_bounds__(256) void mfma_gemm2_kernel(const unsigned short* __restrict__ A,
                                                         const unsigned short* __restrict__ Bt,
                                                         const float* __restrict__ att_src,
                                                         const float* __restrict__ att_dst,
                                                         unsigned short* __restrict__ h2b,
                                                         float* __restrict__ as_,
                                                         float* __restrict__ ad_, int M) {
    int tid = threadIdx.x;
    int w = tid >> 6, l = tid & 63;
    int row_a = blockIdx.x * 64 + w * 16 + (l & 15);
    int kq = (l >> 4) * 8;
    bool aval = row_a < M;
    const unsigned short* Arow = A + (size_t)row_a * 256;
    f32x4 acc[4] = {};
#pragma unroll
    for (int kb = 0; kb < 8; kb++) {
        int k0 = kb * 32 + kq;
        bf16x8 a = {};
        if (aval) a = *reinterpret_cast<const bf16x8*>(&Arow[k0]);
#pragma unroll
        for (int nb = 0; nb < 4; nb++) {
            bf16x8 b = *reinterpret_cast<const bf16x8*>(
                &Bt[(size_t)(nb * 16 + (l & 15)) * 256 + k0]);
            acc[nb] = __builtin_amdgcn_mfma_f32_16x16x32_bf16(a, b, acc[nb], 0, 0, 0);
        }
    }
    int orow = blockIdx.x * 64 + w * 16 + (l >> 4) * 4;
    float ps[4] = {}, pd[4] = {};
#pragma unroll
    for (int nb = 0; nb < 4; nb++) {
        int col = nb * 16 + (l & 15);
        float s = att_src[col], dd = att_dst[col];
#pragma unroll
        for (int r = 0; r < 4; r++) {
            float v = acc[nb][r];
            ps[r] = fmaf(v, s, ps[r]);
            pd[r] = fmaf(v, dd, pd[r]);
            int row = orow + r;
            if (row < M) h2b[(size_t)row * 64 + col] = f2bf(v);
        }
    }
#pragma unroll
    for (int off = 1; off <= 8; off <<= 1)
#pragma unroll
        for (int r = 0; r < 4; r++) {
            ps[r] += __shfl_xor(ps[r], off, 64);
            pd[r] += __shfl_xor(pd[r], off, 64);
        }
    if ((l & 15) == 0) {
#pragma unroll
        for (int r = 0; r < 4; r++) {
            int row = orow + r;
            if (row < M) { as_[row] = ps[r]; ad_[row] = pd[r]; }
        }
    }
}

// decode (K=64, N=256): cols<128 -> recon_x fp32 (+bn); cols>=128 -> PQb bf16
__global__ __launch_bounds__(256) void mfma_gemm_decode_kernel(const unsigned short* __restrict__ zb,
                                                               const unsigned short* __restrict__ Btd,
                                                               const float* __restrict__ bn,
                                                               float* __restrict__ recon_x,
                                                               unsigned short* __restrict__ PQb,
                                                               int M) {
    int tid = threadIdx.x;
    int w = tid >> 6, l = tid & 63;
    int bcol = blockIdx.y * 64;
    int row_a = blockIdx.x * 64 + w * 16 + (l & 15);
    int kq = (l >> 4) * 8;
    bool aval = row_a < M;
    const unsigned short* Arow = zb + (size_t)row_a * 64;
    f32x4 acc[4] = {};
#pragma unroll
    for (int kb = 0; kb < 2; kb++) {
        int k0 = kb * 32 + kq;
        bf16x8 a = {};
        if (aval) a = *reinterpret_cast<const bf16x8*>(&Arow[k0]);
#pragma unroll
        for (int nb = 0; nb < 4; nb++) {
            bf16x8 b = *reinterpret_cast<const bf16x8*>(
                &Btd[(size_t)(bcol + nb * 16 + (l & 15)) * 64 + k0]);
            acc[nb] = __builtin_amdgcn_mfma_f32_16x16x32_bf16(a, b, acc[nb], 0, 0, 0);
        }
    }
    int orow = blockIdx.x * 64 + w * 16 + (l >> 4) * 4;
#pragma unroll
    for (int nb = 0; nb < 4; nb++) {
        int col = bcol + nb * 16 + (l & 15);
        if (col < 128) {
            float bb = bn[col];
#pragma unroll
            for (int r = 0; r < 4; r++) {
                int row = orow + r;
                if (row < M) recon_x[(size_t)row * 128 + col] = acc[nb][r] + bb;
            }
        } else {
#pragma unroll
            for (int r = 0; r < 4; r++) {
                int row = orow + r;
                if (row < M) PQb[(size_t)row * 128 + (col - 128)] = f2bf(acc[nb][r]);
            }
        }
    }
}

// ---------------- conv2 per-edge alpha (CSR order, coalesced) ----------------
__global__ void alpha1_kernel(const int4* __restrict__ edges4,
                              const float* __restrict__ as_, const float* __restrict__ ad_,
                              float* __restrict__ alpha1) {
    int p = blockIdx.x * blockDim.x + threadIdx.x;
    if (p < N_EDGES) {
        int4 t = edges4[p];
        alpha1[p] = __expf(lrelu(as_[t.x] + ad_[t.y]));
    }
}

// ---------------- conv2 accumulate: wave/node, 2 edges/iter, bf16 z out ----------------
__global__ __launch_bounds__(256) void agg1_acc_kernel(const unsigned short* __restrict__ h2b,
                                                       const float* __restrict__ as_,
                                                       const float* __restrict__ ad_,
                                                       const int* __restrict__ row_start,
                                                       const int* __restrict__ esrc,
                                                       const float* __restrict__ alpha1,
                                                       const float* __restrict__ bias,
                                                       unsigned* __restrict__ zb) {
    int wid = (blockIdx.x * blockDim.x + threadIdx.x) >> 6;
    int lane = threadIdx.x & 63;
    if (wid >= N_NODES) return;
    int g = lane >> 5;
    int c = lane & 31;
    int beg = __builtin_amdgcn_readfirstlane(row_start[wid]);
    int end = __builtin_amdgcn_readfirstlane(row_start[wid + 1]);
    float adn = ad_[wid];
    float e_self = __expf(lrelu(as_[wid] + adn));
    float den = (g == 0) ? e_self : 0.f;
    float2 hv = bf2f2(*reinterpret_cast<const unsigned*>(&h2b[(size_t)wid * 64 + 2 * c]));
    float2 acc = (g == 0) ? make_float2(e_self * hv.x, e_self * hv.y)
                          : make_float2(0.f, 0.f);
    for (int j = beg; j < end; j += 2) {
        float a0 = alpha1[j];
        int s0 = esrc[j];
        float a1 = 0.f;
        int s1 = s0;
        if (j + 1 < end) { a1 = alpha1[j + 1]; s1 = esrc[j + 1]; }
        float e = g ? a1 : a0;
        int s = g ? s1 : s0;
        float2 v = bf2f2(*reinterpret_cast<const unsigned*>(&h2b[(size_t)s * 64 + 2 * c]));
        acc.x = fmaf(e, v.x, acc.x);
        acc.y = fmaf(e, v.y, acc.y);
        den += e;
    }
    den += __shfl_xor(den, 32, 64);
    acc.x += __shfl_xor(acc.x, 32, 64);
    acc.y += __shfl_xor(acc.y, 32, 64);
    if (g == 0) {
        float inv = 1.f / (den + 1e-16f);
        float2 bb = *reinterpret_cast<const float2*>(&bias[2 * c]);
        zb[(size_t)wid * 32 + c] = pack2bf(acc.x * inv + bb.x, acc.y * inv + bb.y);
    }
}

// ---------------- edge decode: CSR(dst)-ordered, bf16 PQ, 8 lanes/edge ----------------
#define ED_BLOCKS 2048
__global__ __launch_bounds__(256) void edge_decode_kernel(const unsigned short* __restrict__ PQb,
                                                          const int4* __restrict__ edges4,
                                                          const float* __restrict__ be1,
                                                          const float* __restrict__ We2,
                                                          const float* __restrict__ be2,
                                                          float* __restrict__ out) {
    int lane = threadIdx.x & 63;
    int g = lane >> 3;
    int l8 = lane & 7;
    int c0 = l8 * 8;
    float w[8][8];
#pragma unroll
    for (int i = 0; i < 8; i++) {
        float4 a = *reinterpret_cast<const float4*>(&We2[(c0 + i) * 8]);
        float4 b = *reinterpret_cast<const float4*>(&We2[(c0 + i) * 8 + 4]);
        w[i][0] = a.x; w[i][1] = a.y; w[i][2] = a.z; w[i][3] = a.w;
        w[i][4] = b.x; w[i][5] = b.y; w[i][6] = b.z; w[i][7] = b.w;
    }
    float4 bia = *reinterpret_cast<const float4*>(&be1[c0]);
    float4 bib = *reinterpret_cast<const float4*>(&be1[c0 + 4]);
    float bout = be2[l8];

    int wgid = (blockIdx.x * blockDim.x + threadIdx.x) >> 6;
    const int nwaves = ED_BLOCKS * 4;
    const int ngroups = N_EDGES / 8;
    for (int eg = wgid; eg < ngroups; eg += nwaves) {
        int p = eg * 8 + g;
        int4 t4 = edges4[p];
        int s = t4.x, d = t4.y, o = t4.z;
        uint4 up = *reinterpret_cast<const uint4*>(&PQb[(size_t)s * 128 + c0]);
        uint4 uq = *reinterpret_cast<const uint4*>(&PQb[(size_t)d * 128 + 64 + c0]);
        float2 p0 = bf2f2(up.x), p1 = bf2f2(up.y), p2 = bf2f2(up.z), p3 = bf2f2(up.w);
        float2 q0 = bf2f2(uq.x), q1 = bf2f2(uq.y), q2 = bf2f2(uq.z), q3 = bf2f2(uq.w);
        float t[8];
        t[0] = fmaxf(p0.x + q0.x + bia.x, 0.f);
        t[1] = fmaxf(p0.y + q0.y + bia.y, 0.f);
        t[2] = fmaxf(p1.x + q1.x + bia.z, 0.f);
        t[3] = fmaxf(p1.y + q1.y + bia.w, 0.f);
        t[4] = fmaxf(p2.x + q2.x + bib.x, 0.f);
        t[5] = fmaxf(p2.y + q2.y + bib.y, 0.f);
        t[6] = fmaxf(p3.x + q3.x + bib.z, 0.f);
        t[7] = fmaxf(p3.y + q3.y + bib.w, 0.f);
        float p8[8] = {};
#pragma unroll
        for (int i = 0; i < 8; i++)
#pragma unroll
            for (int jj = 0; jj < 8; jj++) p8[jj] = fmaf(t[i], w[i][jj], p8[jj]);
#pragma unroll
        for (int off = 1; off <= 4; off <<= 1) {
#pragma unroll
            for (int jj = 0; jj < 8; jj++) p8[jj] += __shfl_xor(p8[jj], off, 64);
        }
        float v = p8[0];
        if (l8 == 1) v = p8[1];
        else if (l8 == 2) v = p8[2];
        else if (l8 == 3) v = p8[3];
        else if (l8 == 4) v = p8[4];
        else if (l8 == 5) v = p8[5];
        else if (l8 == 6) v = p8[6];
        else if (l8 == 7) v = p8[7];
        out[(size_t)o * 8 + l8] = v + bout;
    }
}

extern "C" void kernel_launch(void* const* d_in, const int* in_sizes, int n_in,
                              void* d_out, int out_size, void* d_ws, size_t ws_size,
                              hipStream_t stream) {
    const float* x        = (const float*)d_in[0];
    const int*   ei       = (const int*)d_in[1];
    const float* W1       = (const float*)d_in[2];
    const float* att_src1 = (const float*)d_in[3];
    const float* att_dst1 = (const float*)d_in[4];
    const float* b1       = (const float*)d_in[5];
    const float* W2       = (const float*)d_in[6];
    const float* att_src2 = (const float*)d_in[7];
    const float* att_dst2 = (const float*)d_in[8];
    const float* b2       = (const float*)d_in[9];
    const float* Wn       = (const float*)d_in[10];
    const float* bn       = (const float*)d_in[11];
    const float* We1      = (const float*)d_in[12];
    const float* be1      = (const float*)d_in[13];
    const float* We2      = (const float*)d_in[14];
    const float* be2      = (const float*)d_in[15];

    char* ws = (char*)d_ws;
    size_t off = 0;
    auto alloc = [&](size_t bytes) {
        void* p = ws + off;
        off += (bytes + 255) & ~(size_t)255;
        return p;
    };
    int*   cnt       = (int*)alloc((size_t)N_NODES * 4);
    int*   row_start = (int*)alloc((size_t)(N_NODES + 1) * 4);
    int4*  edges4    = (int4*)alloc((size_t)N_EDGES * 16);                    // 12.8 MB
    int*   esrc      = (int*)alloc((size_t)N_EDGES * 4);                      // 3.2 MB
    float* watt      = (float*)alloc((size_t)128 * 8 * 4);
    float* as1       = (float*)alloc((size_t)N_NODES * 4 * 4);
    float* ad1       = (float*)alloc((size_t)N_NODES * 4 * 4);
    unsigned* xb     = (unsigned*)alloc((size_t)N_NODES * 64 * 4);            // 12.8 MB bf16
    float* alpha4    = (float*)alloc((size_t)N_EDGES * 4 * 4);                // 12.8 MB
    unsigned* xaggb  = (unsigned*)alloc((size_t)4 * PLANEU * 4);              // 25.6 MB bf16
    unsigned short* houtb = (unsigned short*)alloc((size_t)N_NODES * 256 * 2); // 25.6 MB bf16
    unsigned* h2b    = (unsigned*)alloc((size_t)N_NODES * 32 * 4);            // 6.4 MB bf16
    float* as2       = (float*)alloc((size_t)N_NODES * 4);
    float* ad2       = (float*)alloc((size_t)N_NODES * 4);
    float* alpha1    = (float*)alloc((size_t)N_EDGES * 4);                    // 3.2 MB
    unsigned* zb     = (unsigned*)alloc((size_t)N_NODES * 32 * 4);            // 6.4 MB bf16
    unsigned short* PQb = (unsigned short*)alloc((size_t)N_NODES * 128 * 2);  // 12.8 MB
    unsigned short* Bt1 = (unsigned short*)alloc((size_t)256 * 128 * 2);
    unsigned short* Bt2 = (unsigned short*)alloc((size_t)64 * 256 * 2);
    unsigned short* Btd = (unsigned short*)alloc((size_t)256 * 64 * 2);

    float* recon_x = (float*)d_out;
    float* recon_e = (float*)d_out + (size_t)N_NODES * F_IN;

    // CSR build: count, scan; attention scalars; packed scatter; CSR-ordered alpha pass
    hipMemsetAsync(cnt, 0, (size_t)N_NODES * 4, stream);
    count_kernel<<<(N_EDGES + 255) / 256, 256, 0, stream>>>(ei, cnt);
    scan_kernel<<<1, 1024, 0, stream>>>(cnt, row_start);
    watt_kernel<<<4, 256, 0, stream>>>(W1, att_src1, att_dst1, watt);
    build_wts_kernel<<<128, 256, 0, stream>>>(W1, W2, Wn, We1, Bt1, Bt2, Btd);
    asad_kernel<<<(N_NODES * 64 + 255) / 256, 256, 0, stream>>>(x, watt, (float4*)as1,
                                                                (float4*)ad1, xb);
    hipMemsetAsync(cnt, 0, (size_t)N_NODES * 4, stream);
    scatter_pack_kernel<<<(N_EDGES + 255) / 256, 256, 0, stream>>>(ei, row_start, cnt, edges4);
    csr_alpha_kernel<<<(N_EDGES + 255) / 256, 256, 0, stream>>>(
        edges4, (const float4*)as1, (const float4*)ad1, esrc, (float4*)alpha4);

    // conv1 accumulate + per-head MFMA GEMM applies W1 (bf16 out)
    agg4x_acc_kernel<<<(N_NODES * 64 + 255) / 256, 256, 0, stream>>>(
        (const unsigned short*)xb, (const float4*)as1, (const float4*)ad1, row_start, esrc,
        (const float4*)alpha4, xaggb);
    dim3 gc1((N_NODES + 63) / 64, 4);
    mfma_gemm1_kernel<128><<<gc1, 256, 0, stream>>>(
        (const unsigned short*)xaggb, 128, (long)PLANE, Bt1, b1, houtb, 256, N_NODES);

    // conv2: MFMA GEMM with fused att-scalar epilogue, then alpha + accumulate
    mfma_gemm2_kernel<<<(N_NODES + 63) / 64, 256, 0, stream>>>(
        houtb, Bt2, att_src2, att_dst2, (unsigned short*)h2b, as2, ad2, N_NODES);
    alpha1_kernel<<<(N_EDGES + 255) / 256, 256, 0, stream>>>(edges4, as2, ad2, alpha1);
    agg1_acc_kernel<<<(N_NODES * 64 + 255) / 256, 256, 0, stream>>>(
        (const unsigned short*)h2b, as2, ad2, row_start, esrc, alpha1, b2, zb);

    // fused decode MFMA GEMM: recon_x (fp32) + PQ (bf16) in one pass over zb
    dim3 gdec((N_NODES + 63) / 64, 4);
    mfma_gemm_decode_kernel<<<gdec, 256, 0, stream>>>(
        (const unsigned short*)zb, Btd, bn, recon_x, PQb, N_NODES);

    // edge decode (CSR order, packed edge records)
    edge_decode_kernel<<<ED_BLOCKS, 256, 0, stream>>>(PQb, edges4, be1, We2, be2, recon_e);
}

// Round 10
// 387.526 us; speedup vs baseline: 3.1010x; 1.0487x over previous
//
#include <hip/hip_runtime.h>

#define N_NODES 50000
#define N_EDGES 800000
#define F_IN    128
#define HEADS   4
#define HID     64
#define LAT     64
#define N_EC    8
#define SLOPE   0.2f
#define PLANE   ((size_t)N_NODES * 128)   // one head's xagg plane (bf16 elements)
#define PLANEU  ((size_t)N_NODES * 64)    // packed 2xbf16 units per plane

typedef __attribute__((ext_vector_type(8))) short bf16x8;   // 8 bf16 (4 VGPRs)
typedef __attribute__((ext_vector_type(4))) float f32x4;

__device__ __forceinline__ float lrelu(float x) { return x > 0.f ? x : SLOPE * x; }
__device__ __forceinline__ float4 operator+(float4 a, float4 b) { return make_float4(a.x+b.x, a.y+b.y, a.z+b.z, a.w+b.w); }
__device__ __forceinline__ float4 lrelu4(float4 a) { return make_float4(lrelu(a.x), lrelu(a.y), lrelu(a.z), lrelu(a.w)); }
__device__ __forceinline__ float4 exp4(float4 a) { return make_float4(__expf(a.x), __expf(a.y), __expf(a.z), __expf(a.w)); }

// bf16 helpers (manual, RNE)
__device__ __forceinline__ unsigned short f2bf(float f) {
    union { float f; unsigned u; } a; a.f = f;
    unsigned r = a.u + 0x7fffu + ((a.u >> 16) & 1u);
    return (unsigned short)(r >> 16);
}
__device__ __forceinline__ unsigned pack2bf(float x, float y) {
    return (unsigned)f2bf(x) | ((unsigned)f2bf(y) << 16);
}
__device__ __forceinline__ float2 bf2f2(unsigned u) {
    union { unsigned q; float f; } a, b;
    a.q = u << 16; b.q = u & 0xffff0000u;
    return make_float2(a.f, b.f);
}

// ---------------- CSR build (by dst) ----------------
__global__ void count_kernel(const int* __restrict__ ei, int* __restrict__ cnt) {
    int e = blockIdx.x * blockDim.x + threadIdx.x;
    if (e < N_EDGES) atomicAdd(&cnt[ei[N_EDGES + e]], 1);
}

__global__ __launch_bounds__(1024) void scan_kernel(const int* __restrict__ cnt,
                                                    int* __restrict__ row_start) {
    __shared__ int wsum[16];
    __shared__ int carry;
    int tid = threadIdx.x, lane = tid & 63, w = tid >> 6;
    if (tid == 0) carry = 0;
    __syncthreads();
    for (int base = 0; base < N_NODES; base += 1024) {
        int i = base + tid;
        int v = (i < N_NODES) ? cnt[i] : 0;
        int incl = v;
#pragma unroll
        for (int off = 1; off < 64; off <<= 1) {
            int t = __shfl_up(incl, off, 64);
            if (lane >= off) incl += t;
        }
        if (lane == 63) wsum[w] = incl;
        __syncthreads();
        if (w == 0 && lane < 16) {
            int s = wsum[lane];
            int si = s;
#pragma unroll
            for (int off = 1; off < 16; off <<= 1) {
                int t = __shfl_up(si, off, 64);
                if (lane >= off) si += t;
            }
            wsum[lane] = si - s;  // exclusive prefix of wave sums
        }
        __syncthreads();
        int total_prev = carry;
        if (i < N_NODES) row_start[i] = total_prev + wsum[w] + incl - v;
        __syncthreads();
        if (tid == 1023) carry = total_prev + wsum[15] + incl;
        __syncthreads();
    }
    if (threadIdx.x == 0) row_start[N_NODES] = carry;
}

// scatter: ONE packed random write per edge (int4 = s, d, orig, 0)
__global__ void scatter_pack_kernel(const int* __restrict__ ei, const int* __restrict__ row_start,
                                    int* __restrict__ cursor, int4* __restrict__ edges4) {
    int e = blockIdx.x * blockDim.x + threadIdx.x;
    if (e < N_EDGES) {
        int s = ei[e];
        int d = ei[N_EDGES + e];
        int pos = row_start[d] + atomicAdd(&cursor[d], 1);
        edges4[pos] = make_int4(s, d, e, 0);
    }
}

// CSR-ordered pass: coalesced read of edges4; emit esrc + conv1 alpha (exp without
// max-subtraction: logits are O(1) at this data scale, softmax is shift-invariant)
__global__ void csr_alpha_kernel(const int4* __restrict__ edges4,
                                 const float4* __restrict__ as4, const float4* __restrict__ ad4,
                                 int* __restrict__ esrc, float4* __restrict__ alpha4) {
    int p = blockIdx.x * blockDim.x + threadIdx.x;
    if (p < N_EDGES) {
        int4 t = edges4[p];
        esrc[p] = t.x;
        alpha4[p] = exp4(lrelu4(as4[t.x] + ad4[t.y]));
    }
}

// ---------------- watt[k][j] = sum_c W1[k][h*64+c] * att_{src|dst}[h][c] ----------------
__global__ void watt_kernel(const float* __restrict__ W1, const float* __restrict__ as_,
                            const float* __restrict__ ad_, float* __restrict__ watt) {
    int idx = blockIdx.x * blockDim.x + threadIdx.x;
    if (idx >= 128 * 8) return;
    int k = idx >> 3, j = idx & 7;
    int h = j & 3;
    const float* av = (j < 4) ? as_ : ad_;
    float sum = 0.f;
    for (int c = 0; c < 64; c++) sum += W1[k * 256 + h * 64 + c] * av[h * 64 + c];
    watt[k * 8 + j] = sum;
}

// ---------------- bf16 transposed weights for MFMA GEMMs ----------------
// Bt1[n][k]=W1[k][n] (256x128); Bt2[n][k]=W2[k][n] (64x256); Btd[n][k] (256x64);
// Bte[n][k] (16x64): n<8 -> We2[k][n], else 0 (zero-padded edge-decode B)
__global__ void build_wts_kernel(const float* __restrict__ W1, const float* __restrict__ W2,
                                 const float* __restrict__ Wn, const float* __restrict__ We1,
                                 const float* __restrict__ We2,
                                 unsigned short* __restrict__ Bt1, unsigned short* __restrict__ Bt2,
                                 unsigned short* __restrict__ Btd, unsigned short* __restrict__ Bte) {
    int idx = blockIdx.x * blockDim.x + threadIdx.x;
    if (idx < 256 * 128) {
        int n = idx >> 7, k = idx & 127;
        Bt1[idx] = f2bf(W1[k * 256 + n]);
    }
    if (idx < 64 * 256) {
        int n = idx >> 8, k = idx & 255;
        Bt2[idx] = f2bf(W2[k * 64 + n]);
    }
    if (idx < 256 * 64) {
        int n = idx >> 6, k = idx & 63;
        float v;
        if (n < 128) v = Wn[k * 128 + n];
        else {
            int nn = n - 128;
            v = (nn < 64) ? We1[k * 64 + nn] : We1[(64 + k) * 64 + (nn - 64)];
        }
        Btd[idx] = f2bf(v);
    }
    if (idx < 16 * 64) {
        int n = idx >> 6, k = idx & 63;
        Bte[idx] = (n < 8) ? f2bf(We2[k * 8 + n]) : (unsigned short)0;
    }
}

// ---------------- attention scalars from x (+ bf16 copy of x): wave per node ----------------
__global__ __launch_bounds__(256) void asad_kernel(const float* __restrict__ x,
                                                   const float* __restrict__ watt,
                                                   float4* __restrict__ as4,
                                                   float4* __restrict__ ad4,
                                                   unsigned* __restrict__ xb) {
    int wid = (blockIdx.x * blockDim.x + threadIdx.x) >> 6;
    int lane = threadIdx.x & 63;
    if (wid >= N_NODES) return;
    float2 xv = *reinterpret_cast<const float2*>(&x[(size_t)wid * 128 + lane * 2]);
    xb[(size_t)wid * 64 + lane] = pack2bf(xv.x, xv.y);
    float p[8];
    const float* w0 = &watt[(2 * lane) * 8];
    const float* w1 = &watt[(2 * lane + 1) * 8];
#pragma unroll
    for (int j = 0; j < 8; j++) p[j] = fmaf(xv.x, w0[j], xv.y * w1[j]);
#pragma unroll
    for (int off = 32; off; off >>= 1)
#pragma unroll
        for (int j = 0; j < 8; j++) p[j] += __shfl_xor(p[j], off, 64);
    if (lane == 0) {
        as4[wid] = make_float4(p[0], p[1], p[2], p[3]);
        ad4[wid] = make_float4(p[4], p[5], p[6], p[7]);
    }
}

// ---------------- conv1 accumulate: wave/node; alpha+src via uniform SCALAR loads ----------------
__global__ __launch_bounds__(256) void agg4x_acc_kernel(const unsigned short* __restrict__ xb,
                                                        const float4* __restrict__ as4,
                                                        const float4* __restrict__ ad4,
                                                        const int* __restrict__ row_start,
                                                        const int* __restrict__ esrc,
                                                        const float4* __restrict__ alpha4,
                                                        unsigned* __restrict__ xaggb) {
    int wid = (blockIdx.x * blockDim.x + threadIdx.x) >> 6;
    int lane = threadIdx.x & 63;
    if (wid >= N_NODES) return;
    int beg = __builtin_amdgcn_readfirstlane(row_start[wid]);
    int end = __builtin_amdgcn_readfirstlane(row_start[wid + 1]);
    float4 adn = ad4[wid];
    float4 e_self = exp4(lrelu4(as4[wid] + adn));
    float4 den = e_self;
    float2 xv = bf2f2(*reinterpret_cast<const unsigned*>(&xb[(size_t)wid * 128 + lane * 2]));
    float2 acc0 = make_float2(e_self.x * xv.x, e_self.x * xv.y);
    float2 acc1 = make_float2(e_self.y * xv.x, e_self.y * xv.y);
    float2 acc2 = make_float2(e_self.z * xv.x, e_self.z * xv.y);
    float2 acc3 = make_float2(e_self.w * xv.x, e_self.w * xv.y);
    int j = beg;
    for (; j + 1 < end; j += 2) {
        float4 ea = alpha4[j];
        int sa = esrc[j];
        float4 eb = alpha4[j + 1];
        int sb = esrc[j + 1];
        float2 va = bf2f2(*reinterpret_cast<const unsigned*>(&xb[(size_t)sa * 128 + lane * 2]));
        float2 vb = bf2f2(*reinterpret_cast<const unsigned*>(&xb[(size_t)sb * 128 + lane * 2]));
        acc0.x = fmaf(ea.x, va.x, acc0.x); acc0.y = fmaf(ea.x, va.y, acc0.y);
        acc1.x = fmaf(ea.y, va.x, acc1.x); acc1.y = fmaf(ea.y, va.y, acc1.y);
        acc2.x = fmaf(ea.z, va.x, acc2.x); acc2.y = fmaf(ea.z, va.y, acc2.y);
        acc3.x = fmaf(ea.w, va.x, acc3.x); acc3.y = fmaf(ea.w, va.y, acc3.y);
        den = den + ea;
        acc0.x = fmaf(eb.x, vb.x, acc0.x); acc0.y = fmaf(eb.x, vb.y, acc0.y);
        acc1.x = fmaf(eb.y, vb.x, acc1.x); acc1.y = fmaf(eb.y, vb.y, acc1.y);
        acc2.x = fmaf(eb.z, vb.x, acc2.x); acc2.y = fmaf(eb.z, vb.y, acc2.y);
        acc3.x = fmaf(eb.w, vb.x, acc3.x); acc3.y = fmaf(eb.w, vb.y, acc3.y);
        den = den + eb;
    }
    if (j < end) {
        float4 ea = alpha4[j];
        int sa = esrc[j];
        float2 va = bf2f2(*reinterpret_cast<const unsigned*>(&xb[(size_t)sa * 128 + lane * 2]));
        acc0.x = fmaf(ea.x, va.x, acc0.x); acc0.y = fmaf(ea.x, va.y, acc0.y);
        acc1.x = fmaf(ea.y, va.x, acc1.x); acc1.y = fmaf(ea.y, va.y, acc1.y);
        acc2.x = fmaf(ea.z, va.x, acc2.x); acc2.y = fmaf(ea.z, va.y, acc2.y);
        acc3.x = fmaf(ea.w, va.x, acc3.x); acc3.y = fmaf(ea.w, va.y, acc3.y);
        den = den + ea;
    }
    float i0 = 1.f / (den.x + 1e-16f);
    float i1 = 1.f / (den.y + 1e-16f);
    float i2 = 1.f / (den.z + 1e-16f);
    float i3 = 1.f / (den.w + 1e-16f);
    size_t base = (size_t)wid * 64 + lane;
    xaggb[0 * PLANEU + base] = pack2bf(acc0.x * i0, acc0.y * i0);
    xaggb[1 * PLANEU + base] = pack2bf(acc1.x * i1, acc1.y * i1);
    xaggb[2 * PLANEU + base] = pack2bf(acc2.x * i2, acc2.y * i2);
    xaggb[3 * PLANEU + base] = pack2bf(acc3.x * i3, acc3.y * i3);
}

// ================= MFMA GEMMs (16x16x32 bf16, LDS-free) =================

// conv1: per-head (blockIdx.y): A plane, cols [y*64, y*64+64); bias+relu, bf16 out
template <int K>
__global__ __launch_bounds__(256) void mfma_gemm1_kernel(const unsigned short* __restrict__ A,
                                                         int lda, long aPlane,
                                                         const unsigned short* __restrict__ Bt,
                                                         const float* __restrict__ bias,
                                                         unsigned short* __restrict__ C, int ldc,
                                                         int M) {
    int tid = threadIdx.x;
    int w = tid >> 6, l = tid & 63;
    int bcol = blockIdx.y * 64;
    A += (size_t)blockIdx.y * aPlane;
    int row_a = blockIdx.x * 64 + w * 16 + (l & 15);
    int kq = (l >> 4) * 8;
    bool aval = row_a < M;
    const unsigned short* Arow = A + (size_t)row_a * lda;
    f32x4 acc[4] = {};
#pragma unroll
    for (int kb = 0; kb < K / 32; kb++) {
        int k0 = kb * 32 + kq;
        bf16x8 a = {};
        if (aval) a = *reinterpret_cast<const bf16x8*>(&Arow[k0]);
#pragma unroll
        for (int nb = 0; nb < 4; nb++) {
            bf16x8 b = *reinterpret_cast<const bf16x8*>(
                &Bt[(size_t)(bcol + nb * 16 + (l & 15)) * K + k0]);
            acc[nb] = __builtin_amdgcn_mfma_f32_16x16x32_bf16(a, b, acc[nb], 0, 0, 0);
        }
    }
    int orow = blockIdx.x * 64 + w * 16 + (l >> 4) * 4;
#pragma unroll
    for (int nb = 0; nb < 4; nb++) {
        int col = bcol + nb * 16 + (l & 15);
        float bb = bias[col];
#pragma unroll
        for (int r = 0; r < 4; r++) {
            int row = orow + r;
            if (row < M) C[(size_t)row * ldc + col] = f2bf(fmaxf(acc[nb][r] + bb, 0.f));
        }
    }
}

// conv2 (K=256, N=64): bf16 H2 out + fused per-row attention scalars (from fp32 acc)
__global__ __launch_bounds__(256) void mfma_gemm2_kernel(const unsigned short* __restrict__ A,
                                                         const unsigned short* __restrict__ Bt,
                                                         const float* __restrict__ att_src,
                                                         const float* __restrict__ att_dst,
                                                         unsigned short* __restrict__ h2b,
                                                         float* __restrict__ as_,
                                                         float* __restrict__ ad_, int M) {
    int tid = threadIdx.x;
    int w = tid >> 6, l = tid & 63;
    int row_a = blockIdx.x * 64 + w * 16 + (l & 15);
    int kq = (l >> 4) * 8;
    bool aval = row_a < M;
    const unsigned short* Arow = A + (size_t)row_a * 256;
    f32x4 acc[4] = {};
#pragma unroll
    for (int kb = 0; kb < 8; kb++) {
        int k0 = kb * 32 + kq;
        bf16x8 a = {};
        if (aval) a = *reinterpret_cast<const bf16x8*>(&Arow[k0]);
#pragma unroll
        for (int nb = 0; nb < 4; nb++) {
            bf16x8 b = *reinterpret_cast<const bf16x8*>(
                &Bt[(size_t)(nb * 16 + (l & 15)) * 256 + k0]);
            acc[nb] = __builtin_amdgcn_mfma_f32_16x16x32_bf16(a, b, acc[nb], 0, 0, 0);
        }
    }
    int orow = blockIdx.x * 64 + w * 16 + (l >> 4) * 4;
    float ps[4] = {}, pd[4] = {};
#pragma unroll
    for (int nb = 0; nb < 4; nb++) {
        int col = nb * 16 + (l & 15);
        float s = att_src[col], dd = att_dst[col];
#pragma unroll
        for (int r = 0; r < 4; r++) {
            float v = acc[nb][r];
            ps[r] = fmaf(v, s, ps[r]);
            pd[r] = fmaf(v, dd, pd[r]);
            int row = orow + r;
            if (row < M) h2b[(size_t)row * 64 + col] = f2bf(v);
        }
    }
#pragma unroll
    for (int off = 1; off <= 8; off <<= 1)
#pragma unroll
        for (int r = 0; r < 4; r++) {
            ps[r] += __shfl_xor(ps[r], off, 64);
            pd[r] += __shfl_xor(pd[r], off, 64);
        }
    if ((l & 15) == 0) {
#pragma unroll
        for (int r = 0; r < 4; r++) {
            int row = orow + r;
            if (row < M) { as_[row] = ps[r]; ad_[row] = pd[r]; }
        }
    }
}

// decode (K=64, N=256): cols<128 -> recon_x fp32 (+bn); cols>=128 -> PQb bf16
__global__ __launch_bounds__(256) void mfma_gemm_decode_kernel(const unsigned short* __restrict__ zb,
                                                               const unsigned short* __restrict__ Btd,
                                                               const float* __restrict__ bn,
                                                               float* __restrict__ recon_x,
                                                               unsigned short* __restrict__ PQb,
                                                               int M) {
    int tid = threadIdx.x;
    int w = tid >> 6, l = tid & 63;
    int bcol = blockIdx.y * 64;
    int row_a = blockIdx.x * 64 + w * 16 + (l & 15);
    int kq = (l >> 4) * 8;
    bool aval = row_a < M;
    const unsigned short* Arow = zb + (size_t)row_a * 64;
    f32x4 acc[4] = {};
#pragma unroll
    for (int kb = 0; kb < 2; kb++) {
        int k0 = kb * 32 + kq;
        bf16x8 a = {};
        if (aval) a = *reinterpret_cast<const bf16x8*>(&Arow[k0]);
#pragma unroll
        for (int nb = 0; nb < 4; nb++) {
            bf16x8 b = *reinterpret_cast<const bf16x8*>(
                &Btd[(size_t)(bcol + nb * 16 + (l & 15)) * 64 + k0]);
            acc[nb] = __builtin_amdgcn_mfma_f32_16x16x32_bf16(a, b, acc[nb], 0, 0, 0);
        }
    }
    int orow = blockIdx.x * 64 + w * 16 + (l >> 4) * 4;
#pragma unroll
    for (int nb = 0; nb < 4; nb++) {
        int col = bcol + nb * 16 + (l & 15);
        if (col < 128) {
            float bb = bn[col];
#pragma unroll
            for (int r = 0; r < 4; r++) {
                int row = orow + r;
                if (row < M) recon_x[(size_t)row * 128 + col] = acc[nb][r] + bb;
            }
        } else {
#pragma unroll
            for (int r = 0; r < 4; r++) {
                int row = orow + r;
                if (row < M) PQb[(size_t)row * 128 + (col - 128)] = f2bf(acc[nb][r]);
            }
        }
    }
}

// ---------------- conv2 per-edge alpha (CSR order, coalesced) ----------------
__global__ void alpha1_kernel(const int4* __restrict__ edges4,
                              const float* __restrict__ as_, const float* __restrict__ ad_,
                              float* __restrict__ alpha1) {
    int p = blockIdx.x * blockDim.x + threadIdx.x;
    if (p < N_EDGES) {
        int4 t = edges4[p];
        alpha1[p] = __expf(lrelu(as_[t.x] + ad_[t.y]));
    }
}

// ---------------- conv2 accumulate: wave/node, 2 edges/iter, bf16 z out ----------------
__global__ __launch_bounds__(256) void agg1_acc_kernel(const unsigned short* __restrict__ h2b,
                                                       const float* __restrict__ as_,
                                                       const float* __restrict__ ad_,
                                                       const int* __restrict__ row_start,
                                                       const int* __restrict__ esrc,
                                                       const float* __restrict__ alpha1,
                                                       const float* __restrict__ bias,
                                                       unsigned* __restrict__ zb) {
    int wid = (blockIdx.x * blockDim.x + threadIdx.x) >> 6;
    int lane = threadIdx.x & 63;
    if (wid >= N_NODES) return;
    int g = lane >> 5;
    int c = lane & 31;
    int beg = __builtin_amdgcn_readfirstlane(row_start[wid]);
    int end = __builtin_amdgcn_readfirstlane(row_start[wid + 1]);
    float adn = ad_[wid];
    float e_self = __expf(lrelu(as_[wid] + adn));
    float den = (g == 0) ? e_self : 0.f;
    float2 hv = bf2f2(*reinterpret_cast<const unsigned*>(&h2b[(size_t)wid * 64 + 2 * c]));
    float2 acc = (g == 0) ? make_float2(e_self * hv.x, e_self * hv.y)
                          : make_float2(0.f, 0.f);
    for (int j = beg; j < end; j += 2) {
        float a0 = alpha1[j];
        int s0 = esrc[j];
        float a1 = 0.f;
        int s1 = s0;
        if (j + 1 < end) { a1 = alpha1[j + 1]; s1 = esrc[j + 1]; }
        float e = g ? a1 : a0;
        int s = g ? s1 : s0;
        float2 v = bf2f2(*reinterpret_cast<const unsigned*>(&h2b[(size_t)s * 64 + 2 * c]));
        acc.x = fmaf(e, v.x, acc.x);
        acc.y = fmaf(e, v.y, acc.y);
        den += e;
    }
    den += __shfl_xor(den, 32, 64);
    acc.x += __shfl_xor(acc.x, 32, 64);
    acc.y += __shfl_xor(acc.y, 32, 64);
    if (g == 0) {
        float inv = 1.f / (den + 1e-16f);
        float2 bb = *reinterpret_cast<const float2*>(&bias[2 * c]);
        zb[(size_t)wid * 32 + c] = pack2bf(acc.x * inv + bb.x, acc.y * inv + bb.y);
    }
}

// ---------------- MFMA edge decode: 16 edges/wave, t built in-register ----------------
// A-frag: lane l = edge row (l&15), k-quarter (l>>4)*8; t = relu(P[s]+Q[d]+be1) in bf16.
// B (Bte, [16][64], zero-padded cols 8..15) hoisted to 2 regs. C/D: outchan=l&15, row=(l>>4)*4+r.
#define ED_BLOCKS 2048
__device__ __forceinline__ bf16x8 make_t(uint4 up, uint4 uq, float4 ba, float4 bb) {
    float2 p0 = bf2f2(up.x), p1 = bf2f2(up.y), p2 = bf2f2(up.z), p3 = bf2f2(up.w);
    float2 q0 = bf2f2(uq.x), q1 = bf2f2(uq.y), q2 = bf2f2(uq.z), q3 = bf2f2(uq.w);
    unsigned r0 = pack2bf(fmaxf(p0.x + q0.x + ba.x, 0.f), fmaxf(p0.y + q0.y + ba.y, 0.f));
    unsigned r1 = pack2bf(fmaxf(p1.x + q1.x + ba.z, 0.f), fmaxf(p1.y + q1.y + ba.w, 0.f));
    unsigned r2 = pack2bf(fmaxf(p2.x + q2.x + bb.x, 0.f), fmaxf(p2.y + q2.y + bb.y, 0.f));
    unsigned r3 = pack2bf(fmaxf(p3.x + q3.x + bb.z, 0.f), fmaxf(p3.y + q3.y + bb.w, 0.f));
    union { uint4 u; bf16x8 v; } c;
    c.u = make_uint4(r0, r1, r2, r3);
    return c.v;
}

__global__ __launch_bounds__(256) void mfma_edge_decode_kernel(const unsigned short* __restrict__ PQb,
                                                               const int4* __restrict__ edges4,
                                                               const float* __restrict__ be1,
                                                               const unsigned short* __restrict__ Bte,
                                                               const float* __restrict__ be2,
                                                               float* __restrict__ out) {
    int tid = threadIdx.x;
    int l = tid & 63;
    int col = l & 15;
    int kq = (l >> 4) * 8;
    bf16x8 b0 = *reinterpret_cast<const bf16x8*>(&Bte[col * 64 + kq]);
    bf16x8 b1 = *reinterpret_cast<const bf16x8*>(&Bte[col * 64 + 32 + kq]);
    float4 ba0 = *reinterpret_cast<const float4*>(&be1[kq]);
    float4 bb0 = *reinterpret_cast<const float4*>(&be1[kq + 4]);
    float4 ba1 = *reinterpret_cast<const float4*>(&be1[32 + kq]);
    float4 bb1 = *reinterpret_cast<const float4*>(&be1[32 + kq + 4]);
    float bout = (col < 8) ? be2[col] : 0.f;
    int rbase = (l >> 4) * 4;

    int wgid = (blockIdx.x * blockDim.x + tid) >> 6;
    const int nwaves = ED_BLOCKS * 4;
    const int ngroups = N_EDGES / 16;
    for (int g = wgid; g < ngroups; g += nwaves) {
        int base = g * 16;
        int4 t4 = edges4[base + col];
        const unsigned short* Pr = &PQb[(size_t)t4.x * 128];
        const unsigned short* Qr = &PQb[(size_t)t4.y * 128 + 64];
        uint4 up0 = *reinterpret_cast<const uint4*>(&Pr[kq]);
        uint4 uq0 = *reinterpret_cast<const uint4*>(&Qr[kq]);
        uint4 up1 = *reinterpret_cast<const uint4*>(&Pr[32 + kq]);
        uint4 uq1 = *reinterpret_cast<const uint4*>(&Qr[32 + kq]);
        bf16x8 a0 = make_t(up0, uq0, ba0, bb0);
        bf16x8 a1 = make_t(up1, uq1, ba1, bb1);
        f32x4 acc = {};
        acc = __builtin_amdgcn_mfma_f32_16x16x32_bf16(a0, b0, acc, 0, 0, 0);
        acc = __builtin_amdgcn_mfma_f32_16x16x32_bf16(a1, b1, acc, 0, 0, 0);
        if (col < 8) {
#pragma unroll
            for (int r = 0; r < 4; r++) {
                int o = edges4[base + rbase + r].z;
                out[(size_t)o * 8 + col] = acc[r] + bout;
            }
        }
    }
}

extern "C" void kernel_launch(void* const* d_in, const int* in_sizes, int n_in,
                              void* d_out, int out_size, void* d_ws, size_t ws_size,
                              hipStream_t stream) {
    const float* x        = (const float*)d_in[0];
    const int*   ei       = (const int*)d_in[1];
    const float* W1       = (const float*)d_in[2];
    const float* att_src1 = (const float*)d_in[3];
    const float* att_dst1 = (const float*)d_in[4];
    const float* b1       = (const float*)d_in[5];
    const float* W2       = (const float*)d_in[6];
    const float* att_src2 = (const float*)d_in[7];
    const float* att_dst2 = (const float*)d_in[8];
    const float* b2       = (const float*)d_in[9];
    const float* Wn       = (const float*)d_in[10];
    const float* bn       = (const float*)d_in[11];
    const float* We1      = (const float*)d_in[12];
    const float* be1      = (const float*)d_in[13];
    const float* We2      = (const float*)d_in[14];
    const float* be2      = (const float*)d_in[15];

    char* ws = (char*)d_ws;
    size_t off = 0;
    auto alloc = [&](size_t bytes) {
        void* p = ws + off;
        off += (bytes + 255) & ~(size_t)255;
        return p;
    };
    int*   cnt       = (int*)alloc((size_t)N_NODES * 4);
    int*   row_start = (int*)alloc((size_t)(N_NODES + 1) * 4);
    int4*  edges4    = (int4*)alloc((size_t)N_EDGES * 16);                    // 12.8 MB
    int*   esrc      = (int*)alloc((size_t)N_EDGES * 4);                      // 3.2 MB
    float* watt      = (float*)alloc((size_t)128 * 8 * 4);
    float* as1       = (float*)alloc((size_t)N_NODES * 4 * 4);
    float* ad1       = (float*)alloc((size_t)N_NODES * 4 * 4);
    unsigned* xb     = (unsigned*)alloc((size_t)N_NODES * 64 * 4);            // 12.8 MB bf16
    float* alpha4    = (float*)alloc((size_t)N_EDGES * 4 * 4);                // 12.8 MB
    unsigned* xaggb  = (unsigned*)alloc((size_t)4 * PLANEU * 4);              // 25.6 MB bf16
    unsigned short* houtb = (unsigned short*)alloc((size_t)N_NODES * 256 * 2); // 25.6 MB bf16
    unsigned* h2b    = (unsigned*)alloc((size_t)N_NODES * 32 * 4);            // 6.4 MB bf16
    float* as2       = (float*)alloc((size_t)N_NODES * 4);
    float* ad2       = (float*)alloc((size_t)N_NODES * 4);
    float* alpha1    = (float*)alloc((size_t)N_EDGES * 4);                    // 3.2 MB
    unsigned* zb     = (unsigned*)alloc((size_t)N_NODES * 32 * 4);            // 6.4 MB bf16
    unsigned short* PQb = (unsigned short*)alloc((size_t)N_NODES * 128 * 2);  // 12.8 MB
    unsigned short* Bt1 = (unsigned short*)alloc((size_t)256 * 128 * 2);
    unsigned short* Bt2 = (unsigned short*)alloc((size_t)64 * 256 * 2);
    unsigned short* Btd = (unsigned short*)alloc((size_t)256 * 64 * 2);
    unsigned short* Bte = (unsigned short*)alloc((size_t)16 * 64 * 2);

    float* recon_x = (float*)d_out;
    float* recon_e = (float*)d_out + (size_t)N_NODES * F_IN;

    // CSR build: count, scan; attention scalars; packed scatter; CSR-ordered alpha pass
    hipMemsetAsync(cnt, 0, (size_t)N_NODES * 4, stream);
    count_kernel<<<(N_EDGES + 255) / 256, 256, 0, stream>>>(ei, cnt);
    scan_kernel<<<1, 1024, 0, stream>>>(cnt, row_start);
    watt_kernel<<<4, 256, 0, stream>>>(W1, att_src1, att_dst1, watt);
    build_wts_kernel<<<128, 256, 0, stream>>>(W1, W2, Wn, We1, We2, Bt1, Bt2, Btd, Bte);
    asad_kernel<<<(N_NODES * 64 + 255) / 256, 256, 0, stream>>>(x, watt, (float4*)as1,
                                                                (float4*)ad1, xb);
    hipMemsetAsync(cnt, 0, (size_t)N_NODES * 4, stream);
    scatter_pack_kernel<<<(N_EDGES + 255) / 256, 256, 0, stream>>>(ei, row_start, cnt, edges4);
    csr_alpha_kernel<<<(N_EDGES + 255) / 256, 256, 0, stream>>>(
        edges4, (const float4*)as1, (const float4*)ad1, esrc, (float4*)alpha4);

    // conv1 accumulate + per-head MFMA GEMM applies W1 (bf16 out)
    agg4x_acc_kernel<<<(N_NODES * 64 + 255) / 256, 256, 0, stream>>>(
        (const unsigned short*)xb, (const float4*)as1, (const float4*)ad1, row_start, esrc,
        (const float4*)alpha4, xaggb);
    dim3 gc1((N_NODES + 63) / 64, 4);
    mfma_gemm1_kernel<128><<<gc1, 256, 0, stream>>>(
        (const unsigned short*)xaggb, 128, (long)PLANE, Bt1, b1, houtb, 256, N_NODES);

    // conv2: MFMA GEMM with fused att-scalar epilogue, then alpha + accumulate
    mfma_gemm2_kernel<<<(N_NODES + 63) / 64, 256, 0, stream>>>(
        houtb, Bt2, att_src2, att_dst2, (unsigned short*)h2b, as2, ad2, N_NODES);
    alpha1_kernel<<<(N_EDGES + 255) / 256, 256, 0, stream>>>(edges4, as2, ad2, alpha1);
    agg1_acc_kernel<<<(N_NODES * 64 + 255) / 256, 256, 0, stream>>>(
        (const unsigned short*)h2b, as2, ad2, row_start, esrc, alpha1, b2, zb);

    // fused decode MFMA GEMM: recon_x (fp32) + PQ (bf16) in one pass over zb
    dim3 gdec((N_NODES + 63) / 64, 4);
    mfma_gemm_decode_kernel<<<gdec, 256, 0, stream>>>(
        (const unsigned short*)zb, Btd, bn, recon_x, PQb, N_NODES);

    // MFMA edge decode (CSR order, packed edge records)
    mfma_edge_decode_kernel<<<ED_BLOCKS, 256, 0, stream>>>(PQb, edges4, be1, Bte, be2, recon_e);
}

// Round 11
// 305.408 us; speedup vs baseline: 3.9348x; 1.2689x over previous
//
#include <hip/hip_runtime.h>

#define N_NODES 50000
#define N_EDGES 800000
#define F_IN    128
#define HEADS   4
#define HID     64
#define LAT     64
#define N_EC    8
#define SLOPE   0.2f
#define NBUCKET 196                       // ceil(N_NODES/256); bucket = dst>>8
#define PLANE   ((size_t)N_NODES * 128)   // one head's xagg plane (bf16 elements)
#define PLANEU  ((size_t)N_NODES * 64)    // packed 2xbf16 units per plane

typedef __attribute__((ext_vector_type(8))) short bf16x8;   // 8 bf16 (4 VGPRs)
typedef __attribute__((ext_vector_type(4))) float f32x4;

__device__ __forceinline__ float lrelu(float x) { return x > 0.f ? x : SLOPE * x; }
__device__ __forceinline__ float4 operator+(float4 a, float4 b) { return make_float4(a.x+b.x, a.y+b.y, a.z+b.z, a.w+b.w); }
__device__ __forceinline__ float4 lrelu4(float4 a) { return make_float4(lrelu(a.x), lrelu(a.y), lrelu(a.z), lrelu(a.w)); }
__device__ __forceinline__ float4 exp4(float4 a) { return make_float4(__expf(a.x), __expf(a.y), __expf(a.z), __expf(a.w)); }

// bf16 helpers (manual, RNE)
__device__ __forceinline__ unsigned short f2bf(float f) {
    union { float f; unsigned u; } a; a.f = f;
    unsigned r = a.u + 0x7fffu + ((a.u >> 16) & 1u);
    return (unsigned short)(r >> 16);
}
__device__ __forceinline__ unsigned pack2bf(float x, float y) {
    return (unsigned)f2bf(x) | ((unsigned)f2bf(y) << 16);
}
__device__ __forceinline__ float2 bf2f2(unsigned u) {
    union { unsigned q; float f; } a, b;
    a.q = u << 16; b.q = u & 0xffff0000u;
    return make_float2(a.f, b.f);
}

// ================= CSR build via 2-level MSD bucket sort =================
// A0: coarse histogram (block-aggregated atomics)
__global__ __launch_bounds__(256) void bucket_count_kernel(const int* __restrict__ ei,
                                                           int* __restrict__ bcnt) {
    __shared__ int h[NBUCKET];
    int tid = threadIdx.x;
    for (int i = tid; i < NBUCKET; i += 256) h[i] = 0;
    __syncthreads();
    int beg = blockIdx.x * 4096;
    int end = min(beg + 4096, N_EDGES);
    for (int e = beg + tid; e < end; e += 256)
        atomicAdd(&h[ei[N_EDGES + e] >> 8], 1);
    __syncthreads();
    for (int i = tid; i < NBUCKET; i += 256)
        if (h[i]) atomicAdd(&bcnt[i], h[i]);
}

// A1: tiny scan of bucket counts; zero cursors; row_start tail
__global__ __launch_bounds__(256) void scan_buckets_kernel(const int* __restrict__ bcnt,
                                                           int* __restrict__ bbase,
                                                           int* __restrict__ bcur,
                                                           int* __restrict__ row_start) {
    __shared__ int sh[NBUCKET + 1];
    int tid = threadIdx.x;
    if (tid < NBUCKET) { sh[tid] = bcnt[tid]; bcur[tid] = 0; }
    __syncthreads();
    if (tid == 0) {
        int a = 0;
        for (int i = 0; i < NBUCKET; i++) { int t = sh[i]; sh[i] = a; a += t; }
        sh[NBUCKET] = a;
        row_start[N_NODES] = N_EDGES;
    }
    __syncthreads();
    if (tid <= NBUCKET) bbase[tid] = sh[tid];
}

// A: coarse scatter — block-aggregated cursors; same-bucket records land contiguously.
// coarse record: word0 = s | (d_lo<<16)  (s<2^16, d_lo<2^8), word1 = original edge id
__global__ __launch_bounds__(256) void coarse_scatter_kernel(const int* __restrict__ ei,
                                                             const int* __restrict__ bbase,
                                                             int* __restrict__ bcur,
                                                             uint2* __restrict__ coarse) {
    __shared__ int h[NBUCKET];
    __shared__ int base[NBUCKET];
    int tid = threadIdx.x;
    for (int i = tid; i < NBUCKET; i += 256) h[i] = 0;
    __syncthreads();
    int beg = blockIdx.x * 4096;
    int w0_[16], o_[16], b_[16];
#pragma unroll
    for (int k = 0; k < 16; k++) {
        int e = beg + k * 256 + tid;
        b_[k] = -1;
        if (e < N_EDGES) {
            int s = ei[e], d = ei[N_EDGES + e];
            int bk = d >> 8;
            b_[k] = bk;
            w0_[k] = s | ((d & 255) << 16);
            o_[k] = e;
            atomicAdd(&h[bk], 1);
        }
    }
    __syncthreads();
    for (int i = tid; i < NBUCKET; i += 256) {
        int c = h[i];
        base[i] = c ? atomicAdd(&bcur[i], c) : 0;
        h[i] = 0;
    }
    __syncthreads();
#pragma unroll
    for (int k = 0; k < 16; k++) {
        if (b_[k] >= 0) {
            int r = atomicAdd(&h[b_[k]], 1);
            coarse[bbase[b_[k]] + base[b_[k]] + r] = make_uint2((unsigned)w0_[k], (unsigned)o_[k]);
        }
    }
}

// B: per-bucket fine sort; emits row_start + esrc + packed edges2 + conv1 alpha (fused).
// exp without max-subtraction: logits are O(1) at this data scale; softmax shift-invariant.
__global__ __launch_bounds__(256) void fine_pass_kernel(const uint2* __restrict__ coarse,
                                                        const int* __restrict__ bbase,
                                                        const float4* __restrict__ as4,
                                                        const float4* __restrict__ ad4,
                                                        int* __restrict__ esrc,
                                                        float4* __restrict__ alpha4,
                                                        uint2* __restrict__ edges2,
                                                        int* __restrict__ row_start) {
    int bucket = blockIdx.x;
    int tid = threadIdx.x;
    int lo = bbase[bucket], hi = bbase[bucket + 1];
    __shared__ int h[256];
    __shared__ int wsum[4];
    __shared__ int cur[256];
    h[tid] = 0;
    __syncthreads();
    for (int p = lo + tid; p < hi; p += 256)
        atomicAdd(&h[(coarse[p].x >> 16) & 0xff], 1);
    __syncthreads();
    int v = h[tid];
    int lane = tid & 63, w = tid >> 6;
    int incl = v;
#pragma unroll
    for (int off = 1; off < 64; off <<= 1) {
        int t = __shfl_up(incl, off, 64);
        if (lane >= off) incl += t;
    }
    if (lane == 63) wsum[w] = incl;
    __syncthreads();
    if (tid == 0) {
        int a = 0;
#pragma unroll
        for (int i = 0; i < 4; i++) { int t = wsum[i]; wsum[i] = a; a += t; }
    }
    __syncthreads();
    int excl = incl - v + wsum[w];
    int node = bucket * 256 + tid;
    if (node < N_NODES) row_start[node] = lo + excl;
    cur[tid] = lo + excl;
    __syncthreads();
    for (int p = lo + tid; p < hi; p += 256) {
        uint2 r = coarse[p];
        int dl = (r.x >> 16) & 0xff;
        int s = r.x & 0xffff;
        int d = bucket * 256 + dl;
        int pos = atomicAdd(&cur[dl], 1);
        esrc[pos] = s;
        edges2[pos] = make_uint2((unsigned)(s | (d << 16)), r.y);
        alpha4[pos] = exp4(lrelu4(as4[s] + ad4[d]));
    }
}

// ---------------- watt[k][j] = sum_c W1[k][h*64+c] * att_{src|dst}[h][c] ----------------
__global__ void watt_kernel(const float* __restrict__ W1, const float* __restrict__ as_,
                            const float* __restrict__ ad_, float* __restrict__ watt) {
    int idx = blockIdx.x * blockDim.x + threadIdx.x;
    if (idx >= 128 * 8) return;
    int k = idx >> 3, j = idx & 7;
    int h = j & 3;
    const float* av = (j < 4) ? as_ : ad_;
    float sum = 0.f;
    for (int c = 0; c < 64; c++) sum += W1[k * 256 + h * 64 + c] * av[h * 64 + c];
    watt[k * 8 + j] = sum;
}

// ---------------- bf16 transposed weights for MFMA GEMMs ----------------
__global__ void build_wts_kernel(const float* __restrict__ W1, const float* __restrict__ W2,
                                 const float* __restrict__ Wn, const float* __restrict__ We1,
                                 const float* __restrict__ We2,
                                 unsigned short* __restrict__ Bt1, unsigned short* __restrict__ Bt2,
                                 unsigned short* __restrict__ Btd, unsigned short* __restrict__ Bte) {
    int idx = blockIdx.x * blockDim.x + threadIdx.x;
    if (idx < 256 * 128) {
        int n = idx >> 7, k = idx & 127;
        Bt1[idx] = f2bf(W1[k * 256 + n]);
    }
    if (idx < 64 * 256) {
        int n = idx >> 8, k = idx & 255;
        Bt2[idx] = f2bf(W2[k * 64 + n]);
    }
    if (idx < 256 * 64) {
        int n = idx >> 6, k = idx & 63;
        float v;
        if (n < 128) v = Wn[k * 128 + n];
        else {
            int nn = n - 128;
            v = (nn < 64) ? We1[k * 64 + nn] : We1[(64 + k) * 64 + (nn - 64)];
        }
        Btd[idx] = f2bf(v);
    }
    if (idx < 16 * 64) {
        int n = idx >> 6, k = idx & 63;
        Bte[idx] = (n < 8) ? f2bf(We2[k * 8 + n]) : (unsigned short)0;
    }
}

// ---------------- attention scalars from x (+ bf16 copy of x): wave per node ----------------
__global__ __launch_bounds__(256) void asad_kernel(const float* __restrict__ x,
                                                   const float* __restrict__ watt,
                                                   float4* __restrict__ as4,
                                                   float4* __restrict__ ad4,
                                                   unsigned* __restrict__ xb) {
    int wid = (blockIdx.x * blockDim.x + threadIdx.x) >> 6;
    int lane = threadIdx.x & 63;
    if (wid >= N_NODES) return;
    float2 xv = *reinterpret_cast<const float2*>(&x[(size_t)wid * 128 + lane * 2]);
    xb[(size_t)wid * 64 + lane] = pack2bf(xv.x, xv.y);
    float p[8];
    const float* w0 = &watt[(2 * lane) * 8];
    const float* w1 = &watt[(2 * lane + 1) * 8];
#pragma unroll
    for (int j = 0; j < 8; j++) p[j] = fmaf(xv.x, w0[j], xv.y * w1[j]);
#pragma unroll
    for (int off = 32; off; off >>= 1)
#pragma unroll
        for (int j = 0; j < 8; j++) p[j] += __shfl_xor(p[j], off, 64);
    if (lane == 0) {
        as4[wid] = make_float4(p[0], p[1], p[2], p[3]);
        ad4[wid] = make_float4(p[4], p[5], p[6], p[7]);
    }
}

// ---------------- conv1 accumulate: wave/node; alpha+src via uniform SCALAR loads ----------------
__global__ __launch_bounds__(256) void agg4x_acc_kernel(const unsigned short* __restrict__ xb,
                                                        const float4* __restrict__ as4,
                                                        const float4* __restrict__ ad4,
                                                        const int* __restrict__ row_start,
                                                        const int* __restrict__ esrc,
                                                        const float4* __restrict__ alpha4,
                                                        unsigned* __restrict__ xaggb) {
    int wid = (blockIdx.x * blockDim.x + threadIdx.x) >> 6;
    int lane = threadIdx.x & 63;
    if (wid >= N_NODES) return;
    int beg = __builtin_amdgcn_readfirstlane(row_start[wid]);
    int end = __builtin_amdgcn_readfirstlane(row_start[wid + 1]);
    float4 adn = ad4[wid];
    float4 e_self = exp4(lrelu4(as4[wid] + adn));
    float4 den = e_self;
    float2 xv = bf2f2(*reinterpret_cast<const unsigned*>(&xb[(size_t)wid * 128 + lane * 2]));
    float2 acc0 = make_float2(e_self.x * xv.x, e_self.x * xv.y);
    float2 acc1 = make_float2(e_self.y * xv.x, e_self.y * xv.y);
    float2 acc2 = make_float2(e_self.z * xv.x, e_self.z * xv.y);
    float2 acc3 = make_float2(e_self.w * xv.x, e_self.w * xv.y);
    int j = beg;
    for (; j + 1 < end; j += 2) {
        float4 ea = alpha4[j];
        int sa = esrc[j];
        float4 eb = alpha4[j + 1];
        int sb = esrc[j + 1];
        float2 va = bf2f2(*reinterpret_cast<const unsigned*>(&xb[(size_t)sa * 128 + lane * 2]));
        float2 vb = bf2f2(*reinterpret_cast<const unsigned*>(&xb[(size_t)sb * 128 + lane * 2]));
        acc0.x = fmaf(ea.x, va.x, acc0.x); acc0.y = fmaf(ea.x, va.y, acc0.y);
        acc1.x = fmaf(ea.y, va.x, acc1.x); acc1.y = fmaf(ea.y, va.y, acc1.y);
        acc2.x = fmaf(ea.z, va.x, acc2.x); acc2.y = fmaf(ea.z, va.y, acc2.y);
        acc3.x = fmaf(ea.w, va.x, acc3.x); acc3.y = fmaf(ea.w, va.y, acc3.y);
        den = den + ea;
        acc0.x = fmaf(eb.x, vb.x, acc0.x); acc0.y = fmaf(eb.x, vb.y, acc0.y);
        acc1.x = fmaf(eb.y, vb.x, acc1.x); acc1.y = fmaf(eb.y, vb.y, acc1.y);
        acc2.x = fmaf(eb.z, vb.x, acc2.x); acc2.y = fmaf(eb.z, vb.y, acc2.y);
        acc3.x = fmaf(eb.w, vb.x, acc3.x); acc3.y = fmaf(eb.w, vb.y, acc3.y);
        den = den + eb;
    }
    if (j < end) {
        float4 ea = alpha4[j];
        int sa = esrc[j];
        float2 va = bf2f2(*reinterpret_cast<const unsigned*>(&xb[(size_t)sa * 128 + lane * 2]));
        acc0.x = fmaf(ea.x, va.x, acc0.x); acc0.y = fmaf(ea.x, va.y, acc0.y);
        acc1.x = fmaf(ea.y, va.x, acc1.x); acc1.y = fmaf(ea.y, va.y, acc1.y);
        acc2.x = fmaf(ea.z, va.x, acc2.x); acc2.y = fmaf(ea.z, va.y, acc2.y);
        acc3.x = fmaf(ea.w, va.x, acc3.x); acc3.y = fmaf(ea.w, va.y, acc3.y);
        den = den + ea;
    }
    float i0 = 1.f / (den.x + 1e-16f);
    float i1 = 1.f / (den.y + 1e-16f);
    float i2 = 1.f / (den.z + 1e-16f);
    float i3 = 1.f / (den.w + 1e-16f);
    size_t base = (size_t)wid * 64 + lane;
    xaggb[0 * PLANEU + base] = pack2bf(acc0.x * i0, acc0.y * i0);
    xaggb[1 * PLANEU + base] = pack2bf(acc1.x * i1, acc1.y * i1);
    xaggb[2 * PLANEU + base] = pack2bf(acc2.x * i2, acc2.y * i2);
    xaggb[3 * PLANEU + base] = pack2bf(acc3.x * i3, acc3.y * i3);
}

// ================= MFMA GEMMs (16x16x32 bf16, LDS-free) =================

// conv1: per-head (blockIdx.y): A plane, cols [y*64, y*64+64); bias+relu, bf16 out
template <int K>
__global__ __launch_bounds__(256) void mfma_gemm1_kernel(const unsigned short* __restrict__ A,
                                                         int lda, long aPlane,
                                                         const unsigned short* __restrict__ Bt,
                                                         const float* __restrict__ bias,
                                                         unsigned short* __restrict__ C, int ldc,
                                                         int M) {
    int tid = threadIdx.x;
    int w = tid >> 6, l = tid & 63;
    int bcol = blockIdx.y * 64;
    A += (size_t)blockIdx.y * aPlane;
    int row_a = blockIdx.x * 64 + w * 16 + (l & 15);
    int kq = (l >> 4) * 8;
    bool aval = row_a < M;
    const unsigned short* Arow = A + (size_t)row_a * lda;
    f32x4 acc[4] = {};
#pragma unroll
    for (int kb = 0; kb < K / 32; kb++) {
        int k0 = kb * 32 + kq;
        bf16x8 a = {};
        if (aval) a = *reinterpret_cast<const bf16x8*>(&Arow[k0]);
#pragma unroll
        for (int nb = 0; nb < 4; nb++) {
            bf16x8 b = *reinterpret_cast<const bf16x8*>(
                &Bt[(size_t)(bcol + nb * 16 + (l & 15)) * K + k0]);
            acc[nb] = __builtin_amdgcn_mfma_f32_16x16x32_bf16(a, b, acc[nb], 0, 0, 0);
        }
    }
    int orow = blockIdx.x * 64 + w * 16 + (l >> 4) * 4;
#pragma unroll
    for (int nb = 0; nb < 4; nb++) {
        int col = bcol + nb * 16 + (l & 15);
        float bb = bias[col];
#pragma unroll
        for (int r = 0; r < 4; r++) {
            int row = orow + r;
            if (row < M) C[(size_t)row * ldc + col] = f2bf(fmaxf(acc[nb][r] + bb, 0.f));
        }
    }
}

// conv2 (K=256, N=64): bf16 H2 out + fused per-row attention scalars (from fp32 acc)
__global__ __launch_bounds__(256) void mfma_gemm2_kernel(const unsigned short* __restrict__ A,
                                                         const unsigned short* __restrict__ Bt,
                                                         const float* __restrict__ att_src,
                                                         const float* __restrict__ att_dst,
                                                         unsigned short* __restrict__ h2b,
                                                         float* __restrict__ as_,
                                                         float* __restrict__ ad_, int M) {
    int tid = threadIdx.x;
    int w = tid >> 6, l = tid & 63;
    int row_a = blockIdx.x * 64 + w * 16 + (l & 15);
    int kq = (l >> 4) * 8;
    bool aval = row_a < M;
    const unsigned short* Arow = A + (size_t)row_a * 256;
    f32x4 acc[4] = {};
#pragma unroll
    for (int kb = 0; kb < 8; kb++) {
        int k0 = kb * 32 + kq;
        bf16x8 a = {};
        if (aval) a = *reinterpret_cast<const bf16x8*>(&Arow[k0]);
#pragma unroll
        for (int nb = 0; nb < 4; nb++) {
            bf16x8 b = *reinterpret_cast<const bf16x8*>(
                &Bt[(size_t)(nb * 16 + (l & 15)) * 256 + k0]);
            acc[nb] = __builtin_amdgcn_mfma_f32_16x16x32_bf16(a, b, acc[nb], 0, 0, 0);
        }
    }
    int orow = blockIdx.x * 64 + w * 16 + (l >> 4) * 4;
    float ps[4] = {}, pd[4] = {};
#pragma unroll
    for (int nb = 0; nb < 4; nb++) {
        int col = nb * 16 + (l & 15);
        float s = att_src[col], dd = att_dst[col];
#pragma unroll
        for (int r = 0; r < 4; r++) {
            float v = acc[nb][r];
            ps[r] = fmaf(v, s, ps[r]);
            pd[r] = fmaf(v, dd, pd[r]);
            int row = orow + r;
            if (row < M) h2b[(size_t)row * 64 + col] = f2bf(v);
        }
    }
#pragma unroll
    for (int off = 1; off <= 8; off <<= 1)
#pragma unroll
        for (int r = 0; r < 4; r++) {
            ps[r] += __shfl_xor(ps[r], off, 64);
            pd[r] += __shfl_xor(pd[r], off, 64);
        }
    if ((l & 15) == 0) {
#pragma unroll
        for (int r = 0; r < 4; r++) {
            int row = orow + r;
            if (row < M) { as_[row] = ps[r]; ad_[row] = pd[r]; }
        }
    }
}

// decode (K=64, N=256): cols<128 -> recon_x fp32 (+bn); cols>=128 -> PQb bf16
__global__ __launch_bounds__(256) void mfma_gemm_decode_kernel(const unsigned short* __restrict__ zb,
                                                               const unsigned short* __restrict__ Btd,
                                                               const float* __restrict__ bn,
                                                               float* __restrict__ recon_x,
                                                               unsigned short* __restrict__ PQb,
                                                               int M) {
    int tid = threadIdx.x;
    int w = tid >> 6, l = tid & 63;
    int bcol = blockIdx.y * 64;
    int row_a = blockIdx.x * 64 + w * 16 + (l & 15);
    int kq = (l >> 4) * 8;
    bool aval = row_a < M;
    const unsigned short* Arow = zb + (size_t)row_a * 64;
    f32x4 acc[4] = {};
#pragma unroll
    for (int kb = 0; kb < 2; kb++) {
        int k0 = kb * 32 + kq;
        bf16x8 a = {};
        if (aval) a = *reinterpret_cast<const bf16x8*>(&Arow[k0]);
#pragma unroll
        for (int nb = 0; nb < 4; nb++) {
            bf16x8 b = *reinterpret_cast<const bf16x8*>(
                &Btd[(size_t)(bcol + nb * 16 + (l & 15)) * 64 + k0]);
            acc[nb] = __builtin_amdgcn_mfma_f32_16x16x32_bf16(a, b, acc[nb], 0, 0, 0);
        }
    }
    int orow = blockIdx.x * 64 + w * 16 + (l >> 4) * 4;
#pragma unroll
    for (int nb = 0; nb < 4; nb++) {
        int col = bcol + nb * 16 + (l & 15);
        if (col < 128) {
            float bb = bn[col];
#pragma unroll
            for (int r = 0; r < 4; r++) {
                int row = orow + r;
                if (row < M) recon_x[(size_t)row * 128 + col] = acc[nb][r] + bb;
            }
        } else {
#pragma unroll
            for (int r = 0; r < 4; r++) {
                int row = orow + r;
                if (row < M) PQb[(size_t)row * 128 + (col - 128)] = f2bf(acc[nb][r]);
            }
        }
    }
}

// ---------------- conv2 per-edge alpha (CSR order, packed records) ----------------
__global__ void alpha1_kernel(const uint2* __restrict__ edges2,
                              const float* __restrict__ as_, const float* __restrict__ ad_,
                              float* __restrict__ alpha1) {
    int p = blockIdx.x * blockDim.x + threadIdx.x;
    if (p < N_EDGES) {
        unsigned w0 = edges2[p].x;
        alpha1[p] = __expf(lrelu(as_[w0 & 0xffff] + ad_[w0 >> 16]));
    }
}

// ---------------- conv2 accumulate: wave/node, 2 edges/iter, bf16 z out ----------------
__global__ __launch_bounds__(256) void agg1_acc_kernel(const unsigned short* __restrict__ h2b,
                                                       const float* __restrict__ as_,
                                                       const float* __restrict__ ad_,
                                                       const int* __restrict__ row_start,
                                                       const int* __restrict__ esrc,
                                                       const float* __restrict__ alpha1,
                                                       const float* __restrict__ bias,
                                                       unsigned* __restrict__ zb) {
    int wid = (blockIdx.x * blockDim.x + threadIdx.x) >> 6;
    int lane = threadIdx.x & 63;
    if (wid >= N_NODES) return;
    int g = lane >> 5;
    int c = lane & 31;
    int beg = __builtin_amdgcn_readfirstlane(row_start[wid]);
    int end = __builtin_amdgcn_readfirstlane(row_start[wid + 1]);
    float adn = ad_[wid];
    float e_self = __expf(lrelu(as_[wid] + adn));
    float den = (g == 0) ? e_self : 0.f;
    float2 hv = bf2f2(*reinterpret_cast<const unsigned*>(&h2b[(size_t)wid * 64 + 2 * c]));
    float2 acc = (g == 0) ? make_float2(e_self * hv.x, e_self * hv.y)
                          : make_float2(0.f, 0.f);
    for (int j = beg; j < end; j += 2) {
        float a0 = alpha1[j];
        int s0 = esrc[j];
        float a1 = 0.f;
        int s1 = s0;
        if (j + 1 < end) { a1 = alpha1[j + 1]; s1 = esrc[j + 1]; }
        float e = g ? a1 : a0;
        int s = g ? s1 : s0;
        float2 v = bf2f2(*reinterpret_cast<const unsigned*>(&h2b[(size_t)s * 64 + 2 * c]));
        acc.x = fmaf(e, v.x, acc.x);
        acc.y = fmaf(e, v.y, acc.y);
        den += e;
    }
    den += __shfl_xor(den, 32, 64);
    acc.x += __shfl_xor(acc.x, 32, 64);
    acc.y += __shfl_xor(acc.y, 32, 64);
    if (g == 0) {
        float inv = 1.f / (den + 1e-16f);
        float2 bb = *reinterpret_cast<const float2*>(&bias[2 * c]);
        zb[(size_t)wid * 32 + c] = pack2bf(acc.x * inv + bb.x, acc.y * inv + bb.y);
    }
}

// ---------------- MFMA edge decode: 16 edges/wave, packed records ----------------
#define ED_BLOCKS 2048
__device__ __forceinline__ bf16x8 make_t(uint4 up, uint4 uq, float4 ba, float4 bb) {
    float2 p0 = bf2f2(up.x), p1 = bf2f2(up.y), p2 = bf2f2(up.z), p3 = bf2f2(up.w);
    float2 q0 = bf2f2(uq.x), q1 = bf2f2(uq.y), q2 = bf2f2(uq.z), q3 = bf2f2(uq.w);
    unsigned r0 = pack2bf(fmaxf(p0.x + q0.x + ba.x, 0.f), fmaxf(p0.y + q0.y + ba.y, 0.f));
    unsigned r1 = pack2bf(fmaxf(p1.x + q1.x + ba.z, 0.f), fmaxf(p1.y + q1.y + ba.w, 0.f));
    unsigned r2 = pack2bf(fmaxf(p2.x + q2.x + bb.x, 0.f), fmaxf(p2.y + q2.y + bb.y, 0.f));
    unsigned r3 = pack2bf(fmaxf(p3.x + q3.x + bb.z, 0.f), fmaxf(p3.y + q3.y + bb.w, 0.f));
    union { uint4 u; bf16x8 v; } c;
    c.u = make_uint4(r0, r1, r2, r3);
    return c.v;
}

__global__ __launch_bounds__(256) void mfma_edge_decode_kernel(const unsigned short* __restrict__ PQb,
                                                               const uint2* __restrict__ edges2,
                                                               const float* __restrict__ be1,
                                                               const unsigned short* __restrict__ Bte,
                                                               const float* __restrict__ be2,
                                                               float* __restrict__ out) {
    int tid = threadIdx.x;
    int l = tid & 63;
    int col = l & 15;
    int kq = (l >> 4) * 8;
    bf16x8 b0 = *reinterpret_cast<const bf16x8*>(&Bte[col * 64 + kq]);
    bf16x8 b1 = *reinterpret_cast<const bf16x8*>(&Bte[col * 64 + 32 + kq]);
    float4 ba0 = *reinterpret_cast<const float4*>(&be1[kq]);
    float4 bb0 = *reinterpret_cast<const float4*>(&be1[kq + 4]);
    float4 ba1 = *reinterpret_cast<const float4*>(&be1[32 + kq]);
    float4 bb1 = *reinterpret_cast<const float4*>(&be1[32 + kq + 4]);
    float bout = (col < 8) ? be2[col] : 0.f;
    int rbase = (l >> 4) * 4;

    int wgid = (blockIdx.x * blockDim.x + tid) >> 6;
    const int nwaves = ED_BLOCKS * 4;
    const int ngroups = N_EDGES / 16;
    for (int g = wgid; g < ngroups; g += nwaves) {
        int base = g * 16;
        uint2 t2 = edges2[base + col];
        int s = t2.x & 0xffff, d = t2.x >> 16;
        const unsigned short* Pr = &PQb[(size_t)s * 128];
        const unsigned short* Qr = &PQb[(size_t)d * 128 + 64];
        uint4 up0 = *reinterpret_cast<const uint4*>(&Pr[kq]);
        uint4 uq0 = *reinterpret_cast<const uint4*>(&Qr[kq]);
        uint4 up1 = *reinterpret_cast<const uint4*>(&Pr[32 + kq]);
        uint4 uq1 = *reinterpret_cast<const uint4*>(&Qr[32 + kq]);
        bf16x8 a0 = make_t(up0, uq0, ba0, bb0);
        bf16x8 a1 = make_t(up1, uq1, ba1, bb1);
        f32x4 acc = {};
        acc = __builtin_amdgcn_mfma_f32_16x16x32_bf16(a0, b0, acc, 0, 0, 0);
        acc = __builtin_amdgcn_mfma_f32_16x16x32_bf16(a1, b1, acc, 0, 0, 0);
        if (col < 8) {
#pragma unroll
            for (int r = 0; r < 4; r++) {
                int o = edges2[base + rbase + r].y;
                out[(size_t)o * 8 + col] = acc[r] + bout;
            }
        }
    }
}

extern "C" void kernel_launch(void* const* d_in, const int* in_sizes, int n_in,
                              void* d_out, int out_size, void* d_ws, size_t ws_size,
                              hipStream_t stream) {
    const float* x        = (const float*)d_in[0];
    const int*   ei       = (const int*)d_in[1];
    const float* W1       = (const float*)d_in[2];
    const float* att_src1 = (const float*)d_in[3];
    const float* att_dst1 = (const float*)d_in[4];
    const float* b1       = (const float*)d_in[5];
    const float* W2       = (const float*)d_in[6];
    const float* att_src2 = (const float*)d_in[7];
    const float* att_dst2 = (const float*)d_in[8];
    const float* b2       = (const float*)d_in[9];
    const float* Wn       = (const float*)d_in[10];
    const float* bn       = (const float*)d_in[11];
    const float* We1      = (const float*)d_in[12];
    const float* be1      = (const float*)d_in[13];
    const float* We2      = (const float*)d_in[14];
    const float* be2      = (const float*)d_in[15];

    char* ws = (char*)d_ws;
    size_t off = 0;
    auto alloc = [&](size_t bytes) {
        void* p = ws + off;
        off += (bytes + 255) & ~(size_t)255;
        return p;
    };
    int*   bcnt      = (int*)alloc((size_t)NBUCKET * 4);
    int*   bbase     = (int*)alloc((size_t)(NBUCKET + 1) * 4);
    int*   bcur      = (int*)alloc((size_t)NBUCKET * 4);
    int*   row_start = (int*)alloc((size_t)(N_NODES + 1) * 4);
    uint2* coarse    = (uint2*)alloc((size_t)N_EDGES * 8);                    // 6.4 MB
    uint2* edges2    = (uint2*)alloc((size_t)N_EDGES * 8);                    // 6.4 MB
    int*   esrc      = (int*)alloc((size_t)N_EDGES * 4);                      // 3.2 MB
    float* watt      = (float*)alloc((size_t)128 * 8 * 4);
    float* as1       = (float*)alloc((size_t)N_NODES * 4 * 4);
    float* ad1       = (float*)alloc((size_t)N_NODES * 4 * 4);
    unsigned* xb     = (unsigned*)alloc((size_t)N_NODES * 64 * 4);            // 12.8 MB bf16
    float* alpha4    = (float*)alloc((size_t)N_EDGES * 4 * 4);                // 12.8 MB
    unsigned* xaggb  = (unsigned*)alloc((size_t)4 * PLANEU * 4);              // 25.6 MB bf16
    unsigned short* houtb = (unsigned short*)alloc((size_t)N_NODES * 256 * 2); // 25.6 MB bf16
    unsigned* h2b    = (unsigned*)alloc((size_t)N_NODES * 32 * 4);            // 6.4 MB bf16
    float* as2       = (float*)alloc((size_t)N_NODES * 4);
    float* ad2       = (float*)alloc((size_t)N_NODES * 4);
    float* alpha1    = (float*)alloc((size_t)N_EDGES * 4);                    // 3.2 MB
    unsigned* zb     = (unsigned*)alloc((size_t)N_NODES * 32 * 4);            // 6.4 MB bf16
    unsigned short* PQb = (unsigned short*)alloc((size_t)N_NODES * 128 * 2);  // 12.8 MB
    unsigned short* Bt1 = (unsigned short*)alloc((size_t)256 * 128 * 2);
    unsigned short* Bt2 = (unsigned short*)alloc((size_t)64 * 256 * 2);
    unsigned short* Btd = (unsigned short*)alloc((size_t)256 * 64 * 2);
    unsigned short* Bte = (unsigned short*)alloc((size_t)16 * 64 * 2);

    float* recon_x = (float*)d_out;
    float* recon_e = (float*)d_out + (size_t)N_NODES * F_IN;

    const int ablocks = (N_EDGES + 4095) / 4096;   // 196

    // CSR build via bucket sort + fused alpha
    hipMemsetAsync(bcnt, 0, (size_t)NBUCKET * 4, stream);
    bucket_count_kernel<<<ablocks, 256, 0, stream>>>(ei, bcnt);
    scan_buckets_kernel<<<1, 256, 0, stream>>>(bcnt, bbase, bcur, row_start);
    watt_kernel<<<4, 256, 0, stream>>>(W1, att_src1, att_dst1, watt);
    build_wts_kernel<<<128, 256, 0, stream>>>(W1, W2, Wn, We1, We2, Bt1, Bt2, Btd, Bte);
    asad_kernel<<<(N_NODES * 64 + 255) / 256, 256, 0, stream>>>(x, watt, (float4*)as1,
                                                                (float4*)ad1, xb);
    coarse_scatter_kernel<<<ablocks, 256, 0, stream>>>(ei, bbase, bcur, coarse);
    fine_pass_kernel<<<NBUCKET, 256, 0, stream>>>(coarse, bbase, (const float4*)as1,
                                                  (const float4*)ad1, esrc, (float4*)alpha4,
                                                  edges2, row_start);

    // conv1 accumulate + per-head MFMA GEMM applies W1 (bf16 out)
    agg4x_acc_kernel<<<(N_NODES * 64 + 255) / 256, 256, 0, stream>>>(
        (const unsigned short*)xb, (const float4*)as1, (const float4*)ad1, row_start, esrc,
        (const float4*)alpha4, xaggb);
    dim3 gc1((N_NODES + 63) / 64, 4);
    mfma_gemm1_kernel<128><<<gc1, 256, 0, stream>>>(
        (const unsigned short*)xaggb, 128, (long)PLANE, Bt1, b1, houtb, 256, N_NODES);

    // conv2: MFMA GEMM with fused att-scalar epilogue, then alpha + accumulate
    mfma_gemm2_kernel<<<(N_NODES + 63) / 64, 256, 0, stream>>>(
        houtb, Bt2, att_src2, att_dst2, (unsigned short*)h2b, as2, ad2, N_NODES);
    alpha1_kernel<<<(N_EDGES + 255) / 256, 256, 0, stream>>>(edges2, as2, ad2, alpha1);
    agg1_acc_kernel<<<(N_NODES * 64 + 255) / 256, 256, 0, stream>>>(
        (const unsigned short*)h2b, as2, ad2, row_start, esrc, alpha1, b2, zb);

    // fused decode MFMA GEMM: recon_x (fp32) + PQ (bf16) in one pass over zb
    dim3 gdec((N_NODES + 63) / 64, 4);
    mfma_gemm_decode_kernel<<<gdec, 256, 0, stream>>>(
        (const unsigned short*)zb, Btd, bn, recon_x, PQb, N_NODES);

    // MFMA edge decode (CSR order, packed edge records)
    mfma_edge_decode_kernel<<<ED_BLOCKS, 256, 0, stream>>>(PQb, edges2, be1, Bte, be2, recon_e);
}